// Round 2
// baseline (1982.665 us; speedup 1.0000x reference)
//
#include <hip/hip_runtime.h>
#include <hip/hip_bf16.h>

#define HW 65536

__device__ __forceinline__ float bfu(unsigned short u){
    return __uint_as_float(((unsigned int)u) << 16);
}
__device__ __forceinline__ unsigned short f2bu(float f){
    unsigned int u = __float_as_uint(f);
    unsigned int r = (u + 0x7fffu + ((u >> 16) & 1u)) >> 16;
    return (unsigned short)r;
}

// ---------------- K0: precompute coefficient tables ----------------
__global__ void k_coef(const float* __restrict__ wlp1, const float* __restrict__ whp1,
                       const float* __restrict__ wlp2,
                       const float* __restrict__ wld, const float* __restrict__ whd,
                       const float* __restrict__ wout,
                       float* __restrict__ ahp1,
                       float* __restrict__ WLP, float* __restrict__ WLN,
                       float* __restrict__ WHP, float* __restrict__ WHN,
                       float* __restrict__ WLD2, float* __restrict__ WHD2,
                       float* __restrict__ woutT){
    __shared__ float aL[508], cp[508], cn[508];
    int t = threadIdx.x;
    if (t < 508){
        int g = t >> 2, o = t & 3;
        float s = 0.f, s2 = 0.f;
        for (int i = 0; i < 4; ++i){ s += wlp1[g*16 + o*4 + i]; s2 += whp1[g*16 + o*4 + i]; }
        aL[t] = s; ahp1[t] = s2;
    }
    __syncthreads();
    if (t < 508){
        int g = t >> 2, o = t & 3;
        float p = 0.f, n = 0.f;
        for (int k = 0; k < 4; ++k){
            int idx = 4*g + k;                    // shuffled position
            int inv = (idx % 127)*4 + idx/127;    // original channel
            float av = aL[inv];
            float w2 = wlp2[g*16 + o*4 + k];
            p += w2 * fmaxf(av, 0.f);
            n += w2 * fminf(av, 0.f);
        }
        cp[t] = p; cn[t] = n;
    }
    __syncthreads();
    for (int idx = t; idx < 127*9; idx += blockDim.x){
        int g = idx/9, q = idx%9;
        float lp=0.f, ln=0.f, hp=0.f, hn=0.f;
        for (int i = 0; i < 4; ++i){
            int ch = 4*g + i;
            if (ch < 254){ float w = wld[g*36 + i*9 + q]; lp += w*cp[ch]; ln += w*cn[ch]; }
            else         { float w = whd[g*36 + i*9 + q]; hp += w*cp[ch]; hn += w*cn[ch]; }
        }
        WLP[idx]=lp; WLN[idx]=ln; WHP[idx]=hp; WHN[idx]=hn;
    }
    for (int idx = t; idx < 127*36; idx += blockDim.x){
        int g = idx/36, r = idx%36; int i = r/9;
        int ch = 4*g + i;
        WLD2[idx] = (ch >= 254) ? wld[idx] : 0.f;
        WHD2[idx] = (ch <  254) ? whd[idx] : 0.f;
    }
    for (int idx = t; idx < 48*254; idx += blockDim.x){
        int c = idx/48, o = idx%48;
        woutT[idx] = wout[o*254 + c];
    }
}

// ---------------- K1a: u = w_inP @ x  (1x1, 48->254), banded, bf16 ----------------
// block = one row (256 threads). grid = nbat * urows.
__global__ __launch_bounds__(256) void k_pconv(const float* __restrict__ x,
        const float* __restrict__ wP, unsigned short* __restrict__ u,
        int b0, int ur0, int urows, int uR){
    int bi = blockIdx.x / urows;
    int lr = blockIdx.x - bi*urows;
    int b = b0 + bi;
    int grow = ur0 + lr;
    int xx = threadIdx.x;
    const float* xb = x + (size_t)b*48*HW + (size_t)grow*256 + xx;
    float xr[48];
    #pragma unroll
    for (int c = 0; c < 48; ++c) xr[c] = xb[(size_t)c*HW];
    unsigned short* ub = u + (size_t)bi*254*uR*256 + (size_t)lr*256 + xx;
    size_t cs = (size_t)uR*256;   // channel stride
    #pragma unroll 2
    for (int o = 0; o < 254; o += 2){
        float a0 = 0.f, a1 = 0.f;
        const float* w0 = wP + o*48;
        #pragma unroll
        for (int c = 0; c < 48; ++c){ a0 = fmaf(w0[c], xr[c], a0); a1 = fmaf(w0[48+c], xr[c], a1); }
        ub[(size_t)o*cs]     = f2bu(a0);
        ub[(size_t)(o+1)*cs] = f2bu(a1);
    }
}

// ---------------- K1b: depthwise 3x3 x2 + relu + channel-sum, banded ----------------
__global__ __launch_bounds__(256) void k_dw(const unsigned short* __restrict__ u,
        const float* __restrict__ wD, unsigned short* __restrict__ t4, float* __restrict__ S,
        int tr0, int trows, int ur0, int uR, int tR){
    int bi = blockIdx.x / trows;
    int lr = blockIdx.x - bi*trows;
    int grow = tr0 + lr;
    int xx = threadIdx.x;
    int lrow0 = grow - ur0;
    const unsigned short* ub = u + (size_t)bi*254*uR*256 + (size_t)lrow0*256 + xx;
    size_t ucs = (size_t)uR*256;
    unsigned short* tb = t4 + (size_t)bi*127*tR*256*4 + ((size_t)lr*256 + xx)*4;
    size_t tcs = (size_t)tR*256*4;
    bool ym = grow>0, yp = grow<255, xm = xx>0, xp = xx<255;
    float ssum = 0.f;
    for (int c = 0; c < 254; c += 2){
        float acc[4];
        #pragma unroll
        for (int uc = 0; uc < 2; ++uc){
            const unsigned short* up = ub + (size_t)(c+uc)*ucs;
            float v[9];
            v[0] = (ym&&xm)? bfu(up[-257]) : 0.f;
            v[1] = (ym)    ? bfu(up[-256]) : 0.f;
            v[2] = (ym&&xp)? bfu(up[-255]) : 0.f;
            v[3] = (xm)    ? bfu(up[-1])   : 0.f;
            v[4] =           bfu(up[0]);
            v[5] = (xp)    ? bfu(up[1])    : 0.f;
            v[6] = (yp&&xm)? bfu(up[255])  : 0.f;
            v[7] = (yp)    ? bfu(up[256])  : 0.f;
            v[8] = (yp&&xp)? bfu(up[257])  : 0.f;
            const float* w0 = wD + (size_t)(2*(c+uc))*9;
            float t0 = 0.f, t1 = 0.f;
            #pragma unroll
            for (int q = 0; q < 9; ++q){ t0 = fmaf(w0[q], v[q], t0); t1 = fmaf(w0[9+q], v[q], t1); }
            acc[2*uc]   = fmaxf(t0, 0.f);
            acc[2*uc+1] = fmaxf(t1, 0.f);
        }
        ssum += (acc[0]+acc[1]) + (acc[2]+acc[3]);
        ushort4 st; st.x=f2bu(acc[0]); st.y=f2bu(acc[1]); st.z=f2bu(acc[2]); st.w=f2bu(acc[3]);
        *reinterpret_cast<ushort4*>(tb + (size_t)(c>>1)*tcs) = st;
    }
    S[(size_t)bi*tR*256 + (size_t)lr*256 + xx] = ssum * (1.f/9.f);
}

// ---------------- K2: 3x3 box with edge clamp, banded ----------------
__global__ __launch_bounds__(256) void k_box(const float* __restrict__ S, float* __restrict__ Lm,
        int lr0, int lrows, int tr0, int tR, int lR){
    int bi = blockIdx.x / lrows;
    int lr = blockIdx.x - bi*lrows;
    int grow = lr0 + lr;
    int xx = threadIdx.x;
    const float* Sb = S + (size_t)bi*tR*256;
    int g0 = max(grow-1,0) - tr0, g1 = grow - tr0, g2 = min(grow+1,255) - tr0;
    int x0 = max(xx-1,0), x2 = min(xx+1,255);
    float s = Sb[g0*256+x0]+Sb[g0*256+xx]+Sb[g0*256+x2]
            + Sb[g1*256+x0]+Sb[g1*256+xx]+Sb[g1*256+x2]
            + Sb[g2*256+x0]+Sb[g2*256+xx]+Sb[g2*256+x2];
    Lm[(size_t)bi*lR*256 + (size_t)lr*256 + xx] = s;
}

// ---------------- K3: h-path g1x1 + relu + shuffle + g1x1 -> h2, banded ----------------
__global__ __launch_bounds__(256) void k_mix(const unsigned short* __restrict__ t4,
        const float* __restrict__ Lm, const float* __restrict__ whp1, const float* __restrict__ whp2,
        const float* __restrict__ ahp1, unsigned short* __restrict__ h2,
        int lr0, int lrows, int tr0, int tR, int lR){
    int bi = blockIdx.x / lrows;
    int lr = blockIdx.x - bi*lrows;
    int grow = lr0 + lr;
    int xx = threadIdx.x;
    const unsigned short* tb = t4 + (size_t)bi*127*tR*256*4 + ((size_t)(grow-tr0)*256 + xx)*4;
    size_t tcs = (size_t)tR*256*4;
    unsigned short* hb = h2 + (size_t)bi*127*lR*256*4 + ((size_t)lr*256 + xx)*4;
    size_t hcs = (size_t)lR*256*4;
    float Lv = Lm[(size_t)bi*lR*256 + (size_t)lr*256 + xx];
    for (int g = 0; g < 127; ++g){
        float a0=0.f,a1=0.f,a2=0.f,a3=0.f;
        #pragma unroll
        for (int k = 0; k < 4; ++k){
            int idx = 4*g + k;          // shuffled channel position
            int gi = idx % 127;         // original group
            int oi = idx / 127;         // original output-in-group
            int ci = gi*4 + oi;         // original (h1) channel
            ushort4 raw = *reinterpret_cast<const ushort4*>(tb + (size_t)gi*tcs);
            const float* w1 = whp1 + gi*16 + oi*4;
            float h1 = fmaf(w1[0], bfu(raw.x), fmaf(w1[1], bfu(raw.y),
                       fmaf(w1[2], bfu(raw.z), w1[3]*bfu(raw.w))));
            h1 = fmaxf(fmaf(-Lv, ahp1[ci], h1), 0.f);
            const float* w2 = whp2 + g*16;
            a0 = fmaf(w2[0*4+k], h1, a0);
            a1 = fmaf(w2[1*4+k], h1, a1);
            a2 = fmaf(w2[2*4+k], h1, a2);
            a3 = fmaf(w2[3*4+k], h1, a3);
        }
        ushort4 st; st.x=f2bu(a0); st.y=f2bu(a1); st.z=f2bu(a2); st.w=f2bu(a3);
        *reinterpret_cast<ushort4*>(hb + (size_t)g*hcs) = st;
    }
}

// ---------------- K4: grouped 3x3 + relu + 1x1 out + residual, banded ----------------
__global__ __launch_bounds__(256) void k_out(const unsigned short* __restrict__ h2,
     const float* __restrict__ Lm, const float* __restrict__ x,
     const float* __restrict__ WLP, const float* __restrict__ WLN,
     const float* __restrict__ WHP, const float* __restrict__ WHN,
     const float* __restrict__ WLD2, const float* __restrict__ WHD2,
     const float* __restrict__ woutT, float* __restrict__ out,
     int b0, int a, int orows, int lr0, int lR){
    int bi = blockIdx.x / orows;
    int lr = blockIdx.x - bi*orows;
    int b = b0 + bi;
    int grow = a + lr;
    int xx = threadIdx.x;
    const float* Lb = Lm + (size_t)bi*lR*256;
    float Lq[9]; int hoff[9]; bool valid[9];
    #pragma unroll
    for (int q = 0; q < 9; ++q){
        int dy = q/3 - 1, dx = q%3 - 1;
        int yy = grow+dy, xc = xx+dx;
        bool v = (yy>=0)&&(yy<256)&&(xc>=0)&&(xc<256);
        valid[q] = v;
        int o = v ? ((yy-lr0)*256 + xc) : ((grow-lr0)*256 + xx);
        hoff[q] = o;
        Lq[q] = v ? Lb[o] : 0.f;
    }
    float acc[48];
    const float* xb = x + (size_t)b*48*HW + (size_t)grow*256 + xx;
    #pragma unroll
    for (int o = 0; o < 48; ++o) acc[o] = xb[(size_t)o*HW];
    const unsigned short* hb = h2 + (size_t)bi*127*lR*256*4;
    size_t hcs = (size_t)lR*256*4;

    for (int g = 0; g < 127; ++g){
        float sl = 0.f, sh = 0.f;
        #pragma unroll
        for (int q = 0; q < 9; ++q){
            float lq = Lq[q];
            bool pos = lq > 0.f;
            float cl  = pos ? WLP[g*9+q] : WLN[g*9+q];
            float chh = pos ? WHP[g*9+q] : WHN[g*9+q];
            sl = fmaf(cl, lq, sl);
            sh = fmaf(chh, lq, sh);
        }
        const unsigned short* hq = hb + (size_t)g*hcs;
        if (g >= 63){   // l-branch h2-sourced channels (4g+i >= 254)
            const float* w = WLD2 + g*36;
            #pragma unroll
            for (int q = 0; q < 9; ++q){
                if (!valid[q]) continue;
                ushort4 r = *reinterpret_cast<const ushort4*>(hq + (size_t)hoff[q]*4);
                sl = fmaf(w[0*9+q], bfu(r.x), sl);
                sl = fmaf(w[1*9+q], bfu(r.y), sl);
                sl = fmaf(w[2*9+q], bfu(r.z), sl);
                sl = fmaf(w[3*9+q], bfu(r.w), sl);
            }
        }
        if (g <= 63){   // h-branch h2-sourced channels (4g+i < 254)
            const float* w = WHD2 + g*36;
            #pragma unroll
            for (int q = 0; q < 9; ++q){
                if (!valid[q]) continue;
                ushort4 r = *reinterpret_cast<const ushort4*>(hq + (size_t)hoff[q]*4);
                sh = fmaf(w[0*9+q], bfu(r.x), sh);
                sh = fmaf(w[1*9+q], bfu(r.y), sh);
                sh = fmaf(w[2*9+q], bfu(r.z), sh);
                sh = fmaf(w[3*9+q], bfu(r.w), sh);
            }
        }
        float vl = fmaxf(sl, 0.f), vh = fmaxf(sh, 0.f);
        const float* wt  = woutT + g*48;
        const float* wt2 = woutT + (127+g)*48;
        #pragma unroll
        for (int o = 0; o < 48; ++o) acc[o] = fmaf(wt[o], vl, fmaf(wt2[o], vh, acc[o]));
    }
    float* ob = out + (size_t)b*48*HW + (size_t)grow*256 + xx;
    #pragma unroll
    for (int o = 0; o < 48; ++o) ob[(size_t)o*HW] = acc[o];
}

extern "C" void kernel_launch(void* const* d_in, const int* in_sizes, int n_in,
                              void* d_out, int out_size, void* d_ws, size_t ws_size,
                              hipStream_t stream){
    const float* x    = (const float*)d_in[0];
    const float* winP = (const float*)d_in[1];
    const float* winD = (const float*)d_in[2];
    const float* wlp1 = (const float*)d_in[3];
    const float* whp1 = (const float*)d_in[4];
    const float* wlp2 = (const float*)d_in[5];
    const float* whp2 = (const float*)d_in[6];
    const float* wld  = (const float*)d_in[7];
    const float* whd  = (const float*)d_in[8];
    const float* wout = (const float*)d_in[9];
    float* out = (float*)d_out;

    char* ws = (char*)d_ws;
    size_t off = 0;
    auto alloc = [&](size_t bytes)->char*{
        char* pp = ws + off; off += (bytes + 255) & ~(size_t)255; return pp;
    };
    auto A = [](size_t bytes)->size_t{ return (bytes + 255) & ~(size_t)255; };

    // tables (always allocated first)
    float* ahp1 = (float*)alloc(508*4);
    float* WLP  = (float*)alloc(127*9*4);
    float* WLN  = (float*)alloc(127*9*4);
    float* WHP  = (float*)alloc(127*9*4);
    float* WHN  = (float*)alloc(127*9*4);
    float* WLD2 = (float*)alloc(127*36*4);
    float* WHD2 = (float*)alloc(127*36*4);
    float* woutT= (float*)alloc(48*254*4);

    // pick band config that fits ws_size
    const int cfgs[7][2] = {{256,2},{128,2},{64,2},{64,1},{32,1},{16,1},{8,1}};
    int Hb = 8, nbat = 1;
    for (int ci = 0; ci < 7; ++ci){
        int hb = cfgs[ci][0], nb = cfgs[ci][1];
        int uR = hb+6 < 256 ? hb+6 : 256;
        int tR = hb+4 < 256 ? hb+4 : 256;
        int lR = hb+2 < 256 ? hb+2 : 256;
        size_t need = off;
        need += A((size_t)nb*254*uR*256*2);
        need += A((size_t)nb*127*tR*256*4*2);
        need += A((size_t)nb*127*lR*256*4*2);
        need += A((size_t)nb*tR*256*4);
        need += A((size_t)nb*lR*256*4);
        if (need <= ws_size){ Hb = hb; nbat = nb; break; }
    }
    int uR = Hb+6 < 256 ? Hb+6 : 256;
    int tR = Hb+4 < 256 ? Hb+4 : 256;
    int lR = Hb+2 < 256 ? Hb+2 : 256;
    unsigned short* u  = (unsigned short*)alloc((size_t)nbat*254*uR*256*2);
    unsigned short* t4 = (unsigned short*)alloc((size_t)nbat*127*tR*256*4*2);
    unsigned short* h2 = (unsigned short*)alloc((size_t)nbat*127*lR*256*4*2);
    float* S  = (float*)alloc((size_t)nbat*tR*256*4);
    float* Lm = (float*)alloc((size_t)nbat*lR*256*4);

    k_coef<<<1, 512, 0, stream>>>(wlp1, whp1, wlp2, wld, whd, wout,
                                  ahp1, WLP, WLN, WHP, WHN, WLD2, WHD2, woutT);

    for (int b0 = 0; b0 < 2; b0 += nbat){
        for (int a = 0; a < 256; a += Hb){
            int ur0 = a-3 > 0 ? a-3 : 0;  int ur1 = a+Hb+3 < 256 ? a+Hb+3 : 256;
            int tr0 = a-2 > 0 ? a-2 : 0;  int tr1 = a+Hb+2 < 256 ? a+Hb+2 : 256;
            int lr0 = a-1 > 0 ? a-1 : 0;  int lr1 = a+Hb+1 < 256 ? a+Hb+1 : 256;
            int urows = ur1-ur0, trows = tr1-tr0, lrows = lr1-lr0;
            int orows = (a+Hb < 256 ? a+Hb : 256) - a;
            k_pconv<<<nbat*urows, 256, 0, stream>>>(x, winP, u, b0, ur0, urows, uR);
            k_dw  <<<nbat*trows, 256, 0, stream>>>(u, winD, t4, S, tr0, trows, ur0, uR, tR);
            k_box <<<nbat*lrows, 256, 0, stream>>>(S, Lm, lr0, lrows, tr0, tR, lR);
            k_mix <<<nbat*lrows, 256, 0, stream>>>(t4, Lm, whp1, whp2, ahp1, h2, lr0, lrows, tr0, tR, lR);
            k_out <<<nbat*orows, 256, 0, stream>>>(h2, Lm, x, WLP, WLN, WHP, WHN, WLD2, WHD2,
                                                   woutT, out, b0, a, orows, lr0, lR);
        }
    }
}

// Round 3
// 816.461 us; speedup vs baseline: 2.4284x; 2.4284x over previous
//
#include <hip/hip_runtime.h>
#include <hip/hip_bf16.h>

#define HW 65536
#define NCH 8   // channel chunks in k_dw

__device__ __forceinline__ float bfu(unsigned short u){
    return __uint_as_float(((unsigned int)u) << 16);
}
__device__ __forceinline__ unsigned short f2bu(float f){
    unsigned int u = __float_as_uint(f);
    unsigned int r = (u + 0x7fffu + ((u >> 16) & 1u)) >> 16;
    return (unsigned short)r;
}

// ---------------- K0: precompute coefficient tables ----------------
__global__ void k_coef(const float* __restrict__ wlp1, const float* __restrict__ whp1,
                       const float* __restrict__ wlp2,
                       const float* __restrict__ wld, const float* __restrict__ whd,
                       const float* __restrict__ wout,
                       float* __restrict__ ahp1,
                       float* __restrict__ WLP, float* __restrict__ WLN,
                       float* __restrict__ WHP, float* __restrict__ WHN,
                       float* __restrict__ WLD2, float* __restrict__ WHD2,
                       float* __restrict__ woutT){
    __shared__ float aL[508], cp[508], cn[508];
    int t = threadIdx.x;
    if (t < 508){
        int g = t >> 2, o = t & 3;
        float s = 0.f, s2 = 0.f;
        for (int i = 0; i < 4; ++i){ s += wlp1[g*16 + o*4 + i]; s2 += whp1[g*16 + o*4 + i]; }
        aL[t] = s; ahp1[t] = s2;
    }
    __syncthreads();
    if (t < 508){
        int g = t >> 2, o = t & 3;
        float p = 0.f, n = 0.f;
        for (int k = 0; k < 4; ++k){
            int idx = 4*g + k;                    // shuffled position
            int inv = (idx % 127)*4 + idx/127;    // original channel
            float av = aL[inv];
            float w2 = wlp2[g*16 + o*4 + k];
            p += w2 * fmaxf(av, 0.f);
            n += w2 * fminf(av, 0.f);
        }
        cp[t] = p; cn[t] = n;
    }
    __syncthreads();
    for (int idx = t; idx < 127*9; idx += blockDim.x){
        int g = idx/9, q = idx%9;
        float lp=0.f, ln=0.f, hp=0.f, hn=0.f;
        for (int i = 0; i < 4; ++i){
            int ch = 4*g + i;
            if (ch < 254){ float w = wld[g*36 + i*9 + q]; lp += w*cp[ch]; ln += w*cn[ch]; }
            else         { float w = whd[g*36 + i*9 + q]; hp += w*cp[ch]; hn += w*cn[ch]; }
        }
        WLP[idx]=lp; WLN[idx]=ln; WHP[idx]=hp; WHN[idx]=hn;
    }
    for (int idx = t; idx < 127*36; idx += blockDim.x){
        int g = idx/36, r = idx%36; int i = r/9;
        int ch = 4*g + i;
        WLD2[idx] = (ch >= 254) ? wld[idx] : 0.f;
        WHD2[idx] = (ch <  254) ? whd[idx] : 0.f;
    }
    for (int idx = t; idx < 48*254; idx += blockDim.x){
        int c = idx/48, o = idx%48;
        woutT[idx] = wout[o*254 + c];
    }
}

// ---------------- K1a: u = w_inP @ x (1x1 48->254), banded, split in 2 o-chunks ----------------
__global__ __launch_bounds__(256) void k_pconv(const float* __restrict__ x,
        const float* __restrict__ wP, unsigned short* __restrict__ u,
        int b0, int ur0, int urows, int uR){
    int t = blockIdx.x;
    int half = t & 1; t >>= 1;
    int bi = t / urows;
    int lr = t - bi*urows;
    int b = b0 + bi;
    int grow = ur0 + lr;
    int xx = threadIdx.x;
    const float* xb = x + (size_t)b*48*HW + (size_t)grow*256 + xx;
    float xr[48];
    #pragma unroll
    for (int c = 0; c < 48; ++c) xr[c] = xb[(size_t)c*HW];
    unsigned short* ub = u + (size_t)bi*254*uR*256 + (size_t)lr*256 + xx;
    size_t cs = (size_t)uR*256;
    int o0 = half*128, o1 = half ? 254 : 128;
    #pragma unroll 2
    for (int o = o0; o < o1; o += 2){
        float a0 = 0.f, a1 = 0.f;
        const float* w0 = wP + o*48;
        #pragma unroll
        for (int c = 0; c < 48; ++c){ a0 = fmaf(w0[c], xr[c], a0); a1 = fmaf(w0[48+c], xr[c], a1); }
        ub[(size_t)o*cs]     = f2bu(a0);
        ub[(size_t)(o+1)*cs] = f2bu(a1);
    }
}

// ---------------- K1b: depthwise 3x3 x2 + relu + partial channel-sum, chunked ----------------
__global__ __launch_bounds__(256) void k_dw(const unsigned short* __restrict__ u,
        const float* __restrict__ wD, unsigned short* __restrict__ t4, float* __restrict__ Sp,
        int tr0, int trows, int ur0, int urows, int uR, int tR, int nbat){
    int chunk = blockIdx.x & (NCH-1);
    int rb = blockIdx.x >> 3;
    int bi = rb / trows;
    int lr = rb - bi*trows;
    int grow = tr0 + lr;
    int xx = threadIdx.x;
    int c0 = chunk*32;
    int c1 = c0+32 < 254 ? c0+32 : 254;
    int lrow = grow - ur0;
    int lm = lrow-1 > 0 ? lrow-1 : 0;
    int lp = lrow+1 < urows-1 ? lrow+1 : urows-1;
    int xl = xx-1 > 0 ? xx-1 : 0;
    int xr_ = xx+1 < 255 ? xx+1 : 255;
    float mym = grow>0 ? 1.f:0.f, myp = grow<255 ? 1.f:0.f;
    float mxm = xx>0 ? 1.f:0.f,  mxp = xx<255 ? 1.f:0.f;
    float m[9] = { mym*mxm, mym, mym*mxp,  mxm, 1.f, mxp,  myp*mxm, myp, myp*mxp };
    int off[9] = { lm*256+xl, lm*256+xx, lm*256+xr_,
                   lrow*256+xl, lrow*256+xx, lrow*256+xr_,
                   lp*256+xl, lp*256+xx, lp*256+xr_ };
    const unsigned short* ub = u + (size_t)bi*254*uR*256;
    unsigned short* tb = t4 + (size_t)bi*127*tR*256*4 + ((size_t)lr*256 + xx)*4;
    size_t tcs = (size_t)tR*256*4;
    size_t ucs = (size_t)uR*256;
    float ssum = 0.f;
    for (int c = c0; c < c1; c += 2){
        const unsigned short* up0 = ub + (size_t)c*ucs;
        const unsigned short* up1 = up0 + ucs;
        unsigned short r0[9], r1[9];
        #pragma unroll
        for (int q = 0; q < 9; ++q){ r0[q] = up0[off[q]]; r1[q] = up1[off[q]]; }
        float v0[9], v1[9];
        #pragma unroll
        for (int q = 0; q < 9; ++q){ v0[q] = bfu(r0[q])*m[q]; v1[q] = bfu(r1[q])*m[q]; }
        const float* w0 = wD + (size_t)(2*c)*9;
        float t0=0.f, t1=0.f, t2=0.f, t3=0.f;
        #pragma unroll
        for (int q = 0; q < 9; ++q){
            t0 = fmaf(w0[q],    v0[q], t0);
            t1 = fmaf(w0[9+q],  v0[q], t1);
            t2 = fmaf(w0[18+q], v1[q], t2);
            t3 = fmaf(w0[27+q], v1[q], t3);
        }
        t0 = fmaxf(t0,0.f); t1 = fmaxf(t1,0.f); t2 = fmaxf(t2,0.f); t3 = fmaxf(t3,0.f);
        ssum += (t0+t1) + (t2+t3);
        ushort4 st; st.x=f2bu(t0); st.y=f2bu(t1); st.z=f2bu(t2); st.w=f2bu(t3);
        *reinterpret_cast<ushort4*>(tb + (size_t)(c>>1)*tcs) = st;
    }
    Sp[((size_t)(chunk*nbat + bi)*tR + lr)*256 + xx] = ssum * (1.f/9.f);
}

// ---------------- K2: sum chunks + 3x3 box with edge clamp ----------------
__global__ __launch_bounds__(256) void k_box(const float* __restrict__ Sp, float* __restrict__ Lm,
        int lr0, int lrows, int tr0, int tR, int lR, int nbat){
    int bi = blockIdx.x / lrows;
    int lr = blockIdx.x - bi*lrows;
    int grow = lr0 + lr;
    int xx = threadIdx.x;
    int g0 = (grow-1 > 0 ? grow-1 : 0) - tr0, g1 = grow - tr0, g2 = (grow+1 < 255 ? grow+1 : 255) - tr0;
    int x0 = xx-1 > 0 ? xx-1 : 0, x2 = xx+1 < 255 ? xx+1 : 255;
    float s = 0.f;
    for (int ch = 0; ch < NCH; ++ch){
        const float* Sb = Sp + ((size_t)(ch*nbat + bi)*tR)*256;
        s += Sb[g0*256+x0]+Sb[g0*256+xx]+Sb[g0*256+x2]
           + Sb[g1*256+x0]+Sb[g1*256+xx]+Sb[g1*256+x2]
           + Sb[g2*256+x0]+Sb[g2*256+xx]+Sb[g2*256+x2];
    }
    Lm[(size_t)bi*lR*256 + (size_t)lr*256 + xx] = s;
}

// ---------------- K3: h-path g1x1 + relu + shuffle + g1x1 -> h2 ----------------
__global__ __launch_bounds__(256) void k_mix(const unsigned short* __restrict__ t4,
        const float* __restrict__ Lm, const float* __restrict__ whp1, const float* __restrict__ whp2,
        const float* __restrict__ ahp1, unsigned short* __restrict__ h2,
        int lr0, int lrows, int tr0, int tR, int lR){
    int bi = blockIdx.x / lrows;
    int lr = blockIdx.x - bi*lrows;
    int grow = lr0 + lr;
    int xx = threadIdx.x;
    const unsigned short* tb = t4 + (size_t)bi*127*tR*256*4 + ((size_t)(grow-tr0)*256 + xx)*4;
    size_t tcs = (size_t)tR*256*4;
    unsigned short* hb = h2 + (size_t)bi*127*lR*256*4 + ((size_t)lr*256 + xx)*4;
    size_t hcs = (size_t)lR*256*4;
    float Lv = Lm[(size_t)bi*lR*256 + (size_t)lr*256 + xx];
    #pragma unroll 2
    for (int g = 0; g < 127; ++g){
        int idx0 = 4*g;
        ushort4 raw[4];
        #pragma unroll
        for (int k = 0; k < 4; ++k){
            int idx = idx0 + k;
            int oi = idx/127;
            int gi = idx - oi*127;
            raw[k] = *reinterpret_cast<const ushort4*>(tb + (size_t)gi*tcs);
        }
        float a0=0.f,a1=0.f,a2=0.f,a3=0.f;
        const float* w2 = whp2 + g*16;
        #pragma unroll
        for (int k = 0; k < 4; ++k){
            int idx = idx0 + k;
            int oi = idx/127;
            int gi = idx - oi*127;
            const float* w1 = whp1 + gi*16 + oi*4;
            float h1 = fmaf(w1[0], bfu(raw[k].x), fmaf(w1[1], bfu(raw[k].y),
                       fmaf(w1[2], bfu(raw[k].z), w1[3]*bfu(raw[k].w))));
            h1 = fmaxf(fmaf(-Lv, ahp1[gi*4+oi], h1), 0.f);
            a0 = fmaf(w2[k],    h1, a0);
            a1 = fmaf(w2[4+k],  h1, a1);
            a2 = fmaf(w2[8+k],  h1, a2);
            a3 = fmaf(w2[12+k], h1, a3);
        }
        ushort4 st; st.x=f2bu(a0); st.y=f2bu(a1); st.z=f2bu(a2); st.w=f2bu(a3);
        *reinterpret_cast<ushort4*>(hb + (size_t)g*hcs) = st;
    }
}

// ---------------- K4: grouped 3x3 + relu + 1x1 out + residual ----------------
__global__ __launch_bounds__(256) void k_out(const unsigned short* __restrict__ h2,
     const float* __restrict__ Lm, const float* __restrict__ x,
     const float* __restrict__ WLP, const float* __restrict__ WLN,
     const float* __restrict__ WHP, const float* __restrict__ WHN,
     const float* __restrict__ WLD2, const float* __restrict__ WHD2,
     const float* __restrict__ woutT, float* __restrict__ out,
     int b0, int a, int orows, int lr0, int lR){
    int bi = blockIdx.x / orows;
    int lr = blockIdx.x - bi*orows;
    int b = b0 + bi;
    int grow = a + lr;
    int xx = threadIdx.x;
    const float* Lb = Lm + (size_t)bi*lR*256;
    float Lq[9], vm[9]; int hoff[9];
    #pragma unroll
    for (int q = 0; q < 9; ++q){
        int dy = q/3 - 1, dx = q%3 - 1;
        int yy = grow+dy, xc = xx+dx;
        bool v = (yy>=0)&&(yy<256)&&(xc>=0)&&(xc<256);
        vm[q] = v ? 1.f : 0.f;
        int o = v ? ((yy-lr0)*256 + xc) : ((grow-lr0)*256 + xx);
        hoff[q] = o;
        Lq[q] = v ? Lb[o] : 0.f;
    }
    float acc[48];
    const float* xb = x + (size_t)b*48*HW + (size_t)grow*256 + xx;
    #pragma unroll
    for (int o = 0; o < 48; ++o) acc[o] = xb[(size_t)o*HW];
    const unsigned short* hb = h2 + (size_t)bi*127*lR*256*4;
    size_t hcs = (size_t)lR*256*4;

    for (int g = 0; g < 127; ++g){
        float sl = 0.f, sh = 0.f;
        #pragma unroll
        for (int q = 0; q < 9; ++q){
            float lq = Lq[q];
            bool pos = lq > 0.f;
            float cl  = pos ? WLP[g*9+q] : WLN[g*9+q];
            float chh = pos ? WHP[g*9+q] : WHN[g*9+q];
            sl = fmaf(cl, lq, sl);
            sh = fmaf(chh, lq, sh);
        }
        const unsigned short* hq = hb + (size_t)g*hcs;
        if (g >= 63){   // l-branch h2-sourced channels (4g+i >= 254)
            const float* w = WLD2 + g*36;
            ushort4 r[9];
            #pragma unroll
            for (int q = 0; q < 9; ++q) r[q] = *reinterpret_cast<const ushort4*>(hq + (size_t)hoff[q]*4);
            #pragma unroll
            for (int q = 0; q < 9; ++q){
                float tv = fmaf(w[0*9+q], bfu(r[q].x), fmaf(w[1*9+q], bfu(r[q].y),
                           fmaf(w[2*9+q], bfu(r[q].z), w[3*9+q]*bfu(r[q].w))));
                sl = fmaf(vm[q], tv, sl);
            }
        }
        if (g <= 63){   // h-branch h2-sourced channels (4g+i < 254)
            const float* w = WHD2 + g*36;
            ushort4 r[9];
            #pragma unroll
            for (int q = 0; q < 9; ++q) r[q] = *reinterpret_cast<const ushort4*>(hq + (size_t)hoff[q]*4);
            #pragma unroll
            for (int q = 0; q < 9; ++q){
                float tv = fmaf(w[0*9+q], bfu(r[q].x), fmaf(w[1*9+q], bfu(r[q].y),
                           fmaf(w[2*9+q], bfu(r[q].z), w[3*9+q]*bfu(r[q].w))));
                sh = fmaf(vm[q], tv, sh);
            }
        }
        float vl = fmaxf(sl, 0.f), vh = fmaxf(sh, 0.f);
        const float* wt  = woutT + g*48;
        const float* wt2 = woutT + (127+g)*48;
        #pragma unroll
        for (int o = 0; o < 48; ++o) acc[o] = fmaf(wt[o], vl, fmaf(wt2[o], vh, acc[o]));
    }
    float* ob = out + (size_t)b*48*HW + (size_t)grow*256 + xx;
    #pragma unroll
    for (int o = 0; o < 48; ++o) ob[(size_t)o*HW] = acc[o];
}

extern "C" void kernel_launch(void* const* d_in, const int* in_sizes, int n_in,
                              void* d_out, int out_size, void* d_ws, size_t ws_size,
                              hipStream_t stream){
    const float* x    = (const float*)d_in[0];
    const float* winP = (const float*)d_in[1];
    const float* winD = (const float*)d_in[2];
    const float* wlp1 = (const float*)d_in[3];
    const float* whp1 = (const float*)d_in[4];
    const float* wlp2 = (const float*)d_in[5];
    const float* whp2 = (const float*)d_in[6];
    const float* wld  = (const float*)d_in[7];
    const float* whd  = (const float*)d_in[8];
    const float* wout = (const float*)d_in[9];
    float* out = (float*)d_out;

    char* ws = (char*)d_ws;
    size_t off = 0;
    auto alloc = [&](size_t bytes)->char*{
        char* pp = ws + off; off += (bytes + 255) & ~(size_t)255; return pp;
    };
    auto A = [](size_t bytes)->size_t{ return (bytes + 255) & ~(size_t)255; };

    float* ahp1 = (float*)alloc(508*4);
    float* WLP  = (float*)alloc(127*9*4);
    float* WLN  = (float*)alloc(127*9*4);
    float* WHP  = (float*)alloc(127*9*4);
    float* WHN  = (float*)alloc(127*9*4);
    float* WLD2 = (float*)alloc(127*36*4);
    float* WHD2 = (float*)alloc(127*36*4);
    float* woutT= (float*)alloc(48*254*4);

    const int cfgs[7][2] = {{256,2},{128,2},{64,2},{64,1},{32,1},{16,1},{8,1}};
    int Hb = 8, nbat = 1;
    for (int ci = 0; ci < 7; ++ci){
        int hb = cfgs[ci][0], nb = cfgs[ci][1];
        int uR = hb+6 < 256 ? hb+6 : 256;
        int tR = hb+4 < 256 ? hb+4 : 256;
        int lR = hb+2 < 256 ? hb+2 : 256;
        size_t need = off;
        need += A((size_t)nb*254*uR*256*2);
        need += A((size_t)nb*127*tR*256*4*2);
        need += A((size_t)nb*127*lR*256*4*2);
        need += A((size_t)nb*NCH*tR*256*4);
        need += A((size_t)nb*lR*256*4);
        if (need <= ws_size){ Hb = hb; nbat = nb; break; }
    }
    int uR = Hb+6 < 256 ? Hb+6 : 256;
    int tR = Hb+4 < 256 ? Hb+4 : 256;
    int lR = Hb+2 < 256 ? Hb+2 : 256;
    unsigned short* u  = (unsigned short*)alloc((size_t)nbat*254*uR*256*2);
    unsigned short* t4 = (unsigned short*)alloc((size_t)nbat*127*tR*256*4*2);
    unsigned short* h2 = (unsigned short*)alloc((size_t)nbat*127*lR*256*4*2);
    float* Sp = (float*)alloc((size_t)nbat*NCH*tR*256*4);
    float* Lm = (float*)alloc((size_t)nbat*lR*256*4);

    k_coef<<<1, 512, 0, stream>>>(wlp1, whp1, wlp2, wld, whd, wout,
                                  ahp1, WLP, WLN, WHP, WHN, WLD2, WHD2, woutT);

    for (int b0 = 0; b0 < 2; b0 += nbat){
        for (int a = 0; a < 256; a += Hb){
            int ur0 = a-3 > 0 ? a-3 : 0;  int ur1 = a+Hb+3 < 256 ? a+Hb+3 : 256;
            int tr0 = a-2 > 0 ? a-2 : 0;  int tr1 = a+Hb+2 < 256 ? a+Hb+2 : 256;
            int lr0 = a-1 > 0 ? a-1 : 0;  int lr1 = a+Hb+1 < 256 ? a+Hb+1 : 256;
            int urows = ur1-ur0, trows = tr1-tr0, lrows = lr1-lr0;
            int orows = (a+Hb < 256 ? a+Hb : 256) - a;
            k_pconv<<<nbat*urows*2, 256, 0, stream>>>(x, winP, u, b0, ur0, urows, uR);
            k_dw  <<<nbat*trows*NCH, 256, 0, stream>>>(u, winD, t4, Sp, tr0, trows, ur0, urows, uR, tR, nbat);
            k_box <<<nbat*lrows, 256, 0, stream>>>(Sp, Lm, lr0, lrows, tr0, tR, lR, nbat);
            k_mix <<<nbat*lrows, 256, 0, stream>>>(t4, Lm, whp1, whp2, ahp1, h2, lr0, lrows, tr0, tR, lR);
            k_out <<<nbat*orows, 256, 0, stream>>>(h2, Lm, x, WLP, WLN, WHP, WHN, WLD2, WHD2,
                                                   woutT, out, b0, a, orows, lr0, lR);
        }
    }
}

// Round 4
// 637.938 us; speedup vs baseline: 3.1079x; 1.2798x over previous
//
#include <hip/hip_runtime.h>
#include <hip/hip_bf16.h>

#define HW 65536
#define NCH 8   // channel chunks in k_dw

__device__ __forceinline__ float bfu(unsigned short u){
    return __uint_as_float(((unsigned int)u) << 16);
}
__device__ __forceinline__ unsigned short f2bu(float f){
    unsigned int u = __float_as_uint(f);
    unsigned int r = (u + 0x7fffu + ((u >> 16) & 1u)) >> 16;
    return (unsigned short)r;
}

// ---------------- K0: precompute coefficient tables ----------------
__global__ void k_coef(const float* __restrict__ wlp1, const float* __restrict__ whp1,
                       const float* __restrict__ wlp2,
                       const float* __restrict__ wld, const float* __restrict__ whd,
                       const float* __restrict__ wout,
                       float* __restrict__ ahp1,
                       float* __restrict__ WLP, float* __restrict__ WLN,
                       float* __restrict__ WHP, float* __restrict__ WHN,
                       float* __restrict__ WLD2, float* __restrict__ WHD2,
                       float* __restrict__ woutT){
    __shared__ float aL[508], cp[508], cn[508];
    int t = threadIdx.x;
    if (t < 508){
        int g = t >> 2, o = t & 3;
        float s = 0.f, s2 = 0.f;
        for (int i = 0; i < 4; ++i){ s += wlp1[g*16 + o*4 + i]; s2 += whp1[g*16 + o*4 + i]; }
        aL[t] = s; ahp1[t] = s2;
    }
    __syncthreads();
    if (t < 508){
        int g = t >> 2, o = t & 3;
        float p = 0.f, n = 0.f;
        for (int k = 0; k < 4; ++k){
            int idx = 4*g + k;                    // shuffled position
            int inv = (idx % 127)*4 + idx/127;    // original channel
            float av = aL[inv];
            float w2 = wlp2[g*16 + o*4 + k];
            p += w2 * fmaxf(av, 0.f);
            n += w2 * fminf(av, 0.f);
        }
        cp[t] = p; cn[t] = n;
    }
    __syncthreads();
    for (int idx = t; idx < 127*9; idx += blockDim.x){
        int g = idx/9, q = idx%9;
        float lp=0.f, ln=0.f, hp=0.f, hn=0.f;
        for (int i = 0; i < 4; ++i){
            int ch = 4*g + i;
            if (ch < 254){ float w = wld[g*36 + i*9 + q]; lp += w*cp[ch]; ln += w*cn[ch]; }
            else         { float w = whd[g*36 + i*9 + q]; hp += w*cp[ch]; hn += w*cn[ch]; }
        }
        WLP[idx]=lp; WLN[idx]=ln; WHP[idx]=hp; WHN[idx]=hn;
    }
    for (int idx = t; idx < 127*36; idx += blockDim.x){
        int g = idx/36, r = idx%36; int i = r/9;
        int ch = 4*g + i;
        WLD2[idx] = (ch >= 254) ? wld[idx] : 0.f;
        WHD2[idx] = (ch <  254) ? whd[idx] : 0.f;
    }
    for (int idx = t; idx < 48*254; idx += blockDim.x){
        int c = idx/48, o = idx%48;
        woutT[idx] = wout[o*254 + c];
    }
}

// ---------------- K1a: u = w_inP @ x (1x1 48->254), banded, 4 o-chunks ----------------
__global__ __launch_bounds__(256) void k_pconv(const float* __restrict__ x,
        const float* __restrict__ wP, unsigned short* __restrict__ u,
        int b0, int ur0, int urows, int uR){
    int chunk = blockIdx.x & 3;
    int t = blockIdx.x >> 2;
    int bi = t / urows;
    int lr = t - bi*urows;
    int b = b0 + bi;
    int grow = ur0 + lr;
    int xx = threadIdx.x;
    const float* xb = x + (size_t)b*48*HW + (size_t)grow*256 + xx;
    float xr[48];
    #pragma unroll
    for (int c = 0; c < 48; ++c) xr[c] = xb[(size_t)c*HW];
    unsigned short* ub = u + (size_t)bi*254*uR*256 + (size_t)lr*256 + xx;
    size_t cs = (size_t)uR*256;
    int o0 = chunk*64, o1 = o0+64 < 254 ? o0+64 : 254;
    #pragma unroll 2
    for (int o = o0; o < o1; o += 2){
        float a0 = 0.f, a1 = 0.f;
        const float* w0 = wP + o*48;
        #pragma unroll
        for (int c = 0; c < 48; ++c){ a0 = fmaf(w0[c], xr[c], a0); a1 = fmaf(w0[48+c], xr[c], a1); }
        ub[(size_t)o*cs]     = f2bu(a0);
        ub[(size_t)(o+1)*cs] = f2bu(a1);
    }
}

// ---------------- K1b: depthwise 3x3 x2 + relu + partial channel-sum, chunked ----------------
__global__ __launch_bounds__(256) void k_dw(const unsigned short* __restrict__ u,
        const float* __restrict__ wD, unsigned short* __restrict__ t4, float* __restrict__ Sp,
        int tr0, int trows, int ur0, int urows, int uR, int tR, int nbat){
    int chunk = blockIdx.x & (NCH-1);
    int rb = blockIdx.x >> 3;
    int bi = rb / trows;
    int lr = rb - bi*trows;
    int grow = tr0 + lr;
    int xx = threadIdx.x;
    int c0 = chunk*32;
    int c1 = c0+32 < 254 ? c0+32 : 254;
    int lrow = grow - ur0;
    int lm = lrow-1 > 0 ? lrow-1 : 0;
    int lp = lrow+1 < urows-1 ? lrow+1 : urows-1;
    int xl = xx-1 > 0 ? xx-1 : 0;
    int xr_ = xx+1 < 255 ? xx+1 : 255;
    float mym = grow>0 ? 1.f:0.f, myp = grow<255 ? 1.f:0.f;
    float mxm = xx>0 ? 1.f:0.f,  mxp = xx<255 ? 1.f:0.f;
    float m[9] = { mym*mxm, mym, mym*mxp,  mxm, 1.f, mxp,  myp*mxm, myp, myp*mxp };
    int off[9] = { lm*256+xl, lm*256+xx, lm*256+xr_,
                   lrow*256+xl, lrow*256+xx, lrow*256+xr_,
                   lp*256+xl, lp*256+xx, lp*256+xr_ };
    const unsigned short* ub = u + (size_t)bi*254*uR*256;
    unsigned short* tb = t4 + (size_t)bi*127*tR*256*4 + ((size_t)lr*256 + xx)*4;
    size_t tcs = (size_t)tR*256*4;
    size_t ucs = (size_t)uR*256;
    float ssum = 0.f;
    for (int c = c0; c < c1; c += 2){
        const unsigned short* up0 = ub + (size_t)c*ucs;
        const unsigned short* up1 = up0 + ucs;
        unsigned short r0[9], r1[9];
        #pragma unroll
        for (int q = 0; q < 9; ++q){ r0[q] = up0[off[q]]; r1[q] = up1[off[q]]; }
        float v0[9], v1[9];
        #pragma unroll
        for (int q = 0; q < 9; ++q){ v0[q] = bfu(r0[q])*m[q]; v1[q] = bfu(r1[q])*m[q]; }
        const float* w0 = wD + (size_t)(2*c)*9;
        float t0=0.f, t1=0.f, t2=0.f, t3=0.f;
        #pragma unroll
        for (int q = 0; q < 9; ++q){
            t0 = fmaf(w0[q],    v0[q], t0);
            t1 = fmaf(w0[9+q],  v0[q], t1);
            t2 = fmaf(w0[18+q], v1[q], t2);
            t3 = fmaf(w0[27+q], v1[q], t3);
        }
        t0 = fmaxf(t0,0.f); t1 = fmaxf(t1,0.f); t2 = fmaxf(t2,0.f); t3 = fmaxf(t3,0.f);
        ssum += (t0+t1) + (t2+t3);
        ushort4 st; st.x=f2bu(t0); st.y=f2bu(t1); st.z=f2bu(t2); st.w=f2bu(t3);
        *reinterpret_cast<ushort4*>(tb + (size_t)(c>>1)*tcs) = st;
    }
    Sp[((size_t)(chunk*nbat + bi)*tR + lr)*256 + xx] = ssum * (1.f/9.f);
}

// ---------------- K2: sum chunks + 3x3 box with edge clamp ----------------
__global__ __launch_bounds__(256) void k_box(const float* __restrict__ Sp, float* __restrict__ Lm,
        int lr0, int lrows, int tr0, int tR, int lR, int nbat){
    int bi = blockIdx.x / lrows;
    int lr = blockIdx.x - bi*lrows;
    int grow = lr0 + lr;
    int xx = threadIdx.x;
    int g0 = (grow-1 > 0 ? grow-1 : 0) - tr0, g1 = grow - tr0, g2 = (grow+1 < 255 ? grow+1 : 255) - tr0;
    int x0 = xx-1 > 0 ? xx-1 : 0, x2 = xx+1 < 255 ? xx+1 : 255;
    float s = 0.f;
    for (int ch = 0; ch < NCH; ++ch){
        const float* Sb = Sp + ((size_t)(ch*nbat + bi)*tR)*256;
        s += Sb[g0*256+x0]+Sb[g0*256+xx]+Sb[g0*256+x2]
           + Sb[g1*256+x0]+Sb[g1*256+xx]+Sb[g1*256+x2]
           + Sb[g2*256+x0]+Sb[g2*256+xx]+Sb[g2*256+x2];
    }
    Lm[(size_t)bi*lR*256 + (size_t)lr*256 + xx] = s;
}

// ---------------- K3: h-path g1x1 + relu + shuffle + g1x1 -> h2, 4 g-chunks ----------------
__global__ __launch_bounds__(256) void k_mix(const unsigned short* __restrict__ t4,
        const float* __restrict__ Lm, const float* __restrict__ whp1, const float* __restrict__ whp2,
        const float* __restrict__ ahp1, unsigned short* __restrict__ h2,
        int lr0, int lrows, int tr0, int tR, int lR){
    int chunk = blockIdx.x & 3;
    int rb = blockIdx.x >> 2;
    int bi = rb / lrows;
    int lr = rb - bi*lrows;
    int grow = lr0 + lr;
    int xx = threadIdx.x;
    const unsigned short* tb = t4 + (size_t)bi*127*tR*256*4 + ((size_t)(grow-tr0)*256 + xx)*4;
    size_t tcs = (size_t)tR*256*4;
    unsigned short* hb = h2 + (size_t)bi*127*lR*256*4 + ((size_t)lr*256 + xx)*4;
    size_t hcs = (size_t)lR*256*4;
    float Lv = Lm[(size_t)bi*lR*256 + (size_t)lr*256 + xx];
    int g0 = chunk*32, gend = g0+32 < 127 ? g0+32 : 127;
    #pragma unroll 2
    for (int g = g0; g < gend; ++g){
        int idx0 = 4*g;
        ushort4 raw[4];
        #pragma unroll
        for (int k = 0; k < 4; ++k){
            int idx = idx0 + k;
            int oi = idx/127;
            int gi = idx - oi*127;
            raw[k] = *reinterpret_cast<const ushort4*>(tb + (size_t)gi*tcs);
        }
        float a0=0.f,a1=0.f,a2=0.f,a3=0.f;
        const float* w2 = whp2 + g*16;
        #pragma unroll
        for (int k = 0; k < 4; ++k){
            int idx = idx0 + k;
            int oi = idx/127;
            int gi = idx - oi*127;
            const float* w1 = whp1 + gi*16 + oi*4;
            float h1 = fmaf(w1[0], bfu(raw[k].x), fmaf(w1[1], bfu(raw[k].y),
                       fmaf(w1[2], bfu(raw[k].z), w1[3]*bfu(raw[k].w))));
            h1 = fmaxf(fmaf(-Lv, ahp1[gi*4+oi], h1), 0.f);
            a0 = fmaf(w2[k],    h1, a0);
            a1 = fmaf(w2[4+k],  h1, a1);
            a2 = fmaf(w2[8+k],  h1, a2);
            a3 = fmaf(w2[12+k], h1, a3);
        }
        ushort4 st; st.x=f2bu(a0); st.y=f2bu(a1); st.z=f2bu(a2); st.w=f2bu(a3);
        *reinterpret_cast<ushort4*>(hb + (size_t)g*hcs) = st;
    }
}

// ---------------- K4a: grouped 3x3 + relu + partial 1x1 out (4 g-chunks, f32 partials) ----------------
__global__ __launch_bounds__(256) void k_outp(const unsigned short* __restrict__ h2,
     const float* __restrict__ Lm,
     const float* __restrict__ WLP, const float* __restrict__ WLN,
     const float* __restrict__ WHP, const float* __restrict__ WHN,
     const float* __restrict__ WLD2, const float* __restrict__ WHD2,
     const float* __restrict__ woutT, float* __restrict__ part,
     int a, int orows, int lr0, int lR, int nbat){
    int chunk = blockIdx.x & 3;
    int rb = blockIdx.x >> 2;
    int bi = rb / orows;
    int lr = rb - bi*orows;
    int grow = a + lr;
    int xx = threadIdx.x;
    const float* Lb = Lm + (size_t)bi*lR*256;
    float Lq[9], vm[9]; int hoff[9];
    #pragma unroll
    for (int q = 0; q < 9; ++q){
        int dy = q/3 - 1, dx = q%3 - 1;
        int yy = grow+dy, xc = xx+dx;
        bool v = (yy>=0)&&(yy<256)&&(xc>=0)&&(xc<256);
        vm[q] = v ? 1.f : 0.f;
        int o = v ? ((yy-lr0)*256 + xc) : ((grow-lr0)*256 + xx);
        hoff[q] = o;
        Lq[q] = v ? Lb[o] : 0.f;
    }
    float acc[48];
    #pragma unroll
    for (int o = 0; o < 48; ++o) acc[o] = 0.f;
    const unsigned short* hb = h2 + (size_t)bi*127*lR*256*4;
    size_t hcs = (size_t)lR*256*4;
    int g0 = chunk*32, gend = g0+32 < 127 ? g0+32 : 127;

    for (int g = g0; g < gend; ++g){
        float sl = 0.f, sh = 0.f;
        #pragma unroll
        for (int q = 0; q < 9; ++q){
            float lq = Lq[q];
            bool pos = lq > 0.f;
            float cl  = pos ? WLP[g*9+q] : WLN[g*9+q];
            float chh = pos ? WHP[g*9+q] : WHN[g*9+q];
            sl = fmaf(cl, lq, sl);
            sh = fmaf(chh, lq, sh);
        }
        const unsigned short* hq = hb + (size_t)g*hcs;
        ushort4 r[9];
        #pragma unroll
        for (int q = 0; q < 9; ++q) r[q] = *reinterpret_cast<const ushort4*>(hq + (size_t)hoff[q]*4);
        if (g >= 63){   // l-branch h2-sourced channels (4g+i >= 254)
            const float* w = WLD2 + g*36;
            #pragma unroll
            for (int q = 0; q < 9; ++q){
                float tv = fmaf(w[0*9+q], bfu(r[q].x), fmaf(w[1*9+q], bfu(r[q].y),
                           fmaf(w[2*9+q], bfu(r[q].z), w[3*9+q]*bfu(r[q].w))));
                sl = fmaf(vm[q], tv, sl);
            }
        }
        if (g <= 63){   // h-branch h2-sourced channels (4g+i < 254)
            const float* w = WHD2 + g*36;
            #pragma unroll
            for (int q = 0; q < 9; ++q){
                float tv = fmaf(w[0*9+q], bfu(r[q].x), fmaf(w[1*9+q], bfu(r[q].y),
                           fmaf(w[2*9+q], bfu(r[q].z), w[3*9+q]*bfu(r[q].w))));
                sh = fmaf(vm[q], tv, sh);
            }
        }
        float vl = fmaxf(sl, 0.f), vh = fmaxf(sh, 0.f);
        const float* wt  = woutT + g*48;
        const float* wt2 = woutT + (127+g)*48;
        #pragma unroll
        for (int o = 0; o < 48; ++o) acc[o] = fmaf(wt[o], vl, fmaf(wt2[o], vh, acc[o]));
    }
    float* pb = part + ((size_t)(chunk*nbat + bi)*48)*orows*256 + (size_t)lr*256 + xx;
    size_t ps = (size_t)orows*256;
    #pragma unroll
    for (int o = 0; o < 48; ++o) pb[(size_t)o*ps] = acc[o];
}

// ---------------- K4b: reduce partials + residual -> out ----------------
__global__ __launch_bounds__(256) void k_red(const float* __restrict__ part,
     const float* __restrict__ x, float* __restrict__ out,
     int b0, int a, int orows, int nbat){
    int oc = blockIdx.x % 6;
    int rb = blockIdx.x / 6;
    int bi = rb / orows;
    int lr = rb - bi*orows;
    int b = b0 + bi;
    int grow = a + lr;
    int xx = threadIdx.x;
    size_t ps = (size_t)orows*256;
    size_t pix = (size_t)lr*256 + xx;
    const float* xb = x + (size_t)b*48*HW + (size_t)grow*256 + xx;
    float* ob = out + (size_t)b*48*HW + (size_t)grow*256 + xx;
    #pragma unroll
    for (int j = 0; j < 8; ++j){
        int o = oc*8 + j;
        float v = xb[(size_t)o*HW];
        #pragma unroll
        for (int c = 0; c < 4; ++c)
            v += part[((size_t)(c*nbat + bi)*48 + o)*ps + pix];
        ob[(size_t)o*HW] = v;
    }
}

extern "C" void kernel_launch(void* const* d_in, const int* in_sizes, int n_in,
                              void* d_out, int out_size, void* d_ws, size_t ws_size,
                              hipStream_t stream){
    const float* x    = (const float*)d_in[0];
    const float* winP = (const float*)d_in[1];
    const float* winD = (const float*)d_in[2];
    const float* wlp1 = (const float*)d_in[3];
    const float* whp1 = (const float*)d_in[4];
    const float* wlp2 = (const float*)d_in[5];
    const float* whp2 = (const float*)d_in[6];
    const float* wld  = (const float*)d_in[7];
    const float* whd  = (const float*)d_in[8];
    const float* wout = (const float*)d_in[9];
    float* out = (float*)d_out;

    char* ws = (char*)d_ws;
    size_t off = 0;
    auto alloc = [&](size_t bytes)->char*{
        char* pp = ws + off; off += (bytes + 255) & ~(size_t)255; return pp;
    };
    auto A = [](size_t bytes)->size_t{ return (bytes + 255) & ~(size_t)255; };

    float* ahp1 = (float*)alloc(508*4);
    float* WLP  = (float*)alloc(127*9*4);
    float* WLN  = (float*)alloc(127*9*4);
    float* WHP  = (float*)alloc(127*9*4);
    float* WHN  = (float*)alloc(127*9*4);
    float* WLD2 = (float*)alloc(127*36*4);
    float* WHD2 = (float*)alloc(127*36*4);
    float* woutT= (float*)alloc(48*254*4);

    const int cfgs[7][2] = {{256,2},{128,2},{64,2},{64,1},{32,1},{16,1},{8,1}};
    int Hb = 8, nbat = 1;
    for (int ci = 0; ci < 7; ++ci){
        int hb = cfgs[ci][0], nb = cfgs[ci][1];
        int uR = hb+6 < 256 ? hb+6 : 256;
        int tR = hb+4 < 256 ? hb+4 : 256;
        int lR = hb+2 < 256 ? hb+2 : 256;
        size_t need = off;
        need += A((size_t)nb*254*uR*256*2);
        need += A((size_t)nb*127*tR*256*4*2);
        need += A((size_t)nb*127*lR*256*4*2);
        need += A((size_t)nb*NCH*tR*256*4);
        need += A((size_t)nb*lR*256*4);
        if (need <= ws_size){ Hb = hb; nbat = nb; break; }
    }
    int uR = Hb+6 < 256 ? Hb+6 : 256;
    int tR = Hb+4 < 256 ? Hb+4 : 256;
    int lR = Hb+2 < 256 ? Hb+2 : 256;
    unsigned short* u  = (unsigned short*)alloc((size_t)nbat*254*uR*256*2);
    unsigned short* t4 = (unsigned short*)alloc((size_t)nbat*127*tR*256*4*2);
    unsigned short* h2 = (unsigned short*)alloc((size_t)nbat*127*lR*256*4*2);
    float* Sp = (float*)alloc((size_t)nbat*NCH*tR*256*4);
    float* Lm = (float*)alloc((size_t)nbat*lR*256*4);
    // partials alias t4: t4 is dead once k_mix has produced h2, and k_outp
    // runs after k_mix on the same stream. size check: 4*nbat*48*Hb*256*4
    // <= nbat*127*(Hb+4)*256*8 for all configs.
    float* part = (float*)t4;

    k_coef<<<1, 512, 0, stream>>>(wlp1, whp1, wlp2, wld, whd, wout,
                                  ahp1, WLP, WLN, WHP, WHN, WLD2, WHD2, woutT);

    for (int b0 = 0; b0 < 2; b0 += nbat){
        for (int a = 0; a < 256; a += Hb){
            int ur0 = a-3 > 0 ? a-3 : 0;  int ur1 = a+Hb+3 < 256 ? a+Hb+3 : 256;
            int tr0 = a-2 > 0 ? a-2 : 0;  int tr1 = a+Hb+2 < 256 ? a+Hb+2 : 256;
            int lr0 = a-1 > 0 ? a-1 : 0;  int lr1 = a+Hb+1 < 256 ? a+Hb+1 : 256;
            int urows = ur1-ur0, trows = tr1-tr0, lrows = lr1-lr0;
            int orows = (a+Hb < 256 ? a+Hb : 256) - a;
            k_pconv<<<nbat*urows*4, 256, 0, stream>>>(x, winP, u, b0, ur0, urows, uR);
            k_dw  <<<nbat*trows*NCH, 256, 0, stream>>>(u, winD, t4, Sp, tr0, trows, ur0, urows, uR, tR, nbat);
            k_box <<<nbat*lrows, 256, 0, stream>>>(Sp, Lm, lr0, lrows, tr0, tR, lR, nbat);
            k_mix <<<nbat*lrows*4, 256, 0, stream>>>(t4, Lm, whp1, whp2, ahp1, h2, lr0, lrows, tr0, tR, lR);
            k_outp<<<nbat*orows*4, 256, 0, stream>>>(h2, Lm, WLP, WLN, WHP, WHN, WLD2, WHD2,
                                                     woutT, part, a, orows, lr0, lR, nbat);
            k_red <<<nbat*orows*6, 256, 0, stream>>>(part, x, out, b0, a, orows, nbat);
        }
    }
}

// Round 5
// 416.721 us; speedup vs baseline: 4.7578x; 1.5309x over previous
//
#include <hip/hip_runtime.h>
#include <hip/hip_bf16.h>

#define HW 65536
#define NCH 8   // channel chunks in k_dw

typedef __attribute__((ext_vector_type(8))) short bf16x8;
typedef __attribute__((ext_vector_type(4))) float f32x4;

__device__ __forceinline__ float bfu(unsigned short u){
    return __uint_as_float(((unsigned int)u) << 16);
}
__device__ __forceinline__ unsigned short f2bu(float f){
    unsigned int u = __float_as_uint(f);
    unsigned int r = (u + 0x7fffu + ((u >> 16) & 1u)) >> 16;
    return (unsigned short)r;
}

// ---------------- K0: precompute coefficient tables ----------------
__global__ void k_coef(const float* __restrict__ wlp1, const float* __restrict__ whp1,
                       const float* __restrict__ wlp2,
                       const float* __restrict__ wld, const float* __restrict__ whd,
                       const float* __restrict__ winP, const float* __restrict__ wout,
                       float* __restrict__ ahp1,
                       float* __restrict__ WLP, float* __restrict__ WLN,
                       float* __restrict__ WHP, float* __restrict__ WHN,
                       float* __restrict__ WLD2, float* __restrict__ WHD2,
                       unsigned short* __restrict__ WPb, unsigned short* __restrict__ BtP){
    __shared__ float aL[508], cp[508], cn[508];
    int t = threadIdx.x;
    if (t < 508){
        int g = t >> 2, o = t & 3;
        float s = 0.f, s2 = 0.f;
        for (int i = 0; i < 4; ++i){ s += wlp1[g*16 + o*4 + i]; s2 += whp1[g*16 + o*4 + i]; }
        aL[t] = s; ahp1[t] = s2;
    }
    __syncthreads();
    if (t < 508){
        int g = t >> 2, o = t & 3;
        float p = 0.f, n = 0.f;
        for (int k = 0; k < 4; ++k){
            int idx = 4*g + k;                    // shuffled position
            int inv = (idx % 127)*4 + idx/127;    // original channel
            float av = aL[inv];
            float w2 = wlp2[g*16 + o*4 + k];
            p += w2 * fmaxf(av, 0.f);
            n += w2 * fminf(av, 0.f);
        }
        cp[t] = p; cn[t] = n;
    }
    __syncthreads();
    for (int idx = t; idx < 127*9; idx += blockDim.x){
        int g = idx/9, q = idx%9;
        float lp=0.f, ln=0.f, hp=0.f, hn=0.f;
        for (int i = 0; i < 4; ++i){
            int ch = 4*g + i;
            if (ch < 254){ float w = wld[g*36 + i*9 + q]; lp += w*cp[ch]; ln += w*cn[ch]; }
            else         { float w = whd[g*36 + i*9 + q]; hp += w*cp[ch]; hn += w*cn[ch]; }
        }
        WLP[idx]=lp; WLN[idx]=ln; WHP[idx]=hp; WHN[idx]=hn;
    }
    for (int idx = t; idx < 127*36; idx += blockDim.x){
        int g = idx/36, r = idx%36; int i = r/9;
        int ch = 4*g + i;
        WLD2[idx] = (ch >= 254) ? wld[idx] : 0.f;
        WHD2[idx] = (ch <  254) ? whd[idx] : 0.f;
    }
    // WPb: [256 o][64 k] bf16, zero-padded winP
    for (int idx = t; idx < 256*64; idx += blockDim.x){
        int o = idx >> 6, k = idx & 63;
        float vv = (o < 254 && k < 48) ? winP[o*48 + k] : 0.f;
        WPb[idx] = f2bu(vv);
    }
    // BtP: [48 n][256 k] bf16; k=2g -> wout[n][g] (l-part), k=2g+1 -> wout[n][127+g] (h-part)
    for (int idx = t; idx < 48*256; idx += blockDim.x){
        int n = idx >> 8, k = idx & 255;
        int g = k >> 1;
        float vv = (g < 127) ? ((k & 1) ? wout[n*254 + 127 + g] : wout[n*254 + g]) : 0.f;
        BtP[idx] = f2bu(vv);
    }
}

// ---------------- K1a: u = w_inP @ x (1x1 48->254) via MFMA ----------------
// block = 64 px (quarter row), 4 waves x 16 px, 16 N-tiles each
__global__ __launch_bounds__(256) void k_pconv(const float* __restrict__ x,
        const unsigned short* __restrict__ WPb, unsigned short* __restrict__ u,
        int b0, int ur0, int urows, int uR){
    __shared__ unsigned short BtS[256*72];   // 36864 B; epilogue overlays [64px][258 u16]=33024 B
    int t = threadIdx.x;
    for (int i = t; i < 256*64; i += 256){
        int o = i >> 6, k = i & 63;
        BtS[o*72 + k] = WPb[i];
    }
    int bpb = urows*4;
    int bi = blockIdx.x / bpb;
    int r  = blockIdx.x - bi*bpb;
    int lr = r >> 2, quarter = r & 3;
    int b = b0 + bi;
    int grow = ur0 + lr;
    const float* xb = x + (size_t)b*48*HW + (size_t)grow*256 + quarter*64;
    int w = t >> 6, lane = t & 63;
    int px = w*16 + (lane & 15);
    int k0 = (lane >> 4)*8;
    bf16x8 afr[2];
    #pragma unroll
    for (int kk = 0; kk < 2; ++kk){
        #pragma unroll
        for (int j = 0; j < 8; ++j){
            int k = kk*32 + k0 + j;
            float vv = (k < 48) ? xb[(size_t)k*HW + px] : 0.f;
            afr[kk][j] = (short)f2bu(vv);
        }
    }
    __syncthreads();
    f32x4 acc[16];
    #pragma unroll
    for (int nt = 0; nt < 16; ++nt) acc[nt] = (f32x4){0.f,0.f,0.f,0.f};
    #pragma unroll
    for (int kk = 0; kk < 2; ++kk){
        #pragma unroll
        for (int nt = 0; nt < 16; ++nt){
            bf16x8 bfr = *reinterpret_cast<const bf16x8*>(&BtS[(nt*16 + (lane&15))*72 + kk*32 + k0]);
            acc[nt] = __builtin_amdgcn_mfma_f32_16x16x32_bf16(afr[kk], bfr, acc[nt], 0, 0, 0);
        }
    }
    __syncthreads();   // BtS dead -> reuse as epilogue buffer
    unsigned short* E = BtS;
    #pragma unroll
    for (int nt = 0; nt < 16; ++nt){
        #pragma unroll
        for (int rg = 0; rg < 4; ++rg){
            int epx = w*16 + (lane>>4)*4 + rg;
            int eo  = nt*16 + (lane&15);
            E[epx*258 + eo] = f2bu(acc[nt][rg]);
        }
    }
    __syncthreads();
    unsigned short* ub = u + (size_t)bi*254*uR*256 + (size_t)lr*256 + quarter*64 + (t & 63);
    size_t cs = (size_t)uR*256;
    int og = t >> 6;
    #pragma unroll
    for (int oo = 0; oo < 64; ++oo){
        int o = og*64 + oo;
        if (o < 254) ub[(size_t)o*cs] = E[(t&63)*258 + o];
    }
}

// ---------------- K1b: depthwise 3x3 x2 + relu + partial channel-sum, chunked ----------------
__global__ __launch_bounds__(256) void k_dw(const unsigned short* __restrict__ u,
        const float* __restrict__ wD, unsigned short* __restrict__ t4, float* __restrict__ Sp,
        int tr0, int trows, int ur0, int urows, int uR, int tR, int nbat){
    int chunk = blockIdx.x & (NCH-1);
    int rb = blockIdx.x >> 3;
    int bi = rb / trows;
    int lr = rb - bi*trows;
    int grow = tr0 + lr;
    int xx = threadIdx.x;
    int c0 = chunk*32;
    int c1 = c0+32 < 254 ? c0+32 : 254;
    int lrow = grow - ur0;
    int lm = lrow-1 > 0 ? lrow-1 : 0;
    int lp = lrow+1 < urows-1 ? lrow+1 : urows-1;
    int xl = xx-1 > 0 ? xx-1 : 0;
    int xr_ = xx+1 < 255 ? xx+1 : 255;
    float mym = grow>0 ? 1.f:0.f, myp = grow<255 ? 1.f:0.f;
    float mxm = xx>0 ? 1.f:0.f,  mxp = xx<255 ? 1.f:0.f;
    float m[9] = { mym*mxm, mym, mym*mxp,  mxm, 1.f, mxp,  myp*mxm, myp, myp*mxp };
    int off[9] = { lm*256+xl, lm*256+xx, lm*256+xr_,
                   lrow*256+xl, lrow*256+xx, lrow*256+xr_,
                   lp*256+xl, lp*256+xx, lp*256+xr_ };
    const unsigned short* ub = u + (size_t)bi*254*uR*256;
    unsigned short* tb = t4 + (size_t)bi*127*tR*256*4 + ((size_t)lr*256 + xx)*4;
    size_t tcs = (size_t)tR*256*4;
    size_t ucs = (size_t)uR*256;
    float ssum = 0.f;
    for (int c = c0; c < c1; c += 2){
        const unsigned short* up0 = ub + (size_t)c*ucs;
        const unsigned short* up1 = up0 + ucs;
        unsigned short r0[9], r1[9];
        #pragma unroll
        for (int q = 0; q < 9; ++q){ r0[q] = up0[off[q]]; r1[q] = up1[off[q]]; }
        float v0[9], v1[9];
        #pragma unroll
        for (int q = 0; q < 9; ++q){ v0[q] = bfu(r0[q])*m[q]; v1[q] = bfu(r1[q])*m[q]; }
        const float* w0 = wD + (size_t)(2*c)*9;
        float t0=0.f, t1=0.f, t2=0.f, t3=0.f;
        #pragma unroll
        for (int q = 0; q < 9; ++q){
            t0 = fmaf(w0[q],    v0[q], t0);
            t1 = fmaf(w0[9+q],  v0[q], t1);
            t2 = fmaf(w0[18+q], v1[q], t2);
            t3 = fmaf(w0[27+q], v1[q], t3);
        }
        t0 = fmaxf(t0,0.f); t1 = fmaxf(t1,0.f); t2 = fmaxf(t2,0.f); t3 = fmaxf(t3,0.f);
        ssum += (t0+t1) + (t2+t3);
        ushort4 st; st.x=f2bu(t0); st.y=f2bu(t1); st.z=f2bu(t2); st.w=f2bu(t3);
        *reinterpret_cast<ushort4*>(tb + (size_t)(c>>1)*tcs) = st;
    }
    Sp[((size_t)(chunk*nbat + bi)*tR + lr)*256 + xx] = ssum * (1.f/9.f);
}

// ---------------- K2: sum chunks + 3x3 box with edge clamp ----------------
__global__ __launch_bounds__(256) void k_box(const float* __restrict__ Sp, float* __restrict__ Lm,
        int lr0, int lrows, int tr0, int tR, int lR, int nbat){
    int bi = blockIdx.x / lrows;
    int lr = blockIdx.x - bi*lrows;
    int grow = lr0 + lr;
    int xx = threadIdx.x;
    int g0 = (grow-1 > 0 ? grow-1 : 0) - tr0, g1 = grow - tr0, g2 = (grow+1 < 255 ? grow+1 : 255) - tr0;
    int x0 = xx-1 > 0 ? xx-1 : 0, x2 = xx+1 < 255 ? xx+1 : 255;
    float s = 0.f;
    for (int ch = 0; ch < NCH; ++ch){
        const float* Sb = Sp + ((size_t)(ch*nbat + bi)*tR)*256;
        s += Sb[g0*256+x0]+Sb[g0*256+xx]+Sb[g0*256+x2]
           + Sb[g1*256+x0]+Sb[g1*256+xx]+Sb[g1*256+x2]
           + Sb[g2*256+x0]+Sb[g2*256+xx]+Sb[g2*256+x2];
    }
    Lm[(size_t)bi*lR*256 + (size_t)lr*256 + xx] = s;
}

// ---------------- K3: h-path g1x1 + relu + shuffle + g1x1 -> h2, 4 g-chunks ----------------
__global__ __launch_bounds__(256) void k_mix(const unsigned short* __restrict__ t4,
        const float* __restrict__ Lm, const float* __restrict__ whp1, const float* __restrict__ whp2,
        const float* __restrict__ ahp1, unsigned short* __restrict__ h2,
        int lr0, int lrows, int tr0, int tR, int lR){
    int chunk = blockIdx.x & 3;
    int rb = blockIdx.x >> 2;
    int bi = rb / lrows;
    int lr = rb - bi*lrows;
    int grow = lr0 + lr;
    int xx = threadIdx.x;
    const unsigned short* tb = t4 + (size_t)bi*127*tR*256*4 + ((size_t)(grow-tr0)*256 + xx)*4;
    size_t tcs = (size_t)tR*256*4;
    unsigned short* hb = h2 + (size_t)bi*127*lR*256*4 + ((size_t)lr*256 + xx)*4;
    size_t hcs = (size_t)lR*256*4;
    float Lv = Lm[(size_t)bi*lR*256 + (size_t)lr*256 + xx];
    int g0 = chunk*32, gend = g0+32 < 127 ? g0+32 : 127;
    #pragma unroll 2
    for (int g = g0; g < gend; ++g){
        int idx0 = 4*g;
        ushort4 raw[4];
        #pragma unroll
        for (int k = 0; k < 4; ++k){
            int idx = idx0 + k;
            int oi = idx/127;
            int gi = idx - oi*127;
            raw[k] = *reinterpret_cast<const ushort4*>(tb + (size_t)gi*tcs);
        }
        float a0=0.f,a1=0.f,a2=0.f,a3=0.f;
        const float* w2 = whp2 + g*16;
        #pragma unroll
        for (int k = 0; k < 4; ++k){
            int idx = idx0 + k;
            int oi = idx/127;
            int gi = idx - oi*127;
            const float* w1 = whp1 + gi*16 + oi*4;
            float h1 = fmaf(w1[0], bfu(raw[k].x), fmaf(w1[1], bfu(raw[k].y),
                       fmaf(w1[2], bfu(raw[k].z), w1[3]*bfu(raw[k].w))));
            h1 = fmaxf(fmaf(-Lv, ahp1[gi*4+oi], h1), 0.f);
            a0 = fmaf(w2[k],    h1, a0);
            a1 = fmaf(w2[4+k],  h1, a1);
            a2 = fmaf(w2[8+k],  h1, a2);
            a3 = fmaf(w2[12+k], h1, a3);
        }
        ushort4 st; st.x=f2bu(a0); st.y=f2bu(a1); st.z=f2bu(a2); st.w=f2bu(a3);
        *reinterpret_cast<ushort4*>(hb + (size_t)g*hcs) = st;
    }
}

// ---------------- K4a: grouped 3x3 + relu -> v (packed vl,vh per group), 8 g-chunks ----------------
__global__ __launch_bounds__(256) void k_outv(const unsigned short* __restrict__ h2,
     const float* __restrict__ Lm,
     const float* __restrict__ WLP, const float* __restrict__ WLN,
     const float* __restrict__ WHP, const float* __restrict__ WHN,
     const float* __restrict__ WLD2, const float* __restrict__ WHD2,
     unsigned int* __restrict__ v,
     int a, int orows, int lr0, int lR){
    int chunk = blockIdx.x & 7;
    int rb = blockIdx.x >> 3;
    int bi = rb / orows;
    int lr = rb - bi*orows;
    int grow = a + lr;
    int xx = threadIdx.x;
    const float* Lb = Lm + (size_t)bi*lR*256;
    float Lq[9], vm[9]; int hoff[9];
    #pragma unroll
    for (int q = 0; q < 9; ++q){
        int dy = q/3 - 1, dx = q%3 - 1;
        int yy = grow+dy, xc = xx+dx;
        bool vv = (yy>=0)&&(yy<256)&&(xc>=0)&&(xc<256);
        vm[q] = vv ? 1.f : 0.f;
        int o = vv ? ((yy-lr0)*256 + xc) : ((grow-lr0)*256 + xx);
        hoff[q] = o;
        Lq[q] = vv ? Lb[o] : 0.f;
    }
    const unsigned short* hb = h2 + (size_t)bi*127*lR*256*4;
    size_t hcs = (size_t)lR*256*4;
    size_t ps = (size_t)orows*256;
    unsigned int* vb = v + (size_t)bi*128*ps + (size_t)lr*256 + xx;
    int g0 = chunk*16, gend = g0+16 < 127 ? g0+16 : 127;

    for (int g = g0; g < gend; ++g){
        float sl = 0.f, sh = 0.f;
        #pragma unroll
        for (int q = 0; q < 9; ++q){
            float lq = Lq[q];
            bool pos = lq > 0.f;
            float cl  = pos ? WLP[g*9+q] : WLN[g*9+q];
            float chh = pos ? WHP[g*9+q] : WHN[g*9+q];
            sl = fmaf(cl, lq, sl);
            sh = fmaf(chh, lq, sh);
        }
        const unsigned short* hq = hb + (size_t)g*hcs;
        ushort4 rr[9];
        #pragma unroll
        for (int q = 0; q < 9; ++q) rr[q] = *reinterpret_cast<const ushort4*>(hq + (size_t)hoff[q]*4);
        if (g >= 63){   // l-branch h2-sourced channels (4g+i >= 254)
            const float* w = WLD2 + g*36;
            #pragma unroll
            for (int q = 0; q < 9; ++q){
                float tv = fmaf(w[0*9+q], bfu(rr[q].x), fmaf(w[1*9+q], bfu(rr[q].y),
                           fmaf(w[2*9+q], bfu(rr[q].z), w[3*9+q]*bfu(rr[q].w))));
                sl = fmaf(vm[q], tv, sl);
            }
        }
        if (g <= 63){   // h-branch h2-sourced channels (4g+i < 254)
            const float* w = WHD2 + g*36;
            #pragma unroll
            for (int q = 0; q < 9; ++q){
                float tv = fmaf(w[0*9+q], bfu(rr[q].x), fmaf(w[1*9+q], bfu(rr[q].y),
                           fmaf(w[2*9+q], bfu(rr[q].z), w[3*9+q]*bfu(rr[q].w))));
                sh = fmaf(vm[q], tv, sh);
            }
        }
        unsigned int lo = f2bu(fmaxf(sl, 0.f));
        unsigned int hi = f2bu(fmaxf(sh, 0.f));
        vb[(size_t)g*ps] = lo | (hi << 16);
    }
    if (chunk == 7) vb[(size_t)127*ps] = 0u;   // zero pad plane (k=254,255)
}

// ---------------- K4b: out = v @ BtP^T + x via MFMA, fused residual ----------------
// block = 1 row (256 px), 4 waves x 64 px (4 M-tiles), 3 N-tiles, K=256
__global__ __launch_bounds__(256) void k_proj(const unsigned int* __restrict__ v,
        const unsigned short* __restrict__ BtP, const float* __restrict__ x,
        float* __restrict__ out, int b0, int a, int orows){
    __shared__ float EoS[256*49];            // 50176 B; Bt overlays first 26112 B
    unsigned short* Bt = (unsigned short*)EoS;   // [48 n][136 u16] stride 272 B
    int t = threadIdx.x;
    for (int i = t; i < 48*256; i += 256){
        int n = i >> 8, k = i & 255;
        Bt[n*136 + k] = BtP[i];
    }
    int bi = blockIdx.x / orows;
    int lr = blockIdx.x - bi*orows;
    int b = b0 + bi;
    size_t ps = (size_t)orows*256;
    const unsigned int* vb = v + (size_t)bi*128*ps + (size_t)lr*256;
    int lane = t & 63, w = t >> 6;
    int pxl = w*64;
    __syncthreads();
    f32x4 acc[4][3];
    #pragma unroll
    for (int m = 0; m < 4; ++m)
        #pragma unroll
        for (int nt = 0; nt < 3; ++nt) acc[m][nt] = (f32x4){0.f,0.f,0.f,0.f};
    #pragma unroll
    for (int ch = 0; ch < 4; ++ch){
        bf16x8 bfr[3][2];
        #pragma unroll
        for (int nt = 0; nt < 3; ++nt)
            #pragma unroll
            for (int kk = 0; kk < 2; ++kk)
                bfr[nt][kk] = *reinterpret_cast<const bf16x8*>(
                    &Bt[(nt*16 + (lane&15))*136 + ch*64 + kk*32 + (lane>>4)*8]);
        #pragma unroll
        for (int m = 0; m < 4; ++m){
            int px = pxl + m*16 + (lane & 15);
            #pragma unroll
            for (int kk = 0; kk < 2; ++kk){
                int pl0 = ch*32 + kk*16 + (lane>>4)*4;
                unsigned int p0 = vb[(size_t)(pl0+0)*ps + px];
                unsigned int p1 = vb[(size_t)(pl0+1)*ps + px];
                unsigned int p2 = vb[(size_t)(pl0+2)*ps + px];
                unsigned int p3 = vb[(size_t)(pl0+3)*ps + px];
                bf16x8 af;
                af[0]=(short)(p0&0xffff); af[1]=(short)(p0>>16);
                af[2]=(short)(p1&0xffff); af[3]=(short)(p1>>16);
                af[4]=(short)(p2&0xffff); af[5]=(short)(p2>>16);
                af[6]=(short)(p3&0xffff); af[7]=(short)(p3>>16);
                #pragma unroll
                for (int nt = 0; nt < 3; ++nt)
                    acc[m][nt] = __builtin_amdgcn_mfma_f32_16x16x32_bf16(af, bfr[nt][kk], acc[m][nt], 0, 0, 0);
            }
        }
    }
    __syncthreads();   // Bt dead -> epilogue buffer
    #pragma unroll
    for (int m = 0; m < 4; ++m){
        #pragma unroll
        for (int nt = 0; nt < 3; ++nt){
            #pragma unroll
            for (int rg = 0; rg < 4; ++rg){
                int epx = pxl + m*16 + (lane>>4)*4 + rg;
                int eo  = nt*16 + (lane&15);
                EoS[epx*49 + eo] = acc[m][nt][rg];
            }
        }
    }
    __syncthreads();
    int grow = a + lr;
    const float* xb = x + (size_t)b*48*HW + (size_t)grow*256 + t;
    float* ob = out + (size_t)b*48*HW + (size_t)grow*256 + t;
    #pragma unroll
    for (int o = 0; o < 48; ++o)
        ob[(size_t)o*HW] = EoS[t*49 + o] + xb[(size_t)o*HW];
}

extern "C" void kernel_launch(void* const* d_in, const int* in_sizes, int n_in,
                              void* d_out, int out_size, void* d_ws, size_t ws_size,
                              hipStream_t stream){
    const float* x    = (const float*)d_in[0];
    const float* winP = (const float*)d_in[1];
    const float* winD = (const float*)d_in[2];
    const float* wlp1 = (const float*)d_in[3];
    const float* whp1 = (const float*)d_in[4];
    const float* wlp2 = (const float*)d_in[5];
    const float* whp2 = (const float*)d_in[6];
    const float* wld  = (const float*)d_in[7];
    const float* whd  = (const float*)d_in[8];
    const float* wout = (const float*)d_in[9];
    float* out = (float*)d_out;

    char* ws = (char*)d_ws;
    size_t off = 0;
    auto alloc = [&](size_t bytes)->char*{
        char* pp = ws + off; off += (bytes + 255) & ~(size_t)255; return pp;
    };
    auto A = [](size_t bytes)->size_t{ return (bytes + 255) & ~(size_t)255; };

    float* ahp1 = (float*)alloc(508*4);
    float* WLP  = (float*)alloc(127*9*4);
    float* WLN  = (float*)alloc(127*9*4);
    float* WHP  = (float*)alloc(127*9*4);
    float* WHN  = (float*)alloc(127*9*4);
    float* WLD2 = (float*)alloc(127*36*4);
    float* WHD2 = (float*)alloc(127*36*4);
    unsigned short* WPb = (unsigned short*)alloc(256*64*2);
    unsigned short* BtP = (unsigned short*)alloc(48*256*2);

    const int cfgs[7][2] = {{256,2},{128,2},{64,2},{64,1},{32,1},{16,1},{8,1}};
    int Hb = 8, nbat = 1;
    for (int ci = 0; ci < 7; ++ci){
        int hb = cfgs[ci][0], nb = cfgs[ci][1];
        int uR = hb+6 < 256 ? hb+6 : 256;
        int tR = hb+4 < 256 ? hb+4 : 256;
        int lR = hb+2 < 256 ? hb+2 : 256;
        size_t need = off;
        need += A((size_t)nb*254*uR*256*2);
        need += A((size_t)nb*127*tR*256*4*2);
        need += A((size_t)nb*127*lR*256*4*2);
        need += A((size_t)nb*NCH*tR*256*4);
        need += A((size_t)nb*lR*256*4);
        if (need <= ws_size){ Hb = hb; nbat = nb; break; }
    }
    int uR = Hb+6 < 256 ? Hb+6 : 256;
    int tR = Hb+4 < 256 ? Hb+4 : 256;
    int lR = Hb+2 < 256 ? Hb+2 : 256;
    unsigned short* u  = (unsigned short*)alloc((size_t)nbat*254*uR*256*2);
    unsigned short* t4 = (unsigned short*)alloc((size_t)nbat*127*tR*256*4*2);
    unsigned short* h2 = (unsigned short*)alloc((size_t)nbat*127*lR*256*4*2);
    float* Sp = (float*)alloc((size_t)nbat*NCH*tR*256*4);
    float* Lm = (float*)alloc((size_t)nbat*lR*256*4);
    // v aliases t4: t4 dead after k_mix; v = nbat*128*orows*256*4 <= t4 size for all cfgs
    unsigned int* v = (unsigned int*)t4;

    k_coef<<<1, 512, 0, stream>>>(wlp1, whp1, wlp2, wld, whd, winP, wout,
                                  ahp1, WLP, WLN, WHP, WHN, WLD2, WHD2, WPb, BtP);

    for (int b0 = 0; b0 < 2; b0 += nbat){
        for (int a = 0; a < 256; a += Hb){
            int ur0 = a-3 > 0 ? a-3 : 0;  int ur1 = a+Hb+3 < 256 ? a+Hb+3 : 256;
            int tr0 = a-2 > 0 ? a-2 : 0;  int tr1 = a+Hb+2 < 256 ? a+Hb+2 : 256;
            int lr0 = a-1 > 0 ? a-1 : 0;  int lr1 = a+Hb+1 < 256 ? a+Hb+1 : 256;
            int urows = ur1-ur0, trows = tr1-tr0, lrows = lr1-lr0;
            int orows = (a+Hb < 256 ? a+Hb : 256) - a;
            k_pconv<<<nbat*urows*4, 256, 0, stream>>>(x, WPb, u, b0, ur0, urows, uR);
            k_dw  <<<nbat*trows*NCH, 256, 0, stream>>>(u, winD, t4, Sp, tr0, trows, ur0, urows, uR, tR, nbat);
            k_box <<<nbat*lrows, 256, 0, stream>>>(Sp, Lm, lr0, lrows, tr0, tR, lR, nbat);
            k_mix <<<nbat*lrows*4, 256, 0, stream>>>(t4, Lm, whp1, whp2, ahp1, h2, lr0, lrows, tr0, tR, lR);
            k_outv<<<nbat*orows*8, 256, 0, stream>>>(h2, Lm, WLP, WLN, WHP, WHN, WLD2, WHD2,
                                                     v, a, orows, lr0, lR);
            k_proj<<<nbat*orows, 256, 0, stream>>>(v, BtP, x, out, b0, a, orows);
        }
    }
}

// Round 6
// 358.472 us; speedup vs baseline: 5.5309x; 1.1625x over previous
//
#include <hip/hip_runtime.h>
#include <hip/hip_bf16.h>

#define HW 65536
#define NCH 8   // channel chunks in k_dw

typedef __attribute__((ext_vector_type(8))) short bf16x8;
typedef __attribute__((ext_vector_type(4))) float f32x4;

__device__ __forceinline__ float bfu(unsigned short u){
    return __uint_as_float(((unsigned int)u) << 16);
}
__device__ __forceinline__ float bflo(unsigned int u){
    return __uint_as_float(u << 16);
}
__device__ __forceinline__ float bfhi(unsigned int u){
    return __uint_as_float(u & 0xffff0000u);
}
__device__ __forceinline__ unsigned short f2bu(float f){
    unsigned int u = __float_as_uint(f);
    unsigned int r = (u + 0x7fffu + ((u >> 16) & 1u)) >> 16;
    return (unsigned short)r;
}

// ---------------- K0: precompute coefficient tables ----------------
__global__ void k_coef(const float* __restrict__ wlp1, const float* __restrict__ whp1,
                       const float* __restrict__ wlp2,
                       const float* __restrict__ wld, const float* __restrict__ whd,
                       const float* __restrict__ winP, const float* __restrict__ winD,
                       const float* __restrict__ wout,
                       float* __restrict__ ahp1,
                       float* __restrict__ WLP, float* __restrict__ WLN,
                       float* __restrict__ WHP, float* __restrict__ WHN,
                       float* __restrict__ WLD2, float* __restrict__ WHD2,
                       float* __restrict__ wDp,
                       unsigned short* __restrict__ WPb, unsigned short* __restrict__ BtP){
    __shared__ float aL[508], cp[508], cn[508];
    int t = threadIdx.x;
    if (t < 508){
        int g = t >> 2, o = t & 3;
        float s = 0.f, s2 = 0.f;
        for (int i = 0; i < 4; ++i){ s += wlp1[g*16 + o*4 + i]; s2 += whp1[g*16 + o*4 + i]; }
        aL[t] = s; ahp1[t] = s2;
    }
    __syncthreads();
    if (t < 508){
        int g = t >> 2, o = t & 3;
        float p = 0.f, n = 0.f;
        for (int k = 0; k < 4; ++k){
            int idx = 4*g + k;                    // shuffled position
            int inv = (idx % 127)*4 + idx/127;    // original channel
            float av = aL[inv];
            float w2 = wlp2[g*16 + o*4 + k];
            p += w2 * fmaxf(av, 0.f);
            n += w2 * fminf(av, 0.f);
        }
        cp[t] = p; cn[t] = n;
    }
    __syncthreads();
    for (int idx = t; idx < 127*9; idx += blockDim.x){
        int g = idx/9, q = idx%9;
        float lp=0.f, ln=0.f, hp=0.f, hn=0.f;
        for (int i = 0; i < 4; ++i){
            int ch = 4*g + i;
            if (ch < 254){ float w = wld[g*36 + i*9 + q]; lp += w*cp[ch]; ln += w*cn[ch]; }
            else         { float w = whd[g*36 + i*9 + q]; hp += w*cp[ch]; hn += w*cn[ch]; }
        }
        WLP[idx]=lp; WLN[idx]=ln; WHP[idx]=hp; WHN[idx]=hn;
    }
    for (int idx = t; idx < 127*36; idx += blockDim.x){
        int g = idx/36, r = idx%36; int i = r/9;
        int ch = 4*g + i;
        WLD2[idx] = (ch >= 254) ? wld[idx] : 0.f;
        WHD2[idx] = (ch <  254) ? whd[idx] : 0.f;
    }
    // wDp: [512 tch][9], zero-padded winD (508x9)
    for (int idx = t; idx < 512*9; idx += blockDim.x){
        int ch = idx/9, q = idx - ch*9;
        wDp[idx] = (ch < 508) ? winD[ch*9 + q] : 0.f;
    }
    // WPb: [256 o][64 k] bf16, zero-padded winP
    for (int idx = t; idx < 256*64; idx += blockDim.x){
        int o = idx >> 6, k = idx & 63;
        float vv = (o < 254 && k < 48) ? winP[o*48 + k] : 0.f;
        WPb[idx] = f2bu(vv);
    }
    // BtP: [48 n][256 k] bf16; k=2g -> wout[n][g] (l-part), k=2g+1 -> wout[n][127+g] (h-part)
    for (int idx = t; idx < 48*256; idx += blockDim.x){
        int n = idx >> 8, k = idx & 255;
        int g = k >> 1;
        float vv = (g < 127) ? ((k & 1) ? wout[n*254 + 127 + g] : wout[n*254 + g]) : 0.f;
        BtP[idx] = f2bu(vv);
    }
}

// ---------------- K1a: u = w_inP @ x (1x1 48->254) via MFMA, quad-layout output ----------------
// block = 64 px (quarter row), 4 waves x 16 px, 16 N-tiles each
__global__ __launch_bounds__(256) void k_pconv(const float* __restrict__ x,
        const unsigned short* __restrict__ WPb, unsigned short* __restrict__ u,
        int b0, int ur0, int urows, int uR){
    __shared__ unsigned short BtS[256*72];   // 36864 B; epilogue overlays [64px][260 u16]=33280 B
    int t = threadIdx.x;
    for (int i = t; i < 256*64; i += 256){
        int o = i >> 6, k = i & 63;
        BtS[o*72 + k] = WPb[i];
    }
    int bpb = urows*4;
    int bi = blockIdx.x / bpb;
    int r  = blockIdx.x - bi*bpb;
    int lr = r >> 2, quarter = r & 3;
    int b = b0 + bi;
    int grow = ur0 + lr;
    const float* xb = x + (size_t)b*48*HW + (size_t)grow*256 + quarter*64;
    int w = t >> 6, lane = t & 63;
    int px = w*16 + (lane & 15);
    int k0 = (lane >> 4)*8;
    bf16x8 afr[2];
    #pragma unroll
    for (int kk = 0; kk < 2; ++kk){
        #pragma unroll
        for (int j = 0; j < 8; ++j){
            int k = kk*32 + k0 + j;
            float vv = (k < 48) ? xb[(size_t)k*HW + px] : 0.f;
            afr[kk][j] = (short)f2bu(vv);
        }
    }
    __syncthreads();
    f32x4 acc[16];
    #pragma unroll
    for (int nt = 0; nt < 16; ++nt) acc[nt] = (f32x4){0.f,0.f,0.f,0.f};
    #pragma unroll
    for (int kk = 0; kk < 2; ++kk){
        #pragma unroll
        for (int nt = 0; nt < 16; ++nt){
            bf16x8 bfr = *reinterpret_cast<const bf16x8*>(&BtS[(nt*16 + (lane&15))*72 + kk*32 + k0]);
            acc[nt] = __builtin_amdgcn_mfma_f32_16x16x32_bf16(afr[kk], bfr, acc[nt], 0, 0, 0);
        }
    }
    __syncthreads();   // BtS dead -> reuse as epilogue buffer, stride 260
    unsigned short* E = BtS;
    #pragma unroll
    for (int nt = 0; nt < 16; ++nt){
        #pragma unroll
        for (int rg = 0; rg < 4; ++rg){
            int epx = w*16 + (lane>>4)*4 + rg;
            int eo  = nt*16 + (lane&15);
            E[epx*260 + eo] = f2bu(acc[nt][rg]);
        }
    }
    __syncthreads();
    int spx = t & 63;
    ushort4* ub4 = (ushort4*)u + (size_t)bi*64*uR*256 + (size_t)lr*256 + quarter*64 + spx;
    size_t cs = (size_t)uR*256;
    int og = t >> 6;
    #pragma unroll
    for (int j = 0; j < 16; ++j){
        int qd = og*16 + j;
        ushort4 q4 = *reinterpret_cast<const ushort4*>(&E[spx*260 + 4*qd]);
        ub4[(size_t)qd*cs] = q4;
    }
}

// ---------------- K1b: depthwise 3x3 x2 + relu + partial channel-sum, quad loads ----------------
__global__ __launch_bounds__(256) void k_dw(const unsigned short* __restrict__ u,
        const float* __restrict__ wDp, unsigned short* __restrict__ t4, float* __restrict__ Sp,
        int tr0, int trows, int ur0, int urows, int uR, int tR, int nbat){
    int chunk = blockIdx.x & (NCH-1);
    int rb = blockIdx.x >> 3;
    int bi = rb / trows;
    int lr = rb - bi*trows;
    int grow = tr0 + lr;
    int xx = threadIdx.x;
    int lrow = grow - ur0;
    int lm = lrow-1 > 0 ? lrow-1 : 0;
    int lp = lrow+1 < urows-1 ? lrow+1 : urows-1;
    int xl = xx-1 > 0 ? xx-1 : 0;
    int xr_ = xx+1 < 255 ? xx+1 : 255;
    bool bym = grow>0, byp = grow<255, bxm = xx>0, bxp = xx<255;
    bool val[9] = { bym&&bxm, bym, bym&&bxp,  bxm, true, bxp,  byp&&bxm, byp, byp&&bxp };
    int off[9] = { lm*256+xl, lm*256+xx, lm*256+xr_,
                   lrow*256+xl, lrow*256+xx, lrow*256+xr_,
                   lp*256+xl, lp*256+xx, lp*256+xr_ };
    const uint2* ub = (const uint2*)u + (size_t)bi*64*uR*256;
    size_t ucs = (size_t)uR*256;
    ushort4* tb = (ushort4*)t4 + (size_t)bi*128*tR*256 + (size_t)lr*256 + xx;
    size_t tcs = (size_t)tR*256;
    float ssum = 0.f;
    int qd0 = chunk*8;
    for (int qd = qd0; qd < qd0+8; ++qd){
        const uint2* up = ub + (size_t)qd*ucs;
        float v0[9], v1[9], v2[9], v3[9];
        #pragma unroll
        for (int q = 0; q < 9; ++q){
            uint2 rv = up[off[q]];
            unsigned int rx = val[q] ? rv.x : 0u;
            unsigned int ry = val[q] ? rv.y : 0u;
            v0[q] = bflo(rx); v1[q] = bfhi(rx);
            v2[q] = bflo(ry); v3[q] = bfhi(ry);
        }
        const float* w = wDp + (size_t)qd*72;
        float o0=0.f,o1=0.f,o2=0.f,o3=0.f,o4=0.f,o5=0.f,o6=0.f,o7=0.f;
        #pragma unroll
        for (int q = 0; q < 9; ++q){
            o0 = fmaf(w[q],    v0[q], o0);
            o1 = fmaf(w[9+q],  v0[q], o1);
            o2 = fmaf(w[18+q], v1[q], o2);
            o3 = fmaf(w[27+q], v1[q], o3);
            o4 = fmaf(w[36+q], v2[q], o4);
            o5 = fmaf(w[45+q], v2[q], o5);
            o6 = fmaf(w[54+q], v3[q], o6);
            o7 = fmaf(w[63+q], v3[q], o7);
        }
        o0=fmaxf(o0,0.f); o1=fmaxf(o1,0.f); o2=fmaxf(o2,0.f); o3=fmaxf(o3,0.f);
        o4=fmaxf(o4,0.f); o5=fmaxf(o5,0.f); o6=fmaxf(o6,0.f); o7=fmaxf(o7,0.f);
        ssum += ((o0+o1)+(o2+o3)) + ((o4+o5)+(o6+o7));
        ushort4 sa; sa.x=f2bu(o0); sa.y=f2bu(o1); sa.z=f2bu(o2); sa.w=f2bu(o3);
        ushort4 sb; sb.x=f2bu(o4); sb.y=f2bu(o5); sb.z=f2bu(o6); sb.w=f2bu(o7);
        tb[(size_t)(2*qd)*tcs]   = sa;
        tb[(size_t)(2*qd+1)*tcs] = sb;
    }
    Sp[((size_t)(chunk*nbat + bi)*tR + lr)*256 + xx] = ssum * (1.f/9.f);
}

// ---------------- K2: sum chunks + 3x3 box with edge clamp ----------------
__global__ __launch_bounds__(256) void k_box(const float* __restrict__ Sp, float* __restrict__ Lm,
        int lr0, int lrows, int tr0, int tR, int lR, int nbat){
    int bi = blockIdx.x / lrows;
    int lr = blockIdx.x - bi*lrows;
    int grow = lr0 + lr;
    int xx = threadIdx.x;
    int g0 = (grow-1 > 0 ? grow-1 : 0) - tr0, g1 = grow - tr0, g2 = (grow+1 < 255 ? grow+1 : 255) - tr0;
    int x0 = xx-1 > 0 ? xx-1 : 0, x2 = xx+1 < 255 ? xx+1 : 255;
    float s = 0.f;
    for (int ch = 0; ch < NCH; ++ch){
        const float* Sb = Sp + ((size_t)(ch*nbat + bi)*tR)*256;
        s += Sb[g0*256+x0]+Sb[g0*256+xx]+Sb[g0*256+x2]
           + Sb[g1*256+x0]+Sb[g1*256+xx]+Sb[g1*256+x2]
           + Sb[g2*256+x0]+Sb[g2*256+xx]+Sb[g2*256+x2];
    }
    Lm[(size_t)bi*lR*256 + (size_t)lr*256 + xx] = s;
}

// ---------------- K3: h-path g1x1 + relu + shuffle + g1x1 -> h2, 4 g-chunks ----------------
__global__ __launch_bounds__(256) void k_mix(const unsigned short* __restrict__ t4,
        const float* __restrict__ Lm, const float* __restrict__ whp1, const float* __restrict__ whp2,
        const float* __restrict__ ahp1, unsigned short* __restrict__ h2,
        int lr0, int lrows, int tr0, int tR, int lR){
    int chunk = blockIdx.x & 3;
    int rb = blockIdx.x >> 2;
    int bi = rb / lrows;
    int lr = rb - bi*lrows;
    int grow = lr0 + lr;
    int xx = threadIdx.x;
    const ushort4* tb = (const ushort4*)t4 + (size_t)bi*128*tR*256 + (size_t)(grow-tr0)*256 + xx;
    size_t tcs = (size_t)tR*256;
    ushort4* hb = (ushort4*)h2 + (size_t)bi*127*lR*256 + (size_t)lr*256 + xx;
    size_t hcs = (size_t)lR*256;
    float Lv = Lm[(size_t)bi*lR*256 + (size_t)lr*256 + xx];
    int g0 = chunk*32, gend = g0+32 < 127 ? g0+32 : 127;
    #pragma unroll 2
    for (int g = g0; g < gend; ++g){
        int idx0 = 4*g;
        ushort4 raw[4];
        #pragma unroll
        for (int k = 0; k < 4; ++k){
            int idx = idx0 + k;
            int oi = idx/127;
            int gi = idx - oi*127;
            raw[k] = tb[(size_t)gi*tcs];
        }
        float a0=0.f,a1=0.f,a2=0.f,a3=0.f;
        const float* w2 = whp2 + g*16;
        #pragma unroll
        for (int k = 0; k < 4; ++k){
            int idx = idx0 + k;
            int oi = idx/127;
            int gi = idx - oi*127;
            const float* w1 = whp1 + gi*16 + oi*4;
            float h1 = fmaf(w1[0], bfu(raw[k].x), fmaf(w1[1], bfu(raw[k].y),
                       fmaf(w1[2], bfu(raw[k].z), w1[3]*bfu(raw[k].w))));
            h1 = fmaxf(fmaf(-Lv, ahp1[gi*4+oi], h1), 0.f);
            a0 = fmaf(w2[k],    h1, a0);
            a1 = fmaf(w2[4+k],  h1, a1);
            a2 = fmaf(w2[8+k],  h1, a2);
            a3 = fmaf(w2[12+k], h1, a3);
        }
        ushort4 st; st.x=f2bu(a0); st.y=f2bu(a1); st.z=f2bu(a2); st.w=f2bu(a3);
        hb[(size_t)g*hcs] = st;
    }
}

// ---------------- K4a: grouped 3x3 + relu -> v (packed vl,vh per group), 16 g-chunks ----------------
__global__ __launch_bounds__(256) void k_outv(const unsigned short* __restrict__ h2,
     const float* __restrict__ Lm,
     const float* __restrict__ WLP, const float* __restrict__ WLN,
     const float* __restrict__ WHP, const float* __restrict__ WHN,
     const float* __restrict__ WLD2, const float* __restrict__ WHD2,
     unsigned int* __restrict__ v,
     int a, int orows, int lr0, int lR){
    int chunk = blockIdx.x & 15;
    int rb = blockIdx.x >> 4;
    int bi = rb / orows;
    int lr = rb - bi*orows;
    int grow = a + lr;
    int xx = threadIdx.x;
    const float* Lb = Lm + (size_t)bi*lR*256;
    float lqp[9], lqn[9], vm[9]; int hoff[9];
    #pragma unroll
    for (int q = 0; q < 9; ++q){
        int dy = q/3 - 1, dx = q%3 - 1;
        int yy = grow+dy, xc = xx+dx;
        bool vv = (yy>=0)&&(yy<256)&&(xc>=0)&&(xc<256);
        vm[q] = vv ? 1.f : 0.f;
        int o = vv ? ((yy-lr0)*256 + xc) : ((grow-lr0)*256 + xx);
        hoff[q] = o;
        float lv = vv ? Lb[o] : 0.f;
        bool pos = lv > 0.f;
        lqp[q] = pos ? lv : 0.f;
        lqn[q] = pos ? 0.f : lv;
    }
    const ushort4* hb = (const ushort4*)h2 + (size_t)bi*127*lR*256;
    size_t hcs = (size_t)lR*256;
    size_t ps = (size_t)orows*256;
    unsigned int* vb = v + (size_t)bi*128*ps + (size_t)lr*256 + xx;
    int g0 = chunk*8, gend = g0+8 < 127 ? g0+8 : 127;

    for (int g = g0; g < gend; ++g){
        float sl = 0.f, sh = 0.f;
        #pragma unroll
        for (int q = 0; q < 9; ++q){
            sl = fmaf(WLP[g*9+q], lqp[q], fmaf(WLN[g*9+q], lqn[q], sl));
            sh = fmaf(WHP[g*9+q], lqp[q], fmaf(WHN[g*9+q], lqn[q], sh));
        }
        const ushort4* hq = hb + (size_t)g*hcs;
        ushort4 rr[9];
        #pragma unroll
        for (int q = 0; q < 9; ++q) rr[q] = hq[hoff[q]];
        if (g >= 63){   // l-branch h2-sourced channels (4g+i >= 254)
            const float* w = WLD2 + g*36;
            #pragma unroll
            for (int q = 0; q < 9; ++q){
                float tv = fmaf(w[0*9+q], bfu(rr[q].x), fmaf(w[1*9+q], bfu(rr[q].y),
                           fmaf(w[2*9+q], bfu(rr[q].z), w[3*9+q]*bfu(rr[q].w))));
                sl = fmaf(vm[q], tv, sl);
            }
        }
        if (g <= 63){   // h-branch h2-sourced channels (4g+i < 254)
            const float* w = WHD2 + g*36;
            #pragma unroll
            for (int q = 0; q < 9; ++q){
                float tv = fmaf(w[0*9+q], bfu(rr[q].x), fmaf(w[1*9+q], bfu(rr[q].y),
                           fmaf(w[2*9+q], bfu(rr[q].z), w[3*9+q]*bfu(rr[q].w))));
                sh = fmaf(vm[q], tv, sh);
            }
        }
        unsigned int lo = f2bu(fmaxf(sl, 0.f));
        unsigned int hi = f2bu(fmaxf(sh, 0.f));
        vb[(size_t)g*ps] = lo | (hi << 16);
    }
    if (chunk == 15) vb[(size_t)127*ps] = 0u;   // zero pad plane (k=254,255)
}

// ---------------- K4b: out = v @ BtP^T + x via MFMA, fused residual ----------------
// block = 1 row (256 px), 4 waves x 64 px (4 M-tiles), 3 N-tiles, K=256
__global__ __launch_bounds__(256) void k_proj(const unsigned int* __restrict__ v,
        const unsigned short* __restrict__ BtP, const float* __restrict__ x,
        float* __restrict__ out, int b0, int a, int orows){
    __shared__ float EoS[256*49];            // 50176 B; Bt overlays first 26112 B
    unsigned short* Bt = (unsigned short*)EoS;   // [48 n][136 u16] stride 272 B
    int t = threadIdx.x;
    for (int i = t; i < 48*256; i += 256){
        int n = i >> 8, k = i & 255;
        Bt[n*136 + k] = BtP[i];
    }
    int bi = blockIdx.x / orows;
    int lr = blockIdx.x - bi*orows;
    int b = b0 + bi;
    size_t ps = (size_t)orows*256;
    const unsigned int* vb = v + (size_t)bi*128*ps + (size_t)lr*256;
    int lane = t & 63, w = t >> 6;
    int pxl = w*64;
    __syncthreads();
    f32x4 acc[4][3];
    #pragma unroll
    for (int m = 0; m < 4; ++m)
        #pragma unroll
        for (int nt = 0; nt < 3; ++nt) acc[m][nt] = (f32x4){0.f,0.f,0.f,0.f};
    #pragma unroll
    for (int ch = 0; ch < 4; ++ch){
        bf16x8 bfr[3][2];
        #pragma unroll
        for (int nt = 0; nt < 3; ++nt)
            #pragma unroll
            for (int kk = 0; kk < 2; ++kk)
                bfr[nt][kk] = *reinterpret_cast<const bf16x8*>(
                    &Bt[(nt*16 + (lane&15))*136 + ch*64 + kk*32 + (lane>>4)*8]);
        #pragma unroll
        for (int m = 0; m < 4; ++m){
            int px = pxl + m*16 + (lane & 15);
            #pragma unroll
            for (int kk = 0; kk < 2; ++kk){
                int pl0 = ch*32 + kk*16 + (lane>>4)*4;
                unsigned int p0 = vb[(size_t)(pl0+0)*ps + px];
                unsigned int p1 = vb[(size_t)(pl0+1)*ps + px];
                unsigned int p2 = vb[(size_t)(pl0+2)*ps + px];
                unsigned int p3 = vb[(size_t)(pl0+3)*ps + px];
                bf16x8 af;
                af[0]=(short)(p0&0xffff); af[1]=(short)(p0>>16);
                af[2]=(short)(p1&0xffff); af[3]=(short)(p1>>16);
                af[4]=(short)(p2&0xffff); af[5]=(short)(p2>>16);
                af[6]=(short)(p3&0xffff); af[7]=(short)(p3>>16);
                #pragma unroll
                for (int nt = 0; nt < 3; ++nt)
                    acc[m][nt] = __builtin_amdgcn_mfma_f32_16x16x32_bf16(af, bfr[nt][kk], acc[m][nt], 0, 0, 0);
            }
        }
    }
    __syncthreads();   // Bt dead -> epilogue buffer
    #pragma unroll
    for (int m = 0; m < 4; ++m){
        #pragma unroll
        for (int nt = 0; nt < 3; ++nt){
            #pragma unroll
            for (int rg = 0; rg < 4; ++rg){
                int epx = pxl + m*16 + (lane>>4)*4 + rg;
                int eo  = nt*16 + (lane&15);
                EoS[epx*49 + eo] = acc[m][nt][rg];
            }
        }
    }
    __syncthreads();
    int grow = a + lr;
    const float* xb = x + (size_t)b*48*HW + (size_t)grow*256 + t;
    float* ob = out + (size_t)b*48*HW + (size_t)grow*256 + t;
    #pragma unroll
    for (int o = 0; o < 48; ++o)
        ob[(size_t)o*HW] = EoS[t*49 + o] + xb[(size_t)o*HW];
}

extern "C" void kernel_launch(void* const* d_in, const int* in_sizes, int n_in,
                              void* d_out, int out_size, void* d_ws, size_t ws_size,
                              hipStream_t stream){
    const float* x    = (const float*)d_in[0];
    const float* winP = (const float*)d_in[1];
    const float* winD = (const float*)d_in[2];
    const float* wlp1 = (const float*)d_in[3];
    const float* whp1 = (const float*)d_in[4];
    const float* wlp2 = (const float*)d_in[5];
    const float* whp2 = (const float*)d_in[6];
    const float* wld  = (const float*)d_in[7];
    const float* whd  = (const float*)d_in[8];
    const float* wout = (const float*)d_in[9];
    float* out = (float*)d_out;

    char* ws = (char*)d_ws;
    size_t off = 0;
    auto alloc = [&](size_t bytes)->char*{
        char* pp = ws + off; off += (bytes + 255) & ~(size_t)255; return pp;
    };
    auto A = [](size_t bytes)->size_t{ return (bytes + 255) & ~(size_t)255; };

    float* ahp1 = (float*)alloc(508*4);
    float* WLP  = (float*)alloc(127*9*4);
    float* WLN  = (float*)alloc(127*9*4);
    float* WHP  = (float*)alloc(127*9*4);
    float* WHN  = (float*)alloc(127*9*4);
    float* WLD2 = (float*)alloc(127*36*4);
    float* WHD2 = (float*)alloc(127*36*4);
    float* wDp  = (float*)alloc(512*9*4);
    unsigned short* WPb = (unsigned short*)alloc(256*64*2);
    unsigned short* BtP = (unsigned short*)alloc(48*256*2);

    const int cfgs[7][2] = {{256,2},{128,2},{64,2},{64,1},{32,1},{16,1},{8,1}};
    int Hb = 8, nbat = 1;
    for (int ci = 0; ci < 7; ++ci){
        int hb = cfgs[ci][0], nb = cfgs[ci][1];
        int uR = hb+6 < 256 ? hb+6 : 256;
        int tR = hb+4 < 256 ? hb+4 : 256;
        int lR = hb+2 < 256 ? hb+2 : 256;
        size_t need = off;
        need += A((size_t)nb*64*uR*256*8);     // u (64 quads, ushort4)
        need += A((size_t)nb*128*tR*256*8);    // t4 (128 quads)
        need += A((size_t)nb*127*lR*256*8);    // h2
        need += A((size_t)nb*NCH*tR*256*4);    // Sp
        need += A((size_t)nb*lR*256*4);        // Lm
        if (need <= ws_size){ Hb = hb; nbat = nb; break; }
    }
    int uR = Hb+6 < 256 ? Hb+6 : 256;
    int tR = Hb+4 < 256 ? Hb+4 : 256;
    int lR = Hb+2 < 256 ? Hb+2 : 256;
    unsigned short* u  = (unsigned short*)alloc((size_t)nbat*64*uR*256*8);
    unsigned short* t4 = (unsigned short*)alloc((size_t)nbat*128*tR*256*8);
    unsigned short* h2 = (unsigned short*)alloc((size_t)nbat*127*lR*256*8);
    float* Sp = (float*)alloc((size_t)nbat*NCH*tR*256*4);
    float* Lm = (float*)alloc((size_t)nbat*lR*256*4);
    // v aliases t4: t4 dead after k_mix; v = nbat*128*orows*256*4 <= t4 size for all cfgs
    unsigned int* v = (unsigned int*)t4;

    k_coef<<<1, 512, 0, stream>>>(wlp1, whp1, wlp2, wld, whd, winP, winD, wout,
                                  ahp1, WLP, WLN, WHP, WHN, WLD2, WHD2, wDp, WPb, BtP);

    for (int b0 = 0; b0 < 2; b0 += nbat){
        for (int a = 0; a < 256; a += Hb){
            int ur0 = a-3 > 0 ? a-3 : 0;  int ur1 = a+Hb+3 < 256 ? a+Hb+3 : 256;
            int tr0 = a-2 > 0 ? a-2 : 0;  int tr1 = a+Hb+2 < 256 ? a+Hb+2 : 256;
            int lr0 = a-1 > 0 ? a-1 : 0;  int lr1 = a+Hb+1 < 256 ? a+Hb+1 : 256;
            int urows = ur1-ur0, trows = tr1-tr0, lrows = lr1-lr0;
            int orows = (a+Hb < 256 ? a+Hb : 256) - a;
            k_pconv<<<nbat*urows*4, 256, 0, stream>>>(x, WPb, u, b0, ur0, urows, uR);
            k_dw  <<<nbat*trows*NCH, 256, 0, stream>>>(u, wDp, t4, Sp, tr0, trows, ur0, urows, uR, tR, nbat);
            k_box <<<nbat*lrows, 256, 0, stream>>>(Sp, Lm, lr0, lrows, tr0, tR, lR, nbat);
            k_mix <<<nbat*lrows*4, 256, 0, stream>>>(t4, Lm, whp1, whp2, ahp1, h2, lr0, lrows, tr0, tR, lR);
            k_outv<<<nbat*orows*16, 256, 0, stream>>>(h2, Lm, WLP, WLN, WHP, WHN, WLD2, WHD2,
                                                      v, a, orows, lr0, lR);
            k_proj<<<nbat*orows, 256, 0, stream>>>(v, BtP, x, out, b0, a, orows);
        }
    }
}

// Round 7
// 303.939 us; speedup vs baseline: 6.5232x; 1.1794x over previous
//
#include <hip/hip_runtime.h>
#include <hip/hip_bf16.h>

#define HW 65536
#define NCH 8   // channel chunks in k_dw

typedef __attribute__((ext_vector_type(8))) short bf16x8;
typedef __attribute__((ext_vector_type(4))) float f32x4;

__device__ __forceinline__ float bfu(unsigned short u){
    return __uint_as_float(((unsigned int)u) << 16);
}
__device__ __forceinline__ float bflo(unsigned int u){
    return __uint_as_float(u << 16);
}
__device__ __forceinline__ float bfhi(unsigned int u){
    return __uint_as_float(u & 0xffff0000u);
}
__device__ __forceinline__ unsigned short f2bu(float f){
    unsigned int u = __float_as_uint(f);
    unsigned int r = (u + 0x7fffu + ((u >> 16) & 1u)) >> 16;
    return (unsigned short)r;
}

// ---------------- K0: precompute coefficient tables ----------------
__global__ void k_coef(const float* __restrict__ wlp1, const float* __restrict__ whp1,
                       const float* __restrict__ wlp2,
                       const float* __restrict__ wld, const float* __restrict__ whd,
                       const float* __restrict__ winP, const float* __restrict__ winD,
                       const float* __restrict__ wout,
                       float* __restrict__ ahp1s,
                       float* __restrict__ WLP, float* __restrict__ WLN,
                       float* __restrict__ WHP, float* __restrict__ WHN,
                       float* __restrict__ WLD2, float* __restrict__ WHD2,
                       float* __restrict__ wDp,
                       unsigned short* __restrict__ WPb, unsigned short* __restrict__ BtP){
    __shared__ float aL[508], cp[508], cn[508], ah[508];
    int t = threadIdx.x;
    if (t < 508){
        int g = t >> 2, o = t & 3;
        float s = 0.f, s2 = 0.f;
        for (int i = 0; i < 4; ++i){ s += wlp1[g*16 + o*4 + i]; s2 += whp1[g*16 + o*4 + i]; }
        aL[t] = s; ah[t] = s2;
    }
    __syncthreads();
    if (t < 508){
        int g = t >> 2, o = t & 3;
        float p = 0.f, n = 0.f;
        for (int k = 0; k < 4; ++k){
            int idx = 4*g + k;                    // shuffled position
            int inv = (idx % 127)*4 + idx/127;    // original channel
            float av = aL[inv];
            float w2 = wlp2[g*16 + o*4 + k];
            p += w2 * fmaxf(av, 0.f);
            n += w2 * fminf(av, 0.f);
        }
        cp[t] = p; cn[t] = n;
        // ahp1 in shuffled order: ahp1s[idx] = ahp1[inv(idx)]
        int inv = (t % 127)*4 + t/127;
        ahp1s[t] = ah[inv];
    }
    __syncthreads();
    for (int idx = t; idx < 127*9; idx += blockDim.x){
        int g = idx/9, q = idx%9;
        float lp=0.f, ln=0.f, hp=0.f, hn=0.f;
        for (int i = 0; i < 4; ++i){
            int ch = 4*g + i;
            if (ch < 254){ float w = wld[g*36 + i*9 + q]; lp += w*cp[ch]; ln += w*cn[ch]; }
            else         { float w = whd[g*36 + i*9 + q]; hp += w*cp[ch]; hn += w*cn[ch]; }
        }
        WLP[idx]=lp; WLN[idx]=ln; WHP[idx]=hp; WHN[idx]=hn;
    }
    for (int idx = t; idx < 127*36; idx += blockDim.x){
        int g = idx/36, r = idx%36; int i = r/9;
        int ch = 4*g + i;
        WLD2[idx] = (ch >= 254) ? wld[idx] : 0.f;
        WHD2[idx] = (ch <  254) ? whd[idx] : 0.f;
    }
    // wDp: [512 tch][9], zero-padded winD (508x9)
    for (int idx = t; idx < 512*9; idx += blockDim.x){
        int ch = idx/9, q = idx - ch*9;
        wDp[idx] = (ch < 508) ? winD[ch*9 + q] : 0.f;
    }
    // WPb: [256 o][64 k] bf16, zero-padded winP
    for (int idx = t; idx < 256*64; idx += blockDim.x){
        int o = idx >> 6, k = idx & 63;
        float vv = (o < 254 && k < 48) ? winP[o*48 + k] : 0.f;
        WPb[idx] = f2bu(vv);
    }
    // BtP: [48 n][256 k] bf16; k=2g -> wout[n][g] (l-part), k=2g+1 -> wout[n][127+g] (h-part)
    for (int idx = t; idx < 48*256; idx += blockDim.x){
        int n = idx >> 8, k = idx & 255;
        int g = k >> 1;
        float vv = (g < 127) ? ((k & 1) ? wout[n*254 + 127 + g] : wout[n*254 + g]) : 0.f;
        BtP[idx] = f2bu(vv);
    }
}

// ---------------- K1a: u = w_inP @ x (1x1 48->254) via MFMA, quad-layout output ----------------
// block = 64 px (quarter row), 4 waves x 16 px, 16 N-tiles each
__global__ __launch_bounds__(256) void k_pconv(const float* __restrict__ x,
        const unsigned short* __restrict__ WPb, unsigned short* __restrict__ u,
        int b0, int ur0, int urows, int uR){
    __shared__ unsigned short BtS[256*72];   // 36864 B; epilogue overlays [64px][260 u16]=33280 B
    int t = threadIdx.x;
    for (int i = t; i < 256*64; i += 256){
        int o = i >> 6, k = i & 63;
        BtS[o*72 + k] = WPb[i];
    }
    int bpb = urows*4;
    int bi = blockIdx.x / bpb;
    int r  = blockIdx.x - bi*bpb;
    int lr = r >> 2, quarter = r & 3;
    int b = b0 + bi;
    int grow = ur0 + lr;
    const float* xb = x + (size_t)b*48*HW + (size_t)grow*256 + quarter*64;
    int w = t >> 6, lane = t & 63;
    int px = w*16 + (lane & 15);
    int k0 = (lane >> 4)*8;
    bf16x8 afr[2];
    #pragma unroll
    for (int kk = 0; kk < 2; ++kk){
        #pragma unroll
        for (int j = 0; j < 8; ++j){
            int k = kk*32 + k0 + j;
            float vv = (k < 48) ? xb[(size_t)k*HW + px] : 0.f;
            afr[kk][j] = (short)f2bu(vv);
        }
    }
    __syncthreads();
    f32x4 acc[16];
    #pragma unroll
    for (int nt = 0; nt < 16; ++nt) acc[nt] = (f32x4){0.f,0.f,0.f,0.f};
    #pragma unroll
    for (int kk = 0; kk < 2; ++kk){
        #pragma unroll
        for (int nt = 0; nt < 16; ++nt){
            bf16x8 bfr = *reinterpret_cast<const bf16x8*>(&BtS[(nt*16 + (lane&15))*72 + kk*32 + k0]);
            acc[nt] = __builtin_amdgcn_mfma_f32_16x16x32_bf16(afr[kk], bfr, acc[nt], 0, 0, 0);
        }
    }
    __syncthreads();   // BtS dead -> reuse as epilogue buffer, stride 260
    unsigned short* E = BtS;
    #pragma unroll
    for (int nt = 0; nt < 16; ++nt){
        #pragma unroll
        for (int rg = 0; rg < 4; ++rg){
            int epx = w*16 + (lane>>4)*4 + rg;
            int eo  = nt*16 + (lane&15);
            E[epx*260 + eo] = f2bu(acc[nt][rg]);
        }
    }
    __syncthreads();
    int spx = t & 63;
    ushort4* ub4 = (ushort4*)u + (size_t)bi*64*uR*256 + (size_t)lr*256 + quarter*64 + spx;
    size_t cs = (size_t)uR*256;
    int og = t >> 6;
    #pragma unroll
    for (int j = 0; j < 16; ++j){
        int qd = og*16 + j;
        ushort4 q4 = *reinterpret_cast<const ushort4*>(&E[spx*260 + 4*qd]);
        ub4[(size_t)qd*cs] = q4;
    }
}

// ---------------- K1b: depthwise 3x3 x2 + relu + channel-sum + fused h-g1x1 -> shuffled d1s ----------------
__global__ __launch_bounds__(256) void k_dw(const unsigned short* __restrict__ u,
        const float* __restrict__ wDp, const float* __restrict__ whp1,
        unsigned short* __restrict__ d1s, float* __restrict__ Sp,
        int tr0, int trows, int ur0, int urows, int uR, int tR, int nbat){
    int chunk = blockIdx.x & (NCH-1);
    int rb = blockIdx.x >> 3;
    int bi = rb / trows;
    int lr = rb - bi*trows;
    int grow = tr0 + lr;
    int xx = threadIdx.x;
    int lrow = grow - ur0;
    int lm = lrow-1 > 0 ? lrow-1 : 0;
    int lp = lrow+1 < urows-1 ? lrow+1 : urows-1;
    int xl = xx-1 > 0 ? xx-1 : 0;
    int xr_ = xx+1 < 255 ? xx+1 : 255;
    bool bym = grow>0, byp = grow<255, bxm = xx>0, bxp = xx<255;
    bool val[9] = { bym&&bxm, bym, bym&&bxp,  bxm, true, bxp,  byp&&bxm, byp, byp&&bxp };
    int off[9] = { lm*256+xl, lm*256+xx, lm*256+xr_,
                   lrow*256+xl, lrow*256+xx, lrow*256+xr_,
                   lp*256+xl, lp*256+xx, lp*256+xr_ };
    const uint2* ub = (const uint2*)u + (size_t)bi*64*uR*256;
    size_t ucs = (size_t)uR*256;
    unsigned short* db = d1s + (size_t)bi*127*tR*256*4 + ((size_t)lr*256 + xx)*4;
    size_t dcs = (size_t)tR*256*4;   // plane stride in u16
    float ssum = 0.f;
    int qd0 = chunk*8;
    for (int qd = qd0; qd < qd0+8; ++qd){
        const uint2* up = ub + (size_t)qd*ucs;
        float v0[9], v1[9], v2[9], v3[9];
        #pragma unroll
        for (int q = 0; q < 9; ++q){
            uint2 rv = up[off[q]];
            unsigned int rx = val[q] ? rv.x : 0u;
            unsigned int ry = val[q] ? rv.y : 0u;
            v0[q] = bflo(rx); v1[q] = bfhi(rx);
            v2[q] = bflo(ry); v3[q] = bfhi(ry);
        }
        const float* w = wDp + (size_t)qd*72;
        float o0=0.f,o1=0.f,o2=0.f,o3=0.f,o4=0.f,o5=0.f,o6=0.f,o7=0.f;
        #pragma unroll
        for (int q = 0; q < 9; ++q){
            o0 = fmaf(w[q],    v0[q], o0);
            o1 = fmaf(w[9+q],  v0[q], o1);
            o2 = fmaf(w[18+q], v1[q], o2);
            o3 = fmaf(w[27+q], v1[q], o3);
            o4 = fmaf(w[36+q], v2[q], o4);
            o5 = fmaf(w[45+q], v2[q], o5);
            o6 = fmaf(w[54+q], v3[q], o6);
            o7 = fmaf(w[63+q], v3[q], o7);
        }
        o0=fmaxf(o0,0.f); o1=fmaxf(o1,0.f); o2=fmaxf(o2,0.f); o3=fmaxf(o3,0.f);
        o4=fmaxf(o4,0.f); o5=fmaxf(o5,0.f); o6=fmaxf(o6,0.f); o7=fmaxf(o7,0.f);
        ssum += ((o0+o1)+(o2+o3)) + ((o4+o5)+(o6+o7));
        // fused h-path first g1x1: d1[4*tq+oi] = dot4(whp1[tq,oi,:], t_quad(tq))
        // stored shuffled: channel ci -> idx = 127*(ci&3... ) precisely idx = 127*oi + tq
        int tq0 = 2*qd;
        {
            const float* w1 = whp1 + tq0*16;
            #pragma unroll
            for (int oi = 0; oi < 4; ++oi){
                float d = fmaf(w1[oi*4+0], o0, fmaf(w1[oi*4+1], o1,
                          fmaf(w1[oi*4+2], o2, w1[oi*4+3]*o3)));
                int idx = 127*oi + tq0;
                db[(size_t)(idx>>2)*dcs + (idx&3)] = f2bu(d);
            }
        }
        int tq1 = tq0 + 1;
        if (tq1 < 127){
            const float* w1 = whp1 + tq1*16;
            #pragma unroll
            for (int oi = 0; oi < 4; ++oi){
                float d = fmaf(w1[oi*4+0], o4, fmaf(w1[oi*4+1], o5,
                          fmaf(w1[oi*4+2], o6, w1[oi*4+3]*o7)));
                int idx = 127*oi + tq1;
                db[(size_t)(idx>>2)*dcs + (idx&3)] = f2bu(d);
            }
        }
    }
    Sp[((size_t)(chunk*nbat + bi)*tR + lr)*256 + xx] = ssum * (1.f/9.f);
}

// ---------------- K2: sum chunks + 3x3 box with edge clamp ----------------
__global__ __launch_bounds__(256) void k_box(const float* __restrict__ Sp, float* __restrict__ Lm,
        int lr0, int lrows, int tr0, int tR, int lR, int nbat){
    int bi = blockIdx.x / lrows;
    int lr = blockIdx.x - bi*lrows;
    int grow = lr0 + lr;
    int xx = threadIdx.x;
    int g0 = (grow-1 > 0 ? grow-1 : 0) - tr0, g1 = grow - tr0, g2 = (grow+1 < 255 ? grow+1 : 255) - tr0;
    int x0 = xx-1 > 0 ? xx-1 : 0, x2 = xx+1 < 255 ? xx+1 : 255;
    float s = 0.f;
    for (int ch = 0; ch < NCH; ++ch){
        const float* Sb = Sp + ((size_t)(ch*nbat + bi)*tR)*256;
        s += Sb[g0*256+x0]+Sb[g0*256+xx]+Sb[g0*256+x2]
           + Sb[g1*256+x0]+Sb[g1*256+xx]+Sb[g1*256+x2]
           + Sb[g2*256+x0]+Sb[g2*256+xx]+Sb[g2*256+x2];
    }
    Lm[(size_t)bi*lR*256 + (size_t)lr*256 + xx] = s;
}

// ---------------- K3: h-path finish: h1 = relu(d1s - Lv*ahp1s), h2 = g1x1(h1), 8 g-chunks ----------------
__global__ __launch_bounds__(256) void k_mix(const unsigned short* __restrict__ d1s,
        const float* __restrict__ Lm, const float* __restrict__ whp2,
        const float* __restrict__ ahp1s, unsigned short* __restrict__ h2,
        int lr0, int lrows, int tr0, int tR, int lR){
    int chunk = blockIdx.x & 7;
    int rb = blockIdx.x >> 3;
    int bi = rb / lrows;
    int lr = rb - bi*lrows;
    int grow = lr0 + lr;
    int xx = threadIdx.x;
    const ushort4* db = (const ushort4*)d1s + (size_t)bi*127*tR*256 + (size_t)(grow-tr0)*256 + xx;
    size_t dcs = (size_t)tR*256;
    ushort4* hb = (ushort4*)h2 + (size_t)bi*127*lR*256 + (size_t)lr*256 + xx;
    size_t hcs = (size_t)lR*256;
    float Lv = Lm[(size_t)bi*lR*256 + (size_t)lr*256 + xx];
    int g0 = chunk*16, gend = g0+16 < 127 ? g0+16 : 127;
    for (int g = g0; g < gend; ++g){
        ushort4 dq = db[(size_t)g*dcs];
        const float* as = ahp1s + 4*g;
        float h0 = fmaxf(fmaf(-Lv, as[0], bfu(dq.x)), 0.f);
        float h1 = fmaxf(fmaf(-Lv, as[1], bfu(dq.y)), 0.f);
        float hv2 = fmaxf(fmaf(-Lv, as[2], bfu(dq.z)), 0.f);
        float h3 = fmaxf(fmaf(-Lv, as[3], bfu(dq.w)), 0.f);
        const float* w2 = whp2 + g*16;
        float a0 = fmaf(w2[0], h0, fmaf(w2[1], h1, fmaf(w2[2], hv2, w2[3]*h3)));
        float a1 = fmaf(w2[4], h0, fmaf(w2[5], h1, fmaf(w2[6], hv2, w2[7]*h3)));
        float a2 = fmaf(w2[8], h0, fmaf(w2[9], h1, fmaf(w2[10], hv2, w2[11]*h3)));
        float a3 = fmaf(w2[12], h0, fmaf(w2[13], h1, fmaf(w2[14], hv2, w2[15]*h3)));
        ushort4 st; st.x=f2bu(a0); st.y=f2bu(a1); st.z=f2bu(a2); st.w=f2bu(a3);
        hb[(size_t)g*hcs] = st;
    }
}

// ---------------- K4a: grouped 3x3 + relu -> v (packed vl,vh per group), 16 g-chunks ----------------
__global__ __launch_bounds__(256) void k_outv(const unsigned short* __restrict__ h2,
     const float* __restrict__ Lm,
     const float* __restrict__ WLP, const float* __restrict__ WLN,
     const float* __restrict__ WHP, const float* __restrict__ WHN,
     const float* __restrict__ WLD2, const float* __restrict__ WHD2,
     unsigned int* __restrict__ v,
     int a, int orows, int lr0, int lR){
    int chunk = blockIdx.x & 15;
    int rb = blockIdx.x >> 4;
    int bi = rb / orows;
    int lr = rb - bi*orows;
    int grow = a + lr;
    int xx = threadIdx.x;
    const float* Lb = Lm + (size_t)bi*lR*256;
    float lqp[9], lqn[9], vm[9]; int hoff[9];
    #pragma unroll
    for (int q = 0; q < 9; ++q){
        int dy = q/3 - 1, dx = q%3 - 1;
        int yy = grow+dy, xc = xx+dx;
        bool vv = (yy>=0)&&(yy<256)&&(xc>=0)&&(xc<256);
        vm[q] = vv ? 1.f : 0.f;
        int o = vv ? ((yy-lr0)*256 + xc) : ((grow-lr0)*256 + xx);
        hoff[q] = o;
        float lv = vv ? Lb[o] : 0.f;
        bool pos = lv > 0.f;
        lqp[q] = pos ? lv : 0.f;
        lqn[q] = pos ? 0.f : lv;
    }
    const ushort4* hb = (const ushort4*)h2 + (size_t)bi*127*lR*256;
    size_t hcs = (size_t)lR*256;
    size_t ps = (size_t)orows*256;
    unsigned int* vb = v + (size_t)bi*128*ps + (size_t)lr*256 + xx;
    int g0 = chunk*8, gend = g0+8 < 127 ? g0+8 : 127;

    for (int g = g0; g < gend; ++g){
        float sl = 0.f, sh = 0.f;
        #pragma unroll
        for (int q = 0; q < 9; ++q){
            sl = fmaf(WLP[g*9+q], lqp[q], fmaf(WLN[g*9+q], lqn[q], sl));
            sh = fmaf(WHP[g*9+q], lqp[q], fmaf(WHN[g*9+q], lqn[q], sh));
        }
        const ushort4* hq = hb + (size_t)g*hcs;
        ushort4 rr[9];
        #pragma unroll
        for (int q = 0; q < 9; ++q) rr[q] = hq[hoff[q]];
        if (g >= 63){   // l-branch h2-sourced channels (4g+i >= 254)
            const float* w = WLD2 + g*36;
            #pragma unroll
            for (int q = 0; q < 9; ++q){
                float tv = fmaf(w[0*9+q], bfu(rr[q].x), fmaf(w[1*9+q], bfu(rr[q].y),
                           fmaf(w[2*9+q], bfu(rr[q].z), w[3*9+q]*bfu(rr[q].w))));
                sl = fmaf(vm[q], tv, sl);
            }
        }
        if (g <= 63){   // h-branch h2-sourced channels (4g+i < 254)
            const float* w = WHD2 + g*36;
            #pragma unroll
            for (int q = 0; q < 9; ++q){
                float tv = fmaf(w[0*9+q], bfu(rr[q].x), fmaf(w[1*9+q], bfu(rr[q].y),
                           fmaf(w[2*9+q], bfu(rr[q].z), w[3*9+q]*bfu(rr[q].w))));
                sh = fmaf(vm[q], tv, sh);
            }
        }
        unsigned int lo = f2bu(fmaxf(sl, 0.f));
        unsigned int hi = f2bu(fmaxf(sh, 0.f));
        vb[(size_t)g*ps] = lo | (hi << 16);
    }
    if (chunk == 15) vb[(size_t)127*ps] = 0u;   // zero pad plane (k=254,255)
}

// ---------------- K4b: out = v @ BtP^T + x via MFMA, fused residual ----------------
// block = 1 row (256 px), 4 waves x 64 px (4 M-tiles), 3 N-tiles, K=256
__global__ __launch_bounds__(256) void k_proj(const unsigned int* __restrict__ v,
        const unsigned short* __restrict__ BtP, const float* __restrict__ x,
        float* __restrict__ out, int b0, int a, int orows){
    __shared__ float EoS[256*49];            // 50176 B; Bt overlays first 26112 B
    unsigned short* Bt = (unsigned short*)EoS;   // [48 n][136 u16] stride 272 B
    int t = threadIdx.x;
    for (int i = t; i < 48*256; i += 256){
        int n = i >> 8, k = i & 255;
        Bt[n*136 + k] = BtP[i];
    }
    int bi = blockIdx.x / orows;
    int lr = blockIdx.x - bi*orows;
    int b = b0 + bi;
    size_t ps = (size_t)orows*256;
    const unsigned int* vb = v + (size_t)bi*128*ps + (size_t)lr*256;
    int lane = t & 63, w = t >> 6;
    int pxl = w*64;
    __syncthreads();
    f32x4 acc[4][3];
    #pragma unroll
    for (int m = 0; m < 4; ++m)
        #pragma unroll
        for (int nt = 0; nt < 3; ++nt) acc[m][nt] = (f32x4){0.f,0.f,0.f,0.f};
    #pragma unroll
    for (int ch = 0; ch < 4; ++ch){
        bf16x8 bfr[3][2];
        #pragma unroll
        for (int nt = 0; nt < 3; ++nt)
            #pragma unroll
            for (int kk = 0; kk < 2; ++kk)
                bfr[nt][kk] = *reinterpret_cast<const bf16x8*>(
                    &Bt[(nt*16 + (lane&15))*136 + ch*64 + kk*32 + (lane>>4)*8]);
        #pragma unroll
        for (int m = 0; m < 4; ++m){
            int px = pxl + m*16 + (lane & 15);
            #pragma unroll
            for (int kk = 0; kk < 2; ++kk){
                int pl0 = ch*32 + kk*16 + (lane>>4)*4;
                unsigned int p0 = vb[(size_t)(pl0+0)*ps + px];
                unsigned int p1 = vb[(size_t)(pl0+1)*ps + px];
                unsigned int p2 = vb[(size_t)(pl0+2)*ps + px];
                unsigned int p3 = vb[(size_t)(pl0+3)*ps + px];
                bf16x8 af;
                af[0]=(short)(p0&0xffff); af[1]=(short)(p0>>16);
                af[2]=(short)(p1&0xffff); af[3]=(short)(p1>>16);
                af[4]=(short)(p2&0xffff); af[5]=(short)(p2>>16);
                af[6]=(short)(p3&0xffff); af[7]=(short)(p3>>16);
                #pragma unroll
                for (int nt = 0; nt < 3; ++nt)
                    acc[m][nt] = __builtin_amdgcn_mfma_f32_16x16x32_bf16(af, bfr[nt][kk], acc[m][nt], 0, 0, 0);
            }
        }
    }
    __syncthreads();   // Bt dead -> epilogue buffer
    #pragma unroll
    for (int m = 0; m < 4; ++m){
        #pragma unroll
        for (int nt = 0; nt < 3; ++nt){
            #pragma unroll
            for (int rg = 0; rg < 4; ++rg){
                int epx = pxl + m*16 + (lane>>4)*4 + rg;
                int eo  = nt*16 + (lane&15);
                EoS[epx*49 + eo] = acc[m][nt][rg];
            }
        }
    }
    __syncthreads();
    int grow = a + lr;
    const float* xb = x + (size_t)b*48*HW + (size_t)grow*256 + t;
    float* ob = out + (size_t)b*48*HW + (size_t)grow*256 + t;
    #pragma unroll
    for (int o = 0; o < 48; ++o)
        ob[(size_t)o*HW] = EoS[t*49 + o] + xb[(size_t)o*HW];
}

extern "C" void kernel_launch(void* const* d_in, const int* in_sizes, int n_in,
                              void* d_out, int out_size, void* d_ws, size_t ws_size,
                              hipStream_t stream){
    const float* x    = (const float*)d_in[0];
    const float* winP = (const float*)d_in[1];
    const float* winD = (const float*)d_in[2];
    const float* wlp1 = (const float*)d_in[3];
    const float* whp1 = (const float*)d_in[4];
    const float* wlp2 = (const float*)d_in[5];
    const float* whp2 = (const float*)d_in[6];
    const float* wld  = (const float*)d_in[7];
    const float* whd  = (const float*)d_in[8];
    const float* wout = (const float*)d_in[9];
    float* out = (float*)d_out;

    char* ws = (char*)d_ws;
    size_t off = 0;
    auto alloc = [&](size_t bytes)->char*{
        char* pp = ws + off; off += (bytes + 255) & ~(size_t)255; return pp;
    };
    auto A = [](size_t bytes)->size_t{ return (bytes + 255) & ~(size_t)255; };

    float* ahp1s = (float*)alloc(508*4);
    float* WLP  = (float*)alloc(127*9*4);
    float* WLN  = (float*)alloc(127*9*4);
    float* WHP  = (float*)alloc(127*9*4);
    float* WHN  = (float*)alloc(127*9*4);
    float* WLD2 = (float*)alloc(127*36*4);
    float* WHD2 = (float*)alloc(127*36*4);
    float* wDp  = (float*)alloc(512*9*4);
    unsigned short* WPb = (unsigned short*)alloc(256*64*2);
    unsigned short* BtP = (unsigned short*)alloc(48*256*2);

    const int cfgs[7][2] = {{256,2},{128,2},{64,2},{64,1},{32,1},{16,1},{8,1}};
    int Hb = 8, nbat = 1;
    for (int ci = 0; ci < 7; ++ci){
        int hb = cfgs[ci][0], nb = cfgs[ci][1];
        int uR = hb+6 < 256 ? hb+6 : 256;
        int tR = hb+4 < 256 ? hb+4 : 256;
        int lR = hb+2 < 256 ? hb+2 : 256;
        size_t need = off;
        need += A((size_t)nb*64*uR*256*8);     // u (64 quads, ushort4)
        need += A((size_t)nb*127*tR*256*8);    // d1s (127 shuffled planes)
        need += A((size_t)nb*127*lR*256*8);    // h2
        need += A((size_t)nb*NCH*tR*256*4);    // Sp
        need += A((size_t)nb*lR*256*4);        // Lm
        if (need <= ws_size){ Hb = hb; nbat = nb; break; }
    }
    int uR = Hb+6 < 256 ? Hb+6 : 256;
    int tR = Hb+4 < 256 ? Hb+4 : 256;
    int lR = Hb+2 < 256 ? Hb+2 : 256;
    unsigned short* u   = (unsigned short*)alloc((size_t)nbat*64*uR*256*8);
    unsigned short* d1s = (unsigned short*)alloc((size_t)nbat*127*tR*256*8);
    unsigned short* h2  = (unsigned short*)alloc((size_t)nbat*127*lR*256*8);
    float* Sp = (float*)alloc((size_t)nbat*NCH*tR*256*4);
    float* Lm = (float*)alloc((size_t)nbat*lR*256*4);
    // v aliases d1s: d1s dead after k_mix; v = nbat*128*orows*256*4 <= d1s size for all cfgs
    unsigned int* v = (unsigned int*)d1s;

    k_coef<<<1, 512, 0, stream>>>(wlp1, whp1, wlp2, wld, whd, winP, winD, wout,
                                  ahp1s, WLP, WLN, WHP, WHN, WLD2, WHD2, wDp, WPb, BtP);

    for (int b0 = 0; b0 < 2; b0 += nbat){
        for (int a = 0; a < 256; a += Hb){
            int ur0 = a-3 > 0 ? a-3 : 0;  int ur1 = a+Hb+3 < 256 ? a+Hb+3 : 256;
            int tr0 = a-2 > 0 ? a-2 : 0;  int tr1 = a+Hb+2 < 256 ? a+Hb+2 : 256;
            int lr0 = a-1 > 0 ? a-1 : 0;  int lr1 = a+Hb+1 < 256 ? a+Hb+1 : 256;
            int urows = ur1-ur0, trows = tr1-tr0, lrows = lr1-lr0;
            int orows = (a+Hb < 256 ? a+Hb : 256) - a;
            k_pconv<<<nbat*urows*4, 256, 0, stream>>>(x, WPb, u, b0, ur0, urows, uR);
            k_dw  <<<nbat*trows*NCH, 256, 0, stream>>>(u, wDp, whp1, d1s, Sp, tr0, trows, ur0, urows, uR, tR, nbat);
            k_box <<<nbat*lrows, 256, 0, stream>>>(Sp, Lm, lr0, lrows, tr0, tR, lR, nbat);
            k_mix <<<nbat*lrows*8, 256, 0, stream>>>(d1s, Lm, whp2, ahp1s, h2, lr0, lrows, tr0, tR, lR);
            k_outv<<<nbat*orows*16, 256, 0, stream>>>(h2, Lm, WLP, WLN, WHP, WHN, WLD2, WHD2,
                                                      v, a, orows, lr0, lR);
            k_proj<<<nbat*orows, 256, 0, stream>>>(v, BtP, x, out, b0, a, orows);
        }
    }
}

// Round 8
// 272.195 us; speedup vs baseline: 7.2840x; 1.1166x over previous
//
#include <hip/hip_runtime.h>
#include <hip/hip_bf16.h>

#define HW 65536
#define NCH 8   // channel chunks in k_dw (4 octs each)

typedef __attribute__((ext_vector_type(8))) short bf16x8;
typedef __attribute__((ext_vector_type(4))) float f32x4;
typedef __attribute__((ext_vector_type(2))) short s16x2;

__device__ __forceinline__ float bfu(unsigned short u){
    return __uint_as_float(((unsigned int)u) << 16);
}
__device__ __forceinline__ float bflo(unsigned int u){
    return __uint_as_float(u << 16);
}
__device__ __forceinline__ float bfhi(unsigned int u){
    return __uint_as_float(u & 0xffff0000u);
}
__device__ __forceinline__ unsigned short f2bu(float f){
    unsigned int u = __float_as_uint(f);
    unsigned int r = (u + 0x7fffu + ((u >> 16) & 1u)) >> 16;
    return (unsigned short)r;
}
__device__ __forceinline__ unsigned int pk2(float a, float b){
    return (unsigned int)f2bu(a) | ((unsigned int)f2bu(b) << 16);
}

#if __has_builtin(__builtin_amdgcn_fdot2_f32_bf16)
__device__ __forceinline__ float DOT2B(s16x2 a, s16x2 b, float c){
    return __builtin_amdgcn_fdot2_f32_bf16(a, b, c, false);
}
#else
__device__ __forceinline__ float DOT2B(s16x2 a, s16x2 b, float c){
    return fmaf(bfu((unsigned short)a.x), bfu((unsigned short)b.x),
           fmaf(bfu((unsigned short)a.y), bfu((unsigned short)b.y), c));
}
#endif

// ---------------- K0: precompute coefficient tables ----------------
__global__ void k_coef(const float* __restrict__ wlp1, const float* __restrict__ whp1,
                       const float* __restrict__ wlp2,
                       const float* __restrict__ wld, const float* __restrict__ whd,
                       const float* __restrict__ winP, const float* __restrict__ winD,
                       const float* __restrict__ wout,
                       float* __restrict__ ahp1s,
                       unsigned int* __restrict__ WPNL, unsigned int* __restrict__ WPNH,
                       unsigned int* __restrict__ WLDpk, unsigned int* __restrict__ WHDpk,
                       float* __restrict__ wDp,
                       unsigned short* __restrict__ WPb, unsigned short* __restrict__ BtP){
    __shared__ float aL[508], cp[508], cn[508], ah[508];
    int t = threadIdx.x;
    if (t < 508){
        int g = t >> 2, o = t & 3;
        float s = 0.f, s2 = 0.f;
        for (int i = 0; i < 4; ++i){ s += wlp1[g*16 + o*4 + i]; s2 += whp1[g*16 + o*4 + i]; }
        aL[t] = s; ah[t] = s2;
    }
    __syncthreads();
    if (t < 508){
        int g = t >> 2, o = t & 3;
        float p = 0.f, n = 0.f;
        for (int k = 0; k < 4; ++k){
            int idx = 4*g + k;                    // shuffled position
            int inv = (idx % 127)*4 + idx/127;    // original channel
            float av = aL[inv];
            float w2 = wlp2[g*16 + o*4 + k];
            p += w2 * fmaxf(av, 0.f);
            n += w2 * fminf(av, 0.f);
        }
        cp[t] = p; cn[t] = n;
        int inv = (t % 127)*4 + t/127;
        ahp1s[t] = ah[inv];
    }
    __syncthreads();
    // analytic tables, packed (pos,neg) bf16 pairs
    for (int idx = t; idx < 127*9; idx += blockDim.x){
        int g = idx/9, q = idx%9;
        float lp=0.f, ln=0.f, hp=0.f, hn=0.f;
        for (int i = 0; i < 4; ++i){
            int ch = 4*g + i;
            if (ch < 254){ float w = wld[g*36 + i*9 + q]; lp += w*cp[ch]; ln += w*cn[ch]; }
            else         { float w = whd[g*36 + i*9 + q]; hp += w*cp[ch]; hn += w*cn[ch]; }
        }
        WPNL[idx] = pk2(lp, ln);
        WPNH[idx] = pk2(hp, hn);
    }
    // conv tables, packed channel-pair bf16 weights (masked to h2-sourced channels)
    for (int idx = t; idx < 127*18; idx += blockDim.x){
        int g = idx/18, r = idx%18; int q = r >> 1, hp_ = r & 1;
        int c0 = 4*g + 2*hp_, c1 = c0 + 1;
        float wl0 = (c0 >= 254) ? wld[g*36 + (2*hp_)*9 + q]   : 0.f;
        float wl1 = (c1 >= 254) ? wld[g*36 + (2*hp_+1)*9 + q] : 0.f;
        float wh0 = (c0 <  254) ? whd[g*36 + (2*hp_)*9 + q]   : 0.f;
        float wh1 = (c1 <  254) ? whd[g*36 + (2*hp_+1)*9 + q] : 0.f;
        WLDpk[idx] = pk2(wl0, wl1);
        WHDpk[idx] = pk2(wh0, wh1);
    }
    // wDp: [512 tch][9], zero-padded winD (508x9)
    for (int idx = t; idx < 512*9; idx += blockDim.x){
        int ch = idx/9, q = idx - ch*9;
        wDp[idx] = (ch < 508) ? winD[ch*9 + q] : 0.f;
    }
    // WPb: [256 o][64 k] bf16, zero-padded winP
    for (int idx = t; idx < 256*64; idx += blockDim.x){
        int o = idx >> 6, k = idx & 63;
        float vv = (o < 254 && k < 48) ? winP[o*48 + k] : 0.f;
        WPb[idx] = f2bu(vv);
    }
    // BtP: [48 n][256 k] bf16; k=2g -> wout[n][g] (l), k=2g+1 -> wout[n][127+g] (h)
    for (int idx = t; idx < 48*256; idx += blockDim.x){
        int n = idx >> 8, k = idx & 255;
        int g = k >> 1;
        float vv = (g < 127) ? ((k & 1) ? wout[n*254 + 127 + g] : wout[n*254 + g]) : 0.f;
        BtP[idx] = f2bu(vv);
    }
}

// ---------------- border zeroing ----------------
// u: [nbat*32 planes][uRp rows][258] uint4 ; h2: [nbat*127][lRp][258] ushort4 ; Lm: [nbat][lRp][258] f32
__global__ void k_pad0(uint4* __restrict__ u, ushort4* __restrict__ h2, float* __restrict__ Lm,
                       int uRp, int lRp, int nbat){
    int p = blockIdx.x, t = threadIdx.x;
    int nu = nbat*32, nh = nbat*127;
    if (p < nu){
        uint4* pl = u + (size_t)p*uRp*258;
        uint4 z = make_uint4(0,0,0,0);
        for (int i = t; i < 258; i += 256) pl[i] = z;
        for (int r = t; r < uRp; r += 256){ pl[(size_t)r*258] = z; pl[(size_t)r*258 + 257] = z; }
    } else if (p < nu + nh){
        ushort4* pl = h2 + (size_t)(p-nu)*lRp*258;
        ushort4 z; z.x=0; z.y=0; z.z=0; z.w=0;
        for (int i = t; i < 258; i += 256) pl[i] = z;
        for (int r = t; r < lRp; r += 256){ pl[(size_t)r*258] = z; pl[(size_t)r*258 + 257] = z; }
    } else {
        float* pl = Lm + (size_t)(p-nu-nh)*lRp*258;
        for (int i = t; i < 258; i += 256) pl[i] = 0.f;
        for (int r = t; r < lRp; r += 256){ pl[(size_t)r*258] = 0.f; pl[(size_t)r*258 + 257] = 0.f; }
    }
}
__global__ void k_padL(uint4* __restrict__ u, ushort4* __restrict__ h2, float* __restrict__ Lm,
                       int rowU, int rowH, int uRp, int lRp, int nbat){
    int p = blockIdx.x, t = threadIdx.x;
    int nu = nbat*32, nh = nbat*127;
    if (p < nu){
        uint4* pl = u + (size_t)p*uRp*258 + (size_t)rowU*258;
        uint4 z = make_uint4(0,0,0,0);
        for (int i = t; i < 258; i += 256) pl[i] = z;
    } else if (p < nu + nh){
        ushort4* pl = h2 + (size_t)(p-nu)*lRp*258 + (size_t)rowH*258;
        ushort4 z; z.x=0; z.y=0; z.z=0; z.w=0;
        for (int i = t; i < 258; i += 256) pl[i] = z;
    } else {
        float* pl = Lm + (size_t)(p-nu-nh)*lRp*258 + (size_t)rowH*258;
        for (int i = t; i < 258; i += 256) pl[i] = 0.f;
    }
}

// ---------------- K1a: u = w_inP @ x (1x1 48->254) via MFMA, padded oct layout ----------------
// block = 64 px (quarter row), 4 waves x 16 px, 16 N-tiles each
__global__ __launch_bounds__(256) void k_pconv(const float* __restrict__ x,
        const unsigned short* __restrict__ WPb, uint4* __restrict__ u,
        int b0, int ur0, int urows, int uRp){
    __shared__ unsigned short BtS[256*72];   // 36864 B; epilogue overlays [64px][264 u16]=33792 B
    int t = threadIdx.x;
    for (int i = t; i < 256*64; i += 256){
        int o = i >> 6, k = i & 63;
        BtS[o*72 + k] = WPb[i];
    }
    int bpb = urows*4;
    int bi = blockIdx.x / bpb;
    int r  = blockIdx.x - bi*bpb;
    int lr = r >> 2, quarter = r & 3;
    int b = b0 + bi;
    int grow = ur0 + lr;
    const float* xb = x + (size_t)b*48*HW + (size_t)grow*256 + quarter*64;
    int w = t >> 6, lane = t & 63;
    int px = w*16 + (lane & 15);
    int k0 = (lane >> 4)*8;
    bf16x8 afr[2];
    #pragma unroll
    for (int kk = 0; kk < 2; ++kk){
        #pragma unroll
        for (int j = 0; j < 8; ++j){
            int k = kk*32 + k0 + j;
            float vv = (k < 48) ? xb[(size_t)k*HW + px] : 0.f;
            afr[kk][j] = (short)f2bu(vv);
        }
    }
    __syncthreads();
    f32x4 acc[16];
    #pragma unroll
    for (int nt = 0; nt < 16; ++nt) acc[nt] = (f32x4){0.f,0.f,0.f,0.f};
    #pragma unroll
    for (int kk = 0; kk < 2; ++kk){
        #pragma unroll
        for (int nt = 0; nt < 16; ++nt){
            bf16x8 bfr = *reinterpret_cast<const bf16x8*>(&BtS[(nt*16 + (lane&15))*72 + kk*32 + k0]);
            acc[nt] = __builtin_amdgcn_mfma_f32_16x16x32_bf16(afr[kk], bfr, acc[nt], 0, 0, 0);
        }
    }
    __syncthreads();   // BtS dead -> epilogue buffer, stride 264 (16B-aligned rows)
    unsigned short* E = BtS;
    #pragma unroll
    for (int nt = 0; nt < 16; ++nt){
        #pragma unroll
        for (int rg = 0; rg < 4; ++rg){
            int epx = w*16 + (lane>>4)*4 + rg;
            int eo  = nt*16 + (lane&15);
            E[epx*264 + eo] = f2bu(acc[nt][rg]);
        }
    }
    __syncthreads();
    int spx = t & 63;
    size_t su = (size_t)uRp*258;
    uint4* ub = u + (size_t)bi*32*su + (size_t)(lr+1)*258 + (quarter*64 + spx + 1);
    int og = t >> 6;
    #pragma unroll
    for (int j = 0; j < 8; ++j){
        int od = og*8 + j;
        uint4 q4 = *reinterpret_cast<const uint4*>(&E[spx*264 + od*8]);
        ub[(size_t)od*su] = q4;
    }
}

// ---------------- K1b: depthwise 3x3 x2 + relu + channel-sum + fused h-g1x1 -> shuffled d1s ----------------
__global__ __launch_bounds__(256) void k_dw(const uint4* __restrict__ u,
        const float* __restrict__ wDp, const float* __restrict__ whp1,
        unsigned short* __restrict__ d1s, float* __restrict__ Sp,
        int tr0, int trows, int ur0, int uRp, int tR, int nbat){
    int chunk = blockIdx.x & (NCH-1);
    int rb = blockIdx.x >> 3;
    int bi = rb / trows;
    int lr = rb - bi*trows;
    int grow = tr0 + lr;
    int xx = threadIdx.x;
    int lrow = grow - ur0;
    size_t su = (size_t)uRp*258;
    const uint4* ubase = u + (size_t)bi*32*su + (size_t)lrow*258 + xx;
    unsigned short* db = d1s + (size_t)bi*127*tR*256*4 + ((size_t)lr*256 + xx)*4;
    size_t dcs = (size_t)tR*256*4;
    float ssum = 0.f;
    int od0 = chunk*4;
    for (int od = od0; od < od0+4; ++od){
        const uint4* up = ubase + (size_t)od*su;
        float o[16];
        #pragma unroll
        for (int j = 0; j < 16; ++j) o[j] = 0.f;
        #pragma unroll
        for (int q = 0; q < 9; ++q){
            uint4 rv = up[(q/3)*258 + (q%3)];
            float c0 = bflo(rv.x), c1 = bfhi(rv.x), c2 = bflo(rv.y), c3 = bfhi(rv.y);
            float c4 = bflo(rv.z), c5 = bfhi(rv.z), c6 = bflo(rv.w), c7 = bfhi(rv.w);
            const float* wq = wDp + (size_t)(16*od)*9 + q;
            o[0]  = fmaf(wq[0],   c0, o[0]);
            o[1]  = fmaf(wq[9],   c0, o[1]);
            o[2]  = fmaf(wq[18],  c1, o[2]);
            o[3]  = fmaf(wq[27],  c1, o[3]);
            o[4]  = fmaf(wq[36],  c2, o[4]);
            o[5]  = fmaf(wq[45],  c2, o[5]);
            o[6]  = fmaf(wq[54],  c3, o[6]);
            o[7]  = fmaf(wq[63],  c3, o[7]);
            o[8]  = fmaf(wq[72],  c4, o[8]);
            o[9]  = fmaf(wq[81],  c4, o[9]);
            o[10] = fmaf(wq[90],  c5, o[10]);
            o[11] = fmaf(wq[99],  c5, o[11]);
            o[12] = fmaf(wq[108], c6, o[12]);
            o[13] = fmaf(wq[117], c6, o[13]);
            o[14] = fmaf(wq[126], c7, o[14]);
            o[15] = fmaf(wq[135], c7, o[15]);
        }
        #pragma unroll
        for (int j = 0; j < 16; ++j){ o[j] = fmaxf(o[j], 0.f); ssum += o[j]; }
        int tqb = 4*od;
        #pragma unroll
        for (int m = 0; m < 4; ++m){
            int tq = tqb + m;
            if (tq < 127){
                const float* w1 = whp1 + tq*16;
                #pragma unroll
                for (int oi = 0; oi < 4; ++oi){
                    float d = fmaf(w1[oi*4+0], o[4*m+0], fmaf(w1[oi*4+1], o[4*m+1],
                              fmaf(w1[oi*4+2], o[4*m+2], w1[oi*4+3]*o[4*m+3])));
                    int idx = 127*oi + tq;
                    db[(size_t)(idx>>2)*dcs + (idx&3)] = f2bu(d);
                }
            }
        }
    }
    Sp[((size_t)(chunk*nbat + bi)*tR + lr)*256 + xx] = ssum * (1.f/9.f);
}

// ---------------- K2: sum chunks + 3x3 box with edge clamp -> padded Lm ----------------
__global__ __launch_bounds__(256) void k_box(const float* __restrict__ Sp, float* __restrict__ Lm,
        int lr0, int lrows, int tr0, int tR, int a, int lRp, int nbat){
    int bi = blockIdx.x / lrows;
    int lr = blockIdx.x - bi*lrows;
    int grow = lr0 + lr;
    int xx = threadIdx.x;
    int g0 = (grow-1 > 0 ? grow-1 : 0) - tr0, g1 = grow - tr0, g2 = (grow+1 < 255 ? grow+1 : 255) - tr0;
    int x0 = xx-1 > 0 ? xx-1 : 0, x2 = xx+1 < 255 ? xx+1 : 255;
    float s = 0.f;
    for (int ch = 0; ch < NCH; ++ch){
        const float* Sb = Sp + ((size_t)(ch*nbat + bi)*tR)*256;
        s += Sb[g0*256+x0]+Sb[g0*256+xx]+Sb[g0*256+x2]
           + Sb[g1*256+x0]+Sb[g1*256+xx]+Sb[g1*256+x2]
           + Sb[g2*256+x0]+Sb[g2*256+xx]+Sb[g2*256+x2];
    }
    Lm[(size_t)bi*lRp*258 + (size_t)(grow-a+1)*258 + xx + 1] = s;
}

// ---------------- K3: h1 = relu(d1s - Lv*ahp1s), h2 = g1x1(h1) -> padded h2, 8 g-chunks ----------------
__global__ __launch_bounds__(256) void k_mix(const unsigned short* __restrict__ d1s,
        const float* __restrict__ Lm, const float* __restrict__ whp2,
        const float* __restrict__ ahp1s, unsigned short* __restrict__ h2,
        int lr0, int lrows, int tr0, int tR, int a, int lRp){
    int chunk = blockIdx.x & 7;
    int rb = blockIdx.x >> 3;
    int bi = rb / lrows;
    int lr = rb - bi*lrows;
    int grow = lr0 + lr;
    int xx = threadIdx.x;
    const ushort4* db = (const ushort4*)d1s + (size_t)bi*127*tR*256 + (size_t)(grow-tr0)*256 + xx;
    size_t dcs = (size_t)tR*256;
    size_t hcs = (size_t)lRp*258;
    int prow = grow - a + 1;
    ushort4* hb = (ushort4*)h2 + (size_t)bi*127*hcs + (size_t)prow*258 + xx + 1;
    float Lv = Lm[(size_t)bi*lRp*258 + (size_t)prow*258 + xx + 1];
    int g0 = chunk*16, gend = g0+16 < 127 ? g0+16 : 127;
    for (int g = g0; g < gend; ++g){
        ushort4 dq = db[(size_t)g*dcs];
        const float* as = ahp1s + 4*g;
        float h0 = fmaxf(fmaf(-Lv, as[0], bfu(dq.x)), 0.f);
        float h1 = fmaxf(fmaf(-Lv, as[1], bfu(dq.y)), 0.f);
        float hv2 = fmaxf(fmaf(-Lv, as[2], bfu(dq.z)), 0.f);
        float h3 = fmaxf(fmaf(-Lv, as[3], bfu(dq.w)), 0.f);
        const float* w2 = whp2 + g*16;
        float a0 = fmaf(w2[0], h0, fmaf(w2[1], h1, fmaf(w2[2], hv2, w2[3]*h3)));
        float a1 = fmaf(w2[4], h0, fmaf(w2[5], h1, fmaf(w2[6], hv2, w2[7]*h3)));
        float a2 = fmaf(w2[8], h0, fmaf(w2[9], h1, fmaf(w2[10], hv2, w2[11]*h3)));
        float a3 = fmaf(w2[12], h0, fmaf(w2[13], h1, fmaf(w2[14], hv2, w2[15]*h3)));
        ushort4 st; st.x=f2bu(a0); st.y=f2bu(a1); st.z=f2bu(a2); st.w=f2bu(a3);
        hb[(size_t)g*hcs] = st;
    }
}

// ---------------- K4a: grouped 3x3 + relu -> v (packed vl,vh), dot2, 16 g-chunks ----------------
__global__ __launch_bounds__(256) void k_outv(const uint2* __restrict__ h2,
     const float* __restrict__ Lm,
     const unsigned int* __restrict__ WPNL, const unsigned int* __restrict__ WPNH,
     const unsigned int* __restrict__ WLDpk, const unsigned int* __restrict__ WHDpk,
     unsigned int* __restrict__ v,
     int a, int orows, int lRp){
    int chunk = blockIdx.x & 15;
    int rb = blockIdx.x >> 4;
    int bi = rb / orows;
    int lr = rb - bi*orows;
    int xx = threadIdx.x;
    const float* Lb = Lm + (size_t)bi*lRp*258 + (size_t)lr*258 + xx;
    s16x2 lpk[9];
    #pragma unroll
    for (int q = 0; q < 9; ++q){
        float lv = Lb[(q/3)*258 + (q%3)];
        lpk[q] = __builtin_bit_cast(s16x2, pk2(fmaxf(lv,0.f), fminf(lv,0.f)));
    }
    size_t hcs = (size_t)lRp*258;
    const uint2* hb = h2 + (size_t)bi*127*hcs + (size_t)lr*258 + xx;
    size_t ps = (size_t)orows*256;
    unsigned int* vb = v + (size_t)bi*128*ps + (size_t)lr*256 + xx;
    const s16x2* WL  = (const s16x2*)WPNL;
    const s16x2* WH  = (const s16x2*)WPNH;
    const s16x2* WLD = (const s16x2*)WLDpk;
    const s16x2* WHD = (const s16x2*)WHDpk;
    int g0 = chunk*8, gend = g0+8 < 127 ? g0+8 : 127;

    for (int g = g0; g < gend; ++g){
        float sl0=0.f, sl1=0.f, sh0=0.f, sh1=0.f;
        #pragma unroll
        for (int q = 0; q < 9; ++q){
            if (q & 1){ sl1 = DOT2B(lpk[q], WL[g*9+q], sl1); sh1 = DOT2B(lpk[q], WH[g*9+q], sh1); }
            else      { sl0 = DOT2B(lpk[q], WL[g*9+q], sl0); sh0 = DOT2B(lpk[q], WH[g*9+q], sh0); }
        }
        const uint2* hq = hb + (size_t)g*hcs;
        uint2 rr[9];
        #pragma unroll
        for (int q = 0; q < 9; ++q) rr[q] = hq[(q/3)*258 + (q%3)];
        if (g >= 63){   // l-branch h2-sourced channels (4g+i >= 254)
            #pragma unroll
            for (int q = 0; q < 9; ++q){
                sl0 = DOT2B(__builtin_bit_cast(s16x2, rr[q].x), WLD[g*18+2*q],   sl0);
                sl1 = DOT2B(__builtin_bit_cast(s16x2, rr[q].y), WLD[g*18+2*q+1], sl1);
            }
        }
        if (g <= 63){   // h-branch h2-sourced channels (4g+i < 254)
            #pragma unroll
            for (int q = 0; q < 9; ++q){
                sh0 = DOT2B(__builtin_bit_cast(s16x2, rr[q].x), WHD[g*18+2*q],   sh0);
                sh1 = DOT2B(__builtin_bit_cast(s16x2, rr[q].y), WHD[g*18+2*q+1], sh1);
            }
        }
        unsigned int lo = f2bu(fmaxf(sl0+sl1, 0.f));
        unsigned int hi = f2bu(fmaxf(sh0+sh1, 0.f));
        vb[(size_t)g*ps] = lo | (hi << 16);
    }
    if (chunk == 15) vb[(size_t)127*ps] = 0u;   // zero pad plane (k=254,255)
}

// ---------------- K4b: out = v @ BtP^T + x via MFMA, fused residual ----------------
__global__ __launch_bounds__(256) void k_proj(const unsigned int* __restrict__ v,
        const unsigned short* __restrict__ BtP, const float* __restrict__ x,
        float* __restrict__ out, int b0, int a, int orows){
    __shared__ float EoS[256*49];            // 50176 B; Bt overlays first 26112 B
    unsigned short* Bt = (unsigned short*)EoS;   // [48 n][136 u16]
    int t = threadIdx.x;
    for (int i = t; i < 48*256; i += 256){
        int n = i >> 8, k = i & 255;
        Bt[n*136 + k] = BtP[i];
    }
    int bi = blockIdx.x / orows;
    int lr = blockIdx.x - bi*orows;
    int b = b0 + bi;
    size_t ps = (size_t)orows*256;
    const unsigned int* vb = v + (size_t)bi*128*ps + (size_t)lr*256;
    int lane = t & 63, w = t >> 6;
    int pxl = w*64;
    __syncthreads();
    f32x4 acc[4][3];
    #pragma unroll
    for (int m = 0; m < 4; ++m)
        #pragma unroll
        for (int nt = 0; nt < 3; ++nt) acc[m][nt] = (f32x4){0.f,0.f,0.f,0.f};
    #pragma unroll
    for (int ch = 0; ch < 4; ++ch){
        bf16x8 bfr[3][2];
        #pragma unroll
        for (int nt = 0; nt < 3; ++nt)
            #pragma unroll
            for (int kk = 0; kk < 2; ++kk)
                bfr[nt][kk] = *reinterpret_cast<const bf16x8*>(
                    &Bt[(nt*16 + (lane&15))*136 + ch*64 + kk*32 + (lane>>4)*8]);
        #pragma unroll
        for (int m = 0; m < 4; ++m){
            int px = pxl + m*16 + (lane & 15);
            #pragma unroll
            for (int kk = 0; kk < 2; ++kk){
                int pl0 = ch*32 + kk*16 + (lane>>4)*4;
                unsigned int p0 = vb[(size_t)(pl0+0)*ps + px];
                unsigned int p1 = vb[(size_t)(pl0+1)*ps + px];
                unsigned int p2 = vb[(size_t)(pl0+2)*ps + px];
                unsigned int p3 = vb[(size_t)(pl0+3)*ps + px];
                bf16x8 af;
                af[0]=(short)(p0&0xffff); af[1]=(short)(p0>>16);
                af[2]=(short)(p1&0xffff); af[3]=(short)(p1>>16);
                af[4]=(short)(p2&0xffff); af[5]=(short)(p2>>16);
                af[6]=(short)(p3&0xffff); af[7]=(short)(p3>>16);
                #pragma unroll
                for (int nt = 0; nt < 3; ++nt)
                    acc[m][nt] = __builtin_amdgcn_mfma_f32_16x16x32_bf16(af, bfr[nt][kk], acc[m][nt], 0, 0, 0);
            }
        }
    }
    __syncthreads();   // Bt dead -> epilogue buffer
    #pragma unroll
    for (int m = 0; m < 4; ++m){
        #pragma unroll
        for (int nt = 0; nt < 3; ++nt){
            #pragma unroll
            for (int rg = 0; rg < 4; ++rg){
                int epx = pxl + m*16 + (lane>>4)*4 + rg;
                int eo  = nt*16 + (lane&15);
                EoS[epx*49 + eo] = acc[m][nt][rg];
            }
        }
    }
    __syncthreads();
    int grow = a + lr;
    const float* xb = x + (size_t)b*48*HW + (size_t)grow*256 + t;
    float* ob = out + (size_t)b*48*HW + (size_t)grow*256 + t;
    #pragma unroll
    for (int o = 0; o < 48; ++o)
        ob[(size_t)o*HW] = EoS[t*49 + o] + xb[(size_t)o*HW];
}

extern "C" void kernel_launch(void* const* d_in, const int* in_sizes, int n_in,
                              void* d_out, int out_size, void* d_ws, size_t ws_size,
                              hipStream_t stream){
    const float* x    = (const float*)d_in[0];
    const float* winP = (const float*)d_in[1];
    const float* winD = (const float*)d_in[2];
    const float* wlp1 = (const float*)d_in[3];
    const float* whp1 = (const float*)d_in[4];
    const float* wlp2 = (const float*)d_in[5];
    const float* whp2 = (const float*)d_in[6];
    const float* wld  = (const float*)d_in[7];
    const float* whd  = (const float*)d_in[8];
    const float* wout = (const float*)d_in[9];
    float* out = (float*)d_out;

    char* ws = (char*)d_ws;
    size_t off = 0;
    auto alloc = [&](size_t bytes)->char*{
        char* pp = ws + off; off += (bytes + 255) & ~(size_t)255; return pp;
    };
    auto A = [](size_t bytes)->size_t{ return (bytes + 255) & ~(size_t)255; };

    float* ahp1s = (float*)alloc(508*4);
    unsigned int* WPNL  = (unsigned int*)alloc(127*9*4);
    unsigned int* WPNH  = (unsigned int*)alloc(127*9*4);
    unsigned int* WLDpk = (unsigned int*)alloc(127*18*4);
    unsigned int* WHDpk = (unsigned int*)alloc(127*18*4);
    float* wDp  = (float*)alloc(512*9*4);
    unsigned short* WPb = (unsigned short*)alloc(256*64*2);
    unsigned short* BtP = (unsigned short*)alloc(48*256*2);

    const int cfgs[7][2] = {{256,2},{128,2},{64,2},{64,1},{32,1},{16,1},{8,1}};
    int Hb = 8, nbat = 1;
    for (int ci = 0; ci < 7; ++ci){
        int hb = cfgs[ci][0], nb = cfgs[ci][1];
        int uRr = hb+6 < 256 ? hb+6 : 256;
        int tRr = hb+4 < 256 ? hb+4 : 256;
        size_t need = off;
        need += A((size_t)nb*32*(uRr+2)*258*16);   // u (padded oct layout)
        need += A((size_t)nb*127*tRr*256*8);       // d1s
        need += A((size_t)nb*127*(hb+2)*258*8);    // h2 (padded)
        need += A((size_t)nb*NCH*tRr*256*4);       // Sp
        need += A((size_t)nb*(hb+2)*258*4);        // Lm (padded)
        if (need <= ws_size){ Hb = hb; nbat = nb; break; }
    }
    int uR = Hb+6 < 256 ? Hb+6 : 256;
    int tR = Hb+4 < 256 ? Hb+4 : 256;
    int uRp = uR + 2;
    int lRp = Hb + 2;
    uint4* u   = (uint4*)alloc((size_t)nbat*32*uRp*258*16);
    unsigned short* d1s = (unsigned short*)alloc((size_t)nbat*127*tR*256*8);
    unsigned short* h2  = (unsigned short*)alloc((size_t)nbat*127*lRp*258*8);
    float* Sp = (float*)alloc((size_t)nbat*NCH*tR*256*4);
    float* Lm = (float*)alloc((size_t)nbat*lRp*258*4);
    // v aliases d1s: d1s dead after k_mix; v = nbat*128*orows*256*4 <= d1s size for all cfgs
    unsigned int* v = (unsigned int*)d1s;

    k_coef<<<1, 512, 0, stream>>>(wlp1, whp1, wlp2, wld, whd, winP, winD, wout,
                                  ahp1s, WPNL, WPNH, WLDpk, WHDpk, wDp, WPb, BtP);
    k_pad0<<<nbat*160, 256, 0, stream>>>(u, (ushort4*)h2, Lm, uRp, lRp, nbat);

    for (int b0 = 0; b0 < 2; b0 += nbat){
        for (int a = 0; a < 256; a += Hb){
            int ur0 = a-3 > 0 ? a-3 : 0;  int ur1 = a+Hb+3 < 256 ? a+Hb+3 : 256;
            int tr0 = a-2 > 0 ? a-2 : 0;  int tr1 = a+Hb+2 < 256 ? a+Hb+2 : 256;
            int lr0 = a-1 > 0 ? a-1 : 0;  int lr1 = a+Hb+1 < 256 ? a+Hb+1 : 256;
            int urows = ur1-ur0, trows = tr1-tr0, lrows = lr1-lr0;
            int orows = (a+Hb < 256 ? a+Hb : 256) - a;
            if (a + Hb >= 256)
                k_padL<<<nbat*160, 256, 0, stream>>>(u, (ushort4*)h2, Lm,
                                                     urows+1, orows+1, uRp, lRp, nbat);
            k_pconv<<<nbat*urows*4, 256, 0, stream>>>(x, WPb, u, b0, ur0, urows, uRp);
            k_dw  <<<nbat*trows*NCH, 256, 0, stream>>>(u, wDp, whp1, d1s, Sp, tr0, trows, ur0, uRp, tR, nbat);
            k_box <<<nbat*lrows, 256, 0, stream>>>(Sp, Lm, lr0, lrows, tr0, tR, a, lRp, nbat);
            k_mix <<<nbat*lrows*8, 256, 0, stream>>>(d1s, Lm, whp2, ahp1s, h2, lr0, lrows, tr0, tR, a, lRp);
            k_outv<<<nbat*orows*16, 256, 0, stream>>>((const uint2*)h2, Lm, WPNL, WPNH, WLDpk, WHDpk,
                                                      v, a, orows, lRp);
            k_proj<<<nbat*orows, 256, 0, stream>>>(v, BtP, x, out, b0, a, orows);
        }
    }
}

// Round 9
// 252.426 us; speedup vs baseline: 7.8545x; 1.0783x over previous
//
#include <hip/hip_runtime.h>
#include <hip/hip_bf16.h>

#define HW 65536
#define NCH 16   // channel chunks in k_dw (2 octs each)

typedef __attribute__((ext_vector_type(8))) short bf16x8;
typedef __attribute__((ext_vector_type(4))) float f32x4;
typedef __attribute__((ext_vector_type(2))) short s16x2;

__device__ __forceinline__ float bfu(unsigned short u){
    return __uint_as_float(((unsigned int)u) << 16);
}
__device__ __forceinline__ float bflo(unsigned int u){
    return __uint_as_float(u << 16);
}
__device__ __forceinline__ float bfhi(unsigned int u){
    return __uint_as_float(u & 0xffff0000u);
}
__device__ __forceinline__ unsigned short f2bu(float f){
    unsigned int u = __float_as_uint(f);
    unsigned int r = (u + 0x7fffu + ((u >> 16) & 1u)) >> 16;
    return (unsigned short)r;
}
__device__ __forceinline__ unsigned int pk2(float a, float b){
    return (unsigned int)f2bu(a) | ((unsigned int)f2bu(b) << 16);
}

#if __has_builtin(__builtin_amdgcn_fdot2_f32_bf16)
__device__ __forceinline__ float DOT2B(s16x2 a, s16x2 b, float c){
    return __builtin_amdgcn_fdot2_f32_bf16(a, b, c, false);
}
#else
__device__ __forceinline__ float DOT2B(s16x2 a, s16x2 b, float c){
    return fmaf(bfu((unsigned short)a.x), bfu((unsigned short)b.x),
           fmaf(bfu((unsigned short)a.y), bfu((unsigned short)b.y), c));
}
#endif

// ---------------- K0a: sequential coefficient core (1 block) ----------------
__global__ void k_coef1(const float* __restrict__ wlp1, const float* __restrict__ whp1,
                        const float* __restrict__ wlp2,
                        float* __restrict__ ahp1s,
                        float* __restrict__ cpG, float* __restrict__ cnG){
    __shared__ float aL[508], ah[508];
    int t = threadIdx.x;
    if (t < 508){
        int g = t >> 2, o = t & 3;
        float s = 0.f, s2 = 0.f;
        for (int i = 0; i < 4; ++i){ s += wlp1[g*16 + o*4 + i]; s2 += whp1[g*16 + o*4 + i]; }
        aL[t] = s; ah[t] = s2;
    }
    __syncthreads();
    if (t < 508){
        int g = t >> 2, o = t & 3;
        float p = 0.f, n = 0.f;
        for (int k = 0; k < 4; ++k){
            int idx = 4*g + k;                    // shuffled position
            int inv = (idx % 127)*4 + idx/127;    // original channel
            float av = aL[inv];
            float w2 = wlp2[g*16 + o*4 + k];
            p += w2 * fmaxf(av, 0.f);
            n += w2 * fminf(av, 0.f);
        }
        cpG[t] = p; cnG[t] = n;
        int inv = (t % 127)*4 + t/127;
        ahp1s[t] = ah[inv];
    }
}

// ---------------- K0b: parallel table fills (64 blocks, grid-strided) ----------------
__global__ void k_coef2(const float* __restrict__ wld, const float* __restrict__ whd,
                        const float* __restrict__ winP, const float* __restrict__ winD,
                        const float* __restrict__ wout,
                        const float* __restrict__ cp, const float* __restrict__ cn,
                        unsigned int* __restrict__ WPNL, unsigned int* __restrict__ WPNH,
                        unsigned int* __restrict__ WLDpk, unsigned int* __restrict__ WHDpk,
                        float* __restrict__ wDp,
                        unsigned short* __restrict__ WPb, unsigned short* __restrict__ BtP){
    int t0 = blockIdx.x*256 + threadIdx.x;
    int str = gridDim.x*256;
    // analytic tables, packed (pos,neg) bf16 pairs
    for (int idx = t0; idx < 127*9; idx += str){
        int g = idx/9, q = idx%9;
        float lp=0.f, ln=0.f, hp=0.f, hn=0.f;
        for (int i = 0; i < 4; ++i){
            int ch = 4*g + i;
            if (ch < 254){ float w = wld[g*36 + i*9 + q]; lp += w*cp[ch]; ln += w*cn[ch]; }
            else         { float w = whd[g*36 + i*9 + q]; hp += w*cp[ch]; hn += w*cn[ch]; }
        }
        WPNL[idx] = pk2(lp, ln);
        WPNH[idx] = pk2(hp, hn);
    }
    // conv tables, packed channel-pair bf16 weights (masked to h2-sourced channels)
    for (int idx = t0; idx < 127*18; idx += str){
        int g = idx/18, r = idx%18; int q = r >> 1, hp_ = r & 1;
        int c0 = 4*g + 2*hp_, c1 = c0 + 1;
        float wl0 = (c0 >= 254) ? wld[g*36 + (2*hp_)*9 + q]   : 0.f;
        float wl1 = (c1 >= 254) ? wld[g*36 + (2*hp_+1)*9 + q] : 0.f;
        float wh0 = (c0 <  254) ? whd[g*36 + (2*hp_)*9 + q]   : 0.f;
        float wh1 = (c1 <  254) ? whd[g*36 + (2*hp_+1)*9 + q] : 0.f;
        WLDpk[idx] = pk2(wl0, wl1);
        WHDpk[idx] = pk2(wh0, wh1);
    }
    // wDp: [512 tch][9], zero-padded winD (508x9)
    for (int idx = t0; idx < 512*9; idx += str){
        int ch = idx/9, q = idx - ch*9;
        wDp[idx] = (ch < 508) ? winD[ch*9 + q] : 0.f;
    }
    // WPb: [256 o][64 k] bf16, zero-padded winP
    for (int idx = t0; idx < 256*64; idx += str){
        int o = idx >> 6, k = idx & 63;
        float vv = (o < 254 && k < 48) ? winP[o*48 + k] : 0.f;
        WPb[idx] = f2bu(vv);
    }
    // BtP: [48 n][256 k] bf16; k=2g -> wout[n][g] (l), k=2g+1 -> wout[n][127+g] (h)
    for (int idx = t0; idx < 48*256; idx += str){
        int n = idx >> 8, k = idx & 255;
        int g = k >> 1;
        float vv = (g < 127) ? ((k & 1) ? wout[n*254 + 127 + g] : wout[n*254 + g]) : 0.f;
        BtP[idx] = f2bu(vv);
    }
}

// ---------------- border zeroing ----------------
// u: [nbat*32 planes][uRp rows][258] uint4 ; h2: [nbat*127][lRp][258] ushort4 ; Lm: [nbat][lRp][258] f32
__global__ void k_pad0(uint4* __restrict__ u, ushort4* __restrict__ h2, float* __restrict__ Lm,
                       int uRp, int lRp, int nbat){
    int p = blockIdx.x, t = threadIdx.x;
    int nu = nbat*32, nh = nbat*127;
    if (p < nu){
        uint4* pl = u + (size_t)p*uRp*258;
        uint4 z = make_uint4(0,0,0,0);
        for (int i = t; i < 258; i += 256) pl[i] = z;
        for (int r = t; r < uRp; r += 256){ pl[(size_t)r*258] = z; pl[(size_t)r*258 + 257] = z; }
    } else if (p < nu + nh){
        ushort4* pl = h2 + (size_t)(p-nu)*lRp*258;
        ushort4 z; z.x=0; z.y=0; z.z=0; z.w=0;
        for (int i = t; i < 258; i += 256) pl[i] = z;
        for (int r = t; r < lRp; r += 256){ pl[(size_t)r*258] = z; pl[(size_t)r*258 + 257] = z; }
    } else {
        float* pl = Lm + (size_t)(p-nu-nh)*lRp*258;
        for (int i = t; i < 258; i += 256) pl[i] = 0.f;
        for (int r = t; r < lRp; r += 256){ pl[(size_t)r*258] = 0.f; pl[(size_t)r*258 + 257] = 0.f; }
    }
}
__global__ void k_padL(uint4* __restrict__ u, ushort4* __restrict__ h2, float* __restrict__ Lm,
                       int rowU, int rowH, int uRp, int lRp, int nbat){
    int p = blockIdx.x, t = threadIdx.x;
    int nu = nbat*32, nh = nbat*127;
    if (p < nu){
        uint4* pl = u + (size_t)p*uRp*258 + (size_t)rowU*258;
        uint4 z = make_uint4(0,0,0,0);
        for (int i = t; i < 258; i += 256) pl[i] = z;
    } else if (p < nu + nh){
        ushort4* pl = h2 + (size_t)(p-nu)*lRp*258 + (size_t)rowH*258;
        ushort4 z; z.x=0; z.y=0; z.z=0; z.w=0;
        for (int i = t; i < 258; i += 256) pl[i] = z;
    } else {
        float* pl = Lm + (size_t)(p-nu-nh)*lRp*258 + (size_t)rowH*258;
        for (int i = t; i < 258; i += 256) pl[i] = 0.f;
    }
}

// ---------------- K1a: u = w_inP @ x (1x1 48->254) via MFMA, padded oct layout ----------------
// block = 64 px (quarter row), 4 waves x 16 px, 16 N-tiles each
__global__ __launch_bounds__(256) void k_pconv(const float* __restrict__ x,
        const unsigned short* __restrict__ WPb, uint4* __restrict__ u,
        int b0, int ur0, int urows, int uRp){
    __shared__ unsigned short BtS[256*72];   // 36864 B; epilogue overlays [64px][264 u16]=33792 B
    int t = threadIdx.x;
    for (int i = t; i < 256*64; i += 256){
        int o = i >> 6, k = i & 63;
        BtS[o*72 + k] = WPb[i];
    }
    int bpb = urows*4;
    int bi = blockIdx.x / bpb;
    int r  = blockIdx.x - bi*bpb;
    int lr = r >> 2, quarter = r & 3;
    int b = b0 + bi;
    int grow = ur0 + lr;
    const float* xb = x + (size_t)b*48*HW + (size_t)grow*256 + quarter*64;
    int w = t >> 6, lane = t & 63;
    int px = w*16 + (lane & 15);
    int k0 = (lane >> 4)*8;
    bf16x8 afr[2];
    #pragma unroll
    for (int kk = 0; kk < 2; ++kk){
        #pragma unroll
        for (int j = 0; j < 8; ++j){
            int k = kk*32 + k0 + j;
            float vv = (k < 48) ? xb[(size_t)k*HW + px] : 0.f;
            afr[kk][j] = (short)f2bu(vv);
        }
    }
    __syncthreads();
    f32x4 acc[16];
    #pragma unroll
    for (int nt = 0; nt < 16; ++nt) acc[nt] = (f32x4){0.f,0.f,0.f,0.f};
    #pragma unroll
    for (int kk = 0; kk < 2; ++kk){
        #pragma unroll
        for (int nt = 0; nt < 16; ++nt){
            bf16x8 bfr = *reinterpret_cast<const bf16x8*>(&BtS[(nt*16 + (lane&15))*72 + kk*32 + k0]);
            acc[nt] = __builtin_amdgcn_mfma_f32_16x16x32_bf16(afr[kk], bfr, acc[nt], 0, 0, 0);
        }
    }
    __syncthreads();   // BtS dead -> epilogue buffer, stride 264 (16B-aligned rows)
    unsigned short* E = BtS;
    #pragma unroll
    for (int nt = 0; nt < 16; ++nt){
        #pragma unroll
        for (int rg = 0; rg < 4; ++rg){
            int epx = w*16 + (lane>>4)*4 + rg;
            int eo  = nt*16 + (lane&15);
            E[epx*264 + eo] = f2bu(acc[nt][rg]);
        }
    }
    __syncthreads();
    int spx = t & 63;
    size_t su = (size_t)uRp*258;
    uint4* ub = u + (size_t)bi*32*su + (size_t)(lr+1)*258 + (quarter*64 + spx + 1);
    int og = t >> 6;
    #pragma unroll
    for (int j = 0; j < 8; ++j){
        int od = og*8 + j;
        uint4 q4 = *reinterpret_cast<const uint4*>(&E[spx*264 + od*8]);
        ub[(size_t)od*su] = q4;
    }
}

// ---------------- K1b: depthwise 3x3 x2 + relu + channel-sum + fused h-g1x1 -> shuffled d1s ----------------
__global__ __launch_bounds__(256) void k_dw(const uint4* __restrict__ u,
        const float* __restrict__ wDp, const float* __restrict__ whp1,
        unsigned short* __restrict__ d1s, float* __restrict__ Sp,
        int tr0, int trows, int ur0, int uRp, int tR, int nbat){
    int chunk = blockIdx.x & (NCH-1);
    int rb = blockIdx.x >> 4;
    int bi = rb / trows;
    int lr = rb - bi*trows;
    int grow = tr0 + lr;
    int xx = threadIdx.x;
    int lrow = grow - ur0;
    size_t su = (size_t)uRp*258;
    const uint4* ubase = u + (size_t)bi*32*su + (size_t)lrow*258 + xx;
    unsigned short* db = d1s + (size_t)bi*127*tR*256*4 + ((size_t)lr*256 + xx)*4;
    size_t dcs = (size_t)tR*256*4;
    float ssum = 0.f;
    int od0 = chunk*2;
    for (int od = od0; od < od0+2; ++od){
        const uint4* up = ubase + (size_t)od*su;
        float o[16];
        #pragma unroll
        for (int j = 0; j < 16; ++j) o[j] = 0.f;
        #pragma unroll
        for (int q = 0; q < 9; ++q){
            uint4 rv = up[(q/3)*258 + (q%3)];
            float c0 = bflo(rv.x), c1 = bfhi(rv.x), c2 = bflo(rv.y), c3 = bfhi(rv.y);
            float c4 = bflo(rv.z), c5 = bfhi(rv.z), c6 = bflo(rv.w), c7 = bfhi(rv.w);
            const float* wq = wDp + (size_t)(16*od)*9 + q;
            o[0]  = fmaf(wq[0],   c0, o[0]);
            o[1]  = fmaf(wq[9],   c0, o[1]);
            o[2]  = fmaf(wq[18],  c1, o[2]);
            o[3]  = fmaf(wq[27],  c1, o[3]);
            o[4]  = fmaf(wq[36],  c2, o[4]);
            o[5]  = fmaf(wq[45],  c2, o[5]);
            o[6]  = fmaf(wq[54],  c3, o[6]);
            o[7]  = fmaf(wq[63],  c3, o[7]);
            o[8]  = fmaf(wq[72],  c4, o[8]);
            o[9]  = fmaf(wq[81],  c4, o[9]);
            o[10] = fmaf(wq[90],  c5, o[10]);
            o[11] = fmaf(wq[99],  c5, o[11]);
            o[12] = fmaf(wq[108], c6, o[12]);
            o[13] = fmaf(wq[117], c6, o[13]);
            o[14] = fmaf(wq[126], c7, o[14]);
            o[15] = fmaf(wq[135], c7, o[15]);
        }
        #pragma unroll
        for (int j = 0; j < 16; ++j){ o[j] = fmaxf(o[j], 0.f); ssum += o[j]; }
        int tqb = 4*od;
        #pragma unroll
        for (int m = 0; m < 4; ++m){
            int tq = tqb + m;
            if (tq < 127){
                const float* w1 = whp1 + tq*16;
                #pragma unroll
                for (int oi = 0; oi < 4; ++oi){
                    float d = fmaf(w1[oi*4+0], o[4*m+0], fmaf(w1[oi*4+1], o[4*m+1],
                              fmaf(w1[oi*4+2], o[4*m+2], w1[oi*4+3]*o[4*m+3])));
                    int idx = 127*oi + tq;
                    db[(size_t)(idx>>2)*dcs + (idx&3)] = f2bu(d);
                }
            }
        }
    }
    Sp[((size_t)(chunk*nbat + bi)*tR + lr)*256 + xx] = ssum * (1.f/9.f);
}

// ---------------- K2: sum chunks + 3x3 box with edge clamp -> padded Lm ----------------
__global__ __launch_bounds__(256) void k_box(const float* __restrict__ Sp, float* __restrict__ Lm,
        int lr0, int lrows, int tr0, int tR, int a, int lRp, int nbat){
    int bi = blockIdx.x / lrows;
    int lr = blockIdx.x - bi*lrows;
    int grow = lr0 + lr;
    int xx = threadIdx.x;
    int g0 = (grow-1 > 0 ? grow-1 : 0) - tr0, g1 = grow - tr0, g2 = (grow+1 < 255 ? grow+1 : 255) - tr0;
    int x0 = xx-1 > 0 ? xx-1 : 0, x2 = xx+1 < 255 ? xx+1 : 255;
    float s = 0.f;
    for (int ch = 0; ch < NCH; ++ch){
        const float* Sb = Sp + ((size_t)(ch*nbat + bi)*tR)*256;
        s += Sb[g0*256+x0]+Sb[g0*256+xx]+Sb[g0*256+x2]
           + Sb[g1*256+x0]+Sb[g1*256+xx]+Sb[g1*256+x2]
           + Sb[g2*256+x0]+Sb[g2*256+xx]+Sb[g2*256+x2];
    }
    Lm[(size_t)bi*lRp*258 + (size_t)(grow-a+1)*258 + xx + 1] = s;
}

// ---------------- K3: h1 = relu(d1s - Lv*ahp1s), h2 = g1x1(h1) -> padded h2, 8 g-chunks ----------------
__global__ __launch_bounds__(256) void k_mix(const unsigned short* __restrict__ d1s,
        const float* __restrict__ Lm, const float* __restrict__ whp2,
        const float* __restrict__ ahp1s, unsigned short* __restrict__ h2,
        int lr0, int lrows, int tr0, int tR, int a, int lRp){
    int chunk = blockIdx.x & 7;
    int rb = blockIdx.x >> 3;
    int bi = rb / lrows;
    int lr = rb - bi*lrows;
    int grow = lr0 + lr;
    int xx = threadIdx.x;
    const ushort4* db = (const ushort4*)d1s + (size_t)bi*127*tR*256 + (size_t)(grow-tr0)*256 + xx;
    size_t dcs = (size_t)tR*256;
    size_t hcs = (size_t)lRp*258;
    int prow = grow - a + 1;
    ushort4* hb = (ushort4*)h2 + (size_t)bi*127*hcs + (size_t)prow*258 + xx + 1;
    float Lv = Lm[(size_t)bi*lRp*258 + (size_t)prow*258 + xx + 1];
    int g0 = chunk*16, gend = g0+16 < 127 ? g0+16 : 127;
    for (int g = g0; g < gend; ++g){
        ushort4 dq = db[(size_t)g*dcs];
        const float* as = ahp1s + 4*g;
        float h0 = fmaxf(fmaf(-Lv, as[0], bfu(dq.x)), 0.f);
        float h1 = fmaxf(fmaf(-Lv, as[1], bfu(dq.y)), 0.f);
        float hv2 = fmaxf(fmaf(-Lv, as[2], bfu(dq.z)), 0.f);
        float h3 = fmaxf(fmaf(-Lv, as[3], bfu(dq.w)), 0.f);
        const float* w2 = whp2 + g*16;
        float a0 = fmaf(w2[0], h0, fmaf(w2[1], h1, fmaf(w2[2], hv2, w2[3]*h3)));
        float a1 = fmaf(w2[4], h0, fmaf(w2[5], h1, fmaf(w2[6], hv2, w2[7]*h3)));
        float a2 = fmaf(w2[8], h0, fmaf(w2[9], h1, fmaf(w2[10], hv2, w2[11]*h3)));
        float a3 = fmaf(w2[12], h0, fmaf(w2[13], h1, fmaf(w2[14], hv2, w2[15]*h3)));
        ushort4 st; st.x=f2bu(a0); st.y=f2bu(a1); st.z=f2bu(a2); st.w=f2bu(a3);
        hb[(size_t)g*hcs] = st;
    }
}

// ---------------- K4a: grouped 3x3 + relu -> v (packed vl,vh), dot2, 16 g-chunks ----------------
__global__ __launch_bounds__(256) void k_outv(const uint2* __restrict__ h2,
     const float* __restrict__ Lm,
     const unsigned int* __restrict__ WPNL, const unsigned int* __restrict__ WPNH,
     const unsigned int* __restrict__ WLDpk, const unsigned int* __restrict__ WHDpk,
     unsigned int* __restrict__ v,
     int a, int orows, int lRp){
    int chunk = blockIdx.x & 15;
    int rb = blockIdx.x >> 4;
    int bi = rb / orows;
    int lr = rb - bi*orows;
    int xx = threadIdx.x;
    const float* Lb = Lm + (size_t)bi*lRp*258 + (size_t)lr*258 + xx;
    s16x2 lpk[9];
    #pragma unroll
    for (int q = 0; q < 9; ++q){
        float lv = Lb[(q/3)*258 + (q%3)];
        lpk[q] = __builtin_bit_cast(s16x2, pk2(fmaxf(lv,0.f), fminf(lv,0.f)));
    }
    size_t hcs = (size_t)lRp*258;
    const uint2* hb = h2 + (size_t)bi*127*hcs + (size_t)lr*258 + xx;
    size_t ps = (size_t)orows*256;
    unsigned int* vb = v + (size_t)bi*128*ps + (size_t)lr*256 + xx;
    const s16x2* WL  = (const s16x2*)WPNL;
    const s16x2* WH  = (const s16x2*)WPNH;
    const s16x2* WLD = (const s16x2*)WLDpk;
    const s16x2* WHD = (const s16x2*)WHDpk;
    int g0 = chunk*8, gend = g0+8 < 127 ? g0+8 : 127;

    for (int g = g0; g < gend; ++g){
        float sl0=0.f, sl1=0.f, sh0=0.f, sh1=0.f;
        #pragma unroll
        for (int q = 0; q < 9; ++q){
            if (q & 1){ sl1 = DOT2B(lpk[q], WL[g*9+q], sl1); sh1 = DOT2B(lpk[q], WH[g*9+q], sh1); }
            else      { sl0 = DOT2B(lpk[q], WL[g*9+q], sl0); sh0 = DOT2B(lpk[q], WH[g*9+q], sh0); }
        }
        const uint2* hq = hb + (size_t)g*hcs;
        uint2 rr[9];
        #pragma unroll
        for (int q = 0; q < 9; ++q) rr[q] = hq[(q/3)*258 + (q%3)];
        if (g >= 63){   // l-branch h2-sourced channels (4g+i >= 254)
            #pragma unroll
            for (int q = 0; q < 9; ++q){
                sl0 = DOT2B(__builtin_bit_cast(s16x2, rr[q].x), WLD[g*18+2*q],   sl0);
                sl1 = DOT2B(__builtin_bit_cast(s16x2, rr[q].y), WLD[g*18+2*q+1], sl1);
            }
        }
        if (g <= 63){   // h-branch h2-sourced channels (4g+i < 254)
            #pragma unroll
            for (int q = 0; q < 9; ++q){
                sh0 = DOT2B(__builtin_bit_cast(s16x2, rr[q].x), WHD[g*18+2*q],   sh0);
                sh1 = DOT2B(__builtin_bit_cast(s16x2, rr[q].y), WHD[g*18+2*q+1], sh1);
            }
        }
        unsigned int lo = f2bu(fmaxf(sl0+sl1, 0.f));
        unsigned int hi = f2bu(fmaxf(sh0+sh1, 0.f));
        vb[(size_t)g*ps] = lo | (hi << 16);
    }
    if (chunk == 15) vb[(size_t)127*ps] = 0u;   // zero pad plane (k=254,255)
}

// ---------------- K4b: out = v @ BtP^T + x via MFMA, fused residual ----------------
__global__ __launch_bounds__(256) void k_proj(const unsigned int* __restrict__ v,
        const unsigned short* __restrict__ BtP, const float* __restrict__ x,
        float* __restrict__ out, int b0, int a, int orows){
    __shared__ float EoS[256*49];            // 50176 B; Bt overlays first 26112 B
    unsigned short* Bt = (unsigned short*)EoS;   // [48 n][136 u16]
    int t = threadIdx.x;
    for (int i = t; i < 48*256; i += 256){
        int n = i >> 8, k = i & 255;
        Bt[n*136 + k] = BtP[i];
    }
    int bi = blockIdx.x / orows;
    int lr = blockIdx.x - bi*orows;
    int b = b0 + bi;
    size_t ps = (size_t)orows*256;
    const unsigned int* vb = v + (size_t)bi*128*ps + (size_t)lr*256;
    int lane = t & 63, w = t >> 6;
    int pxl = w*64;
    __syncthreads();
    f32x4 acc[4][3];
    #pragma unroll
    for (int m = 0; m < 4; ++m)
        #pragma unroll
        for (int nt = 0; nt < 3; ++nt) acc[m][nt] = (f32x4){0.f,0.f,0.f,0.f};
    #pragma unroll
    for (int ch = 0; ch < 4; ++ch){
        bf16x8 bfr[3][2];
        #pragma unroll
        for (int nt = 0; nt < 3; ++nt)
            #pragma unroll
            for (int kk = 0; kk < 2; ++kk)
                bfr[nt][kk] = *reinterpret_cast<const bf16x8*>(
                    &Bt[(nt*16 + (lane&15))*136 + ch*64 + kk*32 + (lane>>4)*8]);
        #pragma unroll
        for (int m = 0; m < 4; ++m){
            int px = pxl + m*16 + (lane & 15);
            #pragma unroll
            for (int kk = 0; kk < 2; ++kk){
                int pl0 = ch*32 + kk*16 + (lane>>4)*4;
                unsigned int p0 = vb[(size_t)(pl0+0)*ps + px];
                unsigned int p1 = vb[(size_t)(pl0+1)*ps + px];
                unsigned int p2 = vb[(size_t)(pl0+2)*ps + px];
                unsigned int p3 = vb[(size_t)(pl0+3)*ps + px];
                bf16x8 af;
                af[0]=(short)(p0&0xffff); af[1]=(short)(p0>>16);
                af[2]=(short)(p1&0xffff); af[3]=(short)(p1>>16);
                af[4]=(short)(p2&0xffff); af[5]=(short)(p2>>16);
                af[6]=(short)(p3&0xffff); af[7]=(short)(p3>>16);
                #pragma unroll
                for (int nt = 0; nt < 3; ++nt)
                    acc[m][nt] = __builtin_amdgcn_mfma_f32_16x16x32_bf16(af, bfr[nt][kk], acc[m][nt], 0, 0, 0);
            }
        }
    }
    __syncthreads();   // Bt dead -> epilogue buffer
    #pragma unroll
    for (int m = 0; m < 4; ++m){
        #pragma unroll
        for (int nt = 0; nt < 3; ++nt){
            #pragma unroll
            for (int rg = 0; rg < 4; ++rg){
                int epx = pxl + m*16 + (lane>>4)*4 + rg;
                int eo  = nt*16 + (lane&15);
                EoS[epx*49 + eo] = acc[m][nt][rg];
            }
        }
    }
    __syncthreads();
    int grow = a + lr;
    const float* xb = x + (size_t)b*48*HW + (size_t)grow*256 + t;
    float* ob = out + (size_t)b*48*HW + (size_t)grow*256 + t;
    #pragma unroll
    for (int o = 0; o < 48; ++o)
        ob[(size_t)o*HW] = EoS[t*49 + o] + xb[(size_t)o*HW];
}

extern "C" void kernel_launch(void* const* d_in, const int* in_sizes, int n_in,
                              void* d_out, int out_size, void* d_ws, size_t ws_size,
                              hipStream_t stream){
    const float* x    = (const float*)d_in[0];
    const float* winP = (const float*)d_in[1];
    const float* winD = (const float*)d_in[2];
    const float* wlp1 = (const float*)d_in[3];
    const float* whp1 = (const float*)d_in[4];
    const float* wlp2 = (const float*)d_in[5];
    const float* whp2 = (const float*)d_in[6];
    const float* wld  = (const float*)d_in[7];
    const float* whd  = (const float*)d_in[8];
    const float* wout = (const float*)d_in[9];
    float* out = (float*)d_out;

    char* ws = (char*)d_ws;
    size_t off = 0;
    auto alloc = [&](size_t bytes)->char*{
        char* pp = ws + off; off += (bytes + 255) & ~(size_t)255; return pp;
    };
    auto A = [](size_t bytes)->size_t{ return (bytes + 255) & ~(size_t)255; };

    float* ahp1s = (float*)alloc(508*4);
    float* cpG = (float*)alloc(508*4);
    float* cnG = (float*)alloc(508*4);
    unsigned int* WPNL  = (unsigned int*)alloc(127*9*4);
    unsigned int* WPNH  = (unsigned int*)alloc(127*9*4);
    unsigned int* WLDpk = (unsigned int*)alloc(127*18*4);
    unsigned int* WHDpk = (unsigned int*)alloc(127*18*4);
    float* wDp  = (float*)alloc(512*9*4);
    unsigned short* WPb = (unsigned short*)alloc(256*64*2);
    unsigned short* BtP = (unsigned short*)alloc(48*256*2);

    const int cfgs[7][2] = {{256,2},{128,2},{64,2},{64,1},{32,1},{16,1},{8,1}};
    int Hb = 8, nbat = 1;
    for (int ci = 0; ci < 7; ++ci){
        int hb = cfgs[ci][0], nb = cfgs[ci][1];
        int uRr = hb+6 < 256 ? hb+6 : 256;
        int tRr = hb+4 < 256 ? hb+4 : 256;
        size_t need = off;
        need += A((size_t)nb*32*(uRr+2)*258*16);   // u (padded oct layout)
        need += A((size_t)nb*127*tRr*256*8);       // d1s
        need += A((size_t)nb*127*(hb+2)*258*8);    // h2 (padded)
        need += A((size_t)nb*NCH*tRr*256*4);       // Sp
        need += A((size_t)nb*(hb+2)*258*4);        // Lm (padded)
        if (need <= ws_size){ Hb = hb; nbat = nb; break; }
    }
    int uR = Hb+6 < 256 ? Hb+6 : 256;
    int tR = Hb+4 < 256 ? Hb+4 : 256;
    int uRp = uR + 2;
    int lRp = Hb + 2;
    uint4* u   = (uint4*)alloc((size_t)nbat*32*uRp*258*16);
    unsigned short* d1s = (unsigned short*)alloc((size_t)nbat*127*tR*256*8);
    unsigned short* h2  = (unsigned short*)alloc((size_t)nbat*127*lRp*258*8);
    float* Sp = (float*)alloc((size_t)nbat*NCH*tR*256*4);
    float* Lm = (float*)alloc((size_t)nbat*lRp*258*4);
    // v aliases d1s: d1s dead after k_mix; v = nbat*128*orows*256*4 <= d1s size for all cfgs
    unsigned int* v = (unsigned int*)d1s;

    k_coef1<<<1, 512, 0, stream>>>(wlp1, whp1, wlp2, ahp1s, cpG, cnG);
    k_coef2<<<64, 256, 0, stream>>>(wld, whd, winP, winD, wout, cpG, cnG,
                                    WPNL, WPNH, WLDpk, WHDpk, wDp, WPb, BtP);
    k_pad0<<<nbat*160, 256, 0, stream>>>(u, (ushort4*)h2, Lm, uRp, lRp, nbat);

    for (int b0 = 0; b0 < 2; b0 += nbat){
        for (int a = 0; a < 256; a += Hb){
            int ur0 = a-3 > 0 ? a-3 : 0;  int ur1 = a+Hb+3 < 256 ? a+Hb+3 : 256;
            int tr0 = a-2 > 0 ? a-2 : 0;  int tr1 = a+Hb+2 < 256 ? a+Hb+2 : 256;
            int lr0 = a-1 > 0 ? a-1 : 0;  int lr1 = a+Hb+1 < 256 ? a+Hb+1 : 256;
            int urows = ur1-ur0, trows = tr1-tr0, lrows = lr1-lr0;
            int orows = (a+Hb < 256 ? a+Hb : 256) - a;
            if (a + Hb >= 256)
                k_padL<<<nbat*160, 256, 0, stream>>>(u, (ushort4*)h2, Lm,
                                                     urows+1, orows+1, uRp, lRp, nbat);
            k_pconv<<<nbat*urows*4, 256, 0, stream>>>(x, WPb, u, b0, ur0, urows, uRp);
            k_dw  <<<nbat*trows*NCH, 256, 0, stream>>>(u, wDp, whp1, d1s, Sp, tr0, trows, ur0, uRp, tR, nbat);
            k_box <<<nbat*lrows, 256, 0, stream>>>(Sp, Lm, lr0, lrows, tr0, tR, a, lRp, nbat);
            k_mix <<<nbat*lrows*8, 256, 0, stream>>>(d1s, Lm, whp2, ahp1s, h2, lr0, lrows, tr0, tR, a, lRp);
            k_outv<<<nbat*orows*16, 256, 0, stream>>>((const uint2*)h2, Lm, WPNL, WPNH, WLDpk, WHDpk,
                                                      v, a, orows, lRp);
            k_proj<<<nbat*orows, 256, 0, stream>>>(v, BtP, x, out, b0, a, orows);
        }
    }
}

// Round 10
// 205.063 us; speedup vs baseline: 9.6686x; 1.2310x over previous
//
#include <hip/hip_runtime.h>
#include <hip/hip_bf16.h>

#define HW 65536
#define NCH 16   // channel chunks in k_dw (2 octs each)

typedef __attribute__((ext_vector_type(8))) short bf16x8;
typedef __attribute__((ext_vector_type(4))) float f32x4;
typedef __attribute__((ext_vector_type(2))) short s16x2;

__device__ __forceinline__ float bfu(unsigned short u){
    return __uint_as_float(((unsigned int)u) << 16);
}
__device__ __forceinline__ float bflo(unsigned int u){
    return __uint_as_float(u << 16);
}
__device__ __forceinline__ float bfhi(unsigned int u){
    return __uint_as_float(u & 0xffff0000u);
}
__device__ __forceinline__ unsigned short f2bu(float f){
    unsigned int u = __float_as_uint(f);
    unsigned int r = (u + 0x7fffu + ((u >> 16) & 1u)) >> 16;
    return (unsigned short)r;
}
__device__ __forceinline__ unsigned int pk2(float a, float b){
    return (unsigned int)f2bu(a) | ((unsigned int)f2bu(b) << 16);
}

#if __has_builtin(__builtin_amdgcn_fdot2_f32_bf16)
__device__ __forceinline__ float DOT2B(s16x2 a, s16x2 b, float c){
    return __builtin_amdgcn_fdot2_f32_bf16(a, b, c, false);
}
#else
__device__ __forceinline__ float DOT2B(s16x2 a, s16x2 b, float c){
    return fmaf(bfu((unsigned short)a.x), bfu((unsigned short)b.x),
           fmaf(bfu((unsigned short)a.y), bfu((unsigned short)b.y), c));
}
#endif

// ---------------- K0a: sequential coefficient core (1 block) ----------------
__global__ void k_coef1(const float* __restrict__ wlp1, const float* __restrict__ whp1,
                        const float* __restrict__ wlp2,
                        float* __restrict__ ahp1s,
                        float* __restrict__ cpG, float* __restrict__ cnG){
    __shared__ float aL[508], ah[508];
    int t = threadIdx.x;
    if (t < 508){
        int g = t >> 2, o = t & 3;
        float s = 0.f, s2 = 0.f;
        for (int i = 0; i < 4; ++i){ s += wlp1[g*16 + o*4 + i]; s2 += whp1[g*16 + o*4 + i]; }
        aL[t] = s; ah[t] = s2;
    }
    __syncthreads();
    if (t < 508){
        int g = t >> 2, o = t & 3;
        float p = 0.f, n = 0.f;
        for (int k = 0; k < 4; ++k){
            int idx = 4*g + k;                    // shuffled position
            int inv = (idx % 127)*4 + idx/127;    // original channel
            float av = aL[inv];
            float w2 = wlp2[g*16 + o*4 + k];
            p += w2 * fmaxf(av, 0.f);
            n += w2 * fminf(av, 0.f);
        }
        cpG[t] = p; cnG[t] = n;
        int inv = (t % 127)*4 + t/127;
        ahp1s[t] = ah[inv];
    }
}

// ---------------- K0b: parallel table fills (64 blocks, grid-strided) ----------------
__global__ void k_coef2(const float* __restrict__ wld, const float* __restrict__ whd,
                        const float* __restrict__ winP, const float* __restrict__ winD,
                        const float* __restrict__ wout,
                        const float* __restrict__ cp, const float* __restrict__ cn,
                        unsigned int* __restrict__ WPNL, unsigned int* __restrict__ WPNH,
                        unsigned int* __restrict__ WLDpk, unsigned int* __restrict__ WHDpk,
                        float* __restrict__ wDp,
                        unsigned short* __restrict__ WPb, unsigned short* __restrict__ BtP){
    int t0 = blockIdx.x*256 + threadIdx.x;
    int str = gridDim.x*256;
    // analytic tables, packed (pos,neg) bf16 pairs
    for (int idx = t0; idx < 127*9; idx += str){
        int g = idx/9, q = idx%9;
        float lp=0.f, ln=0.f, hp=0.f, hn=0.f;
        for (int i = 0; i < 4; ++i){
            int ch = 4*g + i;
            if (ch < 254){ float w = wld[g*36 + i*9 + q]; lp += w*cp[ch]; ln += w*cn[ch]; }
            else         { float w = whd[g*36 + i*9 + q]; hp += w*cp[ch]; hn += w*cn[ch]; }
        }
        WPNL[idx] = pk2(lp, ln);
        WPNH[idx] = pk2(hp, hn);
    }
    // conv tables, packed channel-pair bf16 weights (masked to h2-sourced channels)
    for (int idx = t0; idx < 127*18; idx += str){
        int g = idx/18, r = idx%18; int q = r >> 1, hp_ = r & 1;
        int c0 = 4*g + 2*hp_, c1 = c0 + 1;
        float wl0 = (c0 >= 254) ? wld[g*36 + (2*hp_)*9 + q]   : 0.f;
        float wl1 = (c1 >= 254) ? wld[g*36 + (2*hp_+1)*9 + q] : 0.f;
        float wh0 = (c0 <  254) ? whd[g*36 + (2*hp_)*9 + q]   : 0.f;
        float wh1 = (c1 <  254) ? whd[g*36 + (2*hp_+1)*9 + q] : 0.f;
        WLDpk[idx] = pk2(wl0, wl1);
        WHDpk[idx] = pk2(wh0, wh1);
    }
    // wDp: [512 tch][9], zero-padded winD (508x9)
    for (int idx = t0; idx < 512*9; idx += str){
        int ch = idx/9, q = idx - ch*9;
        wDp[idx] = (ch < 508) ? winD[ch*9 + q] : 0.f;
    }
    // WPb: [256 o][64 k] bf16, zero-padded winP
    for (int idx = t0; idx < 256*64; idx += str){
        int o = idx >> 6, k = idx & 63;
        float vv = (o < 254 && k < 48) ? winP[o*48 + k] : 0.f;
        WPb[idx] = f2bu(vv);
    }
    // BtP: [48 n][256 k] bf16; k=2g -> wout[n][g] (l), k=2g+1 -> wout[n][127+g] (h)
    for (int idx = t0; idx < 48*256; idx += str){
        int n = idx >> 8, k = idx & 255;
        int g = k >> 1;
        float vv = (g < 127) ? ((k & 1) ? wout[n*254 + 127 + g] : wout[n*254 + g]) : 0.f;
        BtP[idx] = f2bu(vv);
    }
}

// ---------------- per-band border zeroing ----------------
// u: [nbat*32 planes][uRp rows][258] uint4 ; Lm: [nbat][lRp][258] f32
// u is re-zeroed every band (its buffer gets trashed by the v alias);
// Lm pad rows re-zeroed only at image top/bottom bands.
__global__ void k_padU(uint4* __restrict__ u, float* __restrict__ Lm,
                       int uRp, int lRp, int nbat, int zeroTop, int zeroBot){
    int p = blockIdx.x, t = threadIdx.x;
    int nu = nbat*32;
    if (p < nu){
        uint4* pl = u + (size_t)p*uRp*258;
        uint4 z = make_uint4(0,0,0,0);
        for (int i = t; i < 258; i += 256){ pl[i] = z; pl[(size_t)(uRp-1)*258 + i] = z; }
        for (int r = t; r < uRp; r += 256){ pl[(size_t)r*258] = z; pl[(size_t)r*258 + 257] = z; }
    } else {
        float* pl = Lm + (size_t)(p-nu)*lRp*258;
        if (zeroTop) for (int i = t; i < 258; i += 256) pl[i] = 0.f;
        if (zeroBot) for (int i = t; i < 258; i += 256) pl[(size_t)(lRp-1)*258 + i] = 0.f;
        for (int r = t; r < lRp; r += 256){ pl[(size_t)r*258] = 0.f; pl[(size_t)r*258 + 257] = 0.f; }
    }
}

// ---------------- K1a: u = w_inP @ x (1x1 48->254) via MFMA, padded oct layout ----------------
// block = 64 px (quarter row), 4 waves x 16 px, 16 N-tiles each
__global__ __launch_bounds__(256) void k_pconv(const float* __restrict__ x,
        const unsigned short* __restrict__ WPb, uint4* __restrict__ u,
        int b0, int ur0, int urows, int uRp){
    __shared__ unsigned short BtS[256*72];   // 36864 B; epilogue overlays [64px][264 u16]=33792 B
    int t = threadIdx.x;
    for (int i = t; i < 256*64; i += 256){
        int o = i >> 6, k = i & 63;
        BtS[o*72 + k] = WPb[i];
    }
    int bpb = urows*4;
    int bi = blockIdx.x / bpb;
    int r  = blockIdx.x - bi*bpb;
    int lr = r >> 2, quarter = r & 3;
    int b = b0 + bi;
    int grow = ur0 + lr;
    const float* xb = x + (size_t)b*48*HW + (size_t)grow*256 + quarter*64;
    int w = t >> 6, lane = t & 63;
    int px = w*16 + (lane & 15);
    int k0 = (lane >> 4)*8;
    bf16x8 afr[2];
    #pragma unroll
    for (int kk = 0; kk < 2; ++kk){
        #pragma unroll
        for (int j = 0; j < 8; ++j){
            int k = kk*32 + k0 + j;
            float vv = (k < 48) ? xb[(size_t)k*HW + px] : 0.f;
            afr[kk][j] = (short)f2bu(vv);
        }
    }
    __syncthreads();
    f32x4 acc[16];
    #pragma unroll
    for (int nt = 0; nt < 16; ++nt) acc[nt] = (f32x4){0.f,0.f,0.f,0.f};
    #pragma unroll
    for (int kk = 0; kk < 2; ++kk){
        #pragma unroll
        for (int nt = 0; nt < 16; ++nt){
            bf16x8 bfr = *reinterpret_cast<const bf16x8*>(&BtS[(nt*16 + (lane&15))*72 + kk*32 + k0]);
            acc[nt] = __builtin_amdgcn_mfma_f32_16x16x32_bf16(afr[kk], bfr, acc[nt], 0, 0, 0);
        }
    }
    __syncthreads();   // BtS dead -> epilogue buffer, stride 264 (16B-aligned rows)
    unsigned short* E = BtS;
    #pragma unroll
    for (int nt = 0; nt < 16; ++nt){
        #pragma unroll
        for (int rg = 0; rg < 4; ++rg){
            int epx = w*16 + (lane>>4)*4 + rg;
            int eo  = nt*16 + (lane&15);
            E[epx*264 + eo] = f2bu(acc[nt][rg]);
        }
    }
    __syncthreads();
    int spx = t & 63;
    size_t su = (size_t)uRp*258;
    uint4* ub = u + (size_t)bi*32*su + (size_t)(lr+1)*258 + (quarter*64 + spx + 1);
    int og = t >> 6;
    #pragma unroll
    for (int j = 0; j < 8; ++j){
        int od = og*8 + j;
        uint4 q4 = *reinterpret_cast<const uint4*>(&E[spx*264 + od*8]);
        ub[(size_t)od*su] = q4;
    }
}

// ---------------- K1b: depthwise 3x3 x2 + relu + channel-sum + fused h-g1x1 -> shuffled d1s ----------------
__global__ __launch_bounds__(256) void k_dw(const uint4* __restrict__ u,
        const float* __restrict__ wDp, const float* __restrict__ whp1,
        unsigned short* __restrict__ d1s, float* __restrict__ Sp,
        int tr0, int trows, int ur0, int uRp, int tR, int nbat){
    int chunk = blockIdx.x & (NCH-1);
    int rb = blockIdx.x >> 4;
    int bi = rb / trows;
    int lr = rb - bi*trows;
    int grow = tr0 + lr;
    int xx = threadIdx.x;
    int lrow = grow - ur0;
    size_t su = (size_t)uRp*258;
    const uint4* ubase = u + (size_t)bi*32*su + (size_t)lrow*258 + xx;
    unsigned short* db = d1s + (size_t)bi*127*tR*256*4 + ((size_t)lr*256 + xx)*4;
    size_t dcs = (size_t)tR*256*4;
    float ssum = 0.f;
    int od0 = chunk*2;
    for (int od = od0; od < od0+2; ++od){
        const uint4* up = ubase + (size_t)od*su;
        float o[16];
        #pragma unroll
        for (int j = 0; j < 16; ++j) o[j] = 0.f;
        #pragma unroll
        for (int q = 0; q < 9; ++q){
            uint4 rv = up[(q/3)*258 + (q%3)];
            float c0 = bflo(rv.x), c1 = bfhi(rv.x), c2 = bflo(rv.y), c3 = bfhi(rv.y);
            float c4 = bflo(rv.z), c5 = bfhi(rv.z), c6 = bflo(rv.w), c7 = bfhi(rv.w);
            const float* wq = wDp + (size_t)(16*od)*9 + q;
            o[0]  = fmaf(wq[0],   c0, o[0]);
            o[1]  = fmaf(wq[9],   c0, o[1]);
            o[2]  = fmaf(wq[18],  c1, o[2]);
            o[3]  = fmaf(wq[27],  c1, o[3]);
            o[4]  = fmaf(wq[36],  c2, o[4]);
            o[5]  = fmaf(wq[45],  c2, o[5]);
            o[6]  = fmaf(wq[54],  c3, o[6]);
            o[7]  = fmaf(wq[63],  c3, o[7]);
            o[8]  = fmaf(wq[72],  c4, o[8]);
            o[9]  = fmaf(wq[81],  c4, o[9]);
            o[10] = fmaf(wq[90],  c5, o[10]);
            o[11] = fmaf(wq[99],  c5, o[11]);
            o[12] = fmaf(wq[108], c6, o[12]);
            o[13] = fmaf(wq[117], c6, o[13]);
            o[14] = fmaf(wq[126], c7, o[14]);
            o[15] = fmaf(wq[135], c7, o[15]);
        }
        #pragma unroll
        for (int j = 0; j < 16; ++j){ o[j] = fmaxf(o[j], 0.f); ssum += o[j]; }
        int tqb = 4*od;
        #pragma unroll
        for (int m = 0; m < 4; ++m){
            int tq = tqb + m;
            if (tq < 127){
                const float* w1 = whp1 + tq*16;
                #pragma unroll
                for (int oi = 0; oi < 4; ++oi){
                    float d = fmaf(w1[oi*4+0], o[4*m+0], fmaf(w1[oi*4+1], o[4*m+1],
                              fmaf(w1[oi*4+2], o[4*m+2], w1[oi*4+3]*o[4*m+3])));
                    int idx = 127*oi + tq;
                    db[(size_t)(idx>>2)*dcs + (idx&3)] = f2bu(d);
                }
            }
        }
    }
    Sp[((size_t)(chunk*nbat + bi)*tR + lr)*256 + xx] = ssum * (1.f/9.f);
}

// ---------------- K2: sum chunks + 3x3 box with edge clamp -> padded Lm ----------------
__global__ __launch_bounds__(256) void k_box(const float* __restrict__ Sp, float* __restrict__ Lm,
        int lr0, int lrows, int tr0, int tR, int a, int lRp, int nbat){
    int bi = blockIdx.x / lrows;
    int lr = blockIdx.x - bi*lrows;
    int grow = lr0 + lr;
    int xx = threadIdx.x;
    int g0 = (grow-1 > 0 ? grow-1 : 0) - tr0, g1 = grow - tr0, g2 = (grow+1 < 255 ? grow+1 : 255) - tr0;
    int x0 = xx-1 > 0 ? xx-1 : 0, x2 = xx+1 < 255 ? xx+1 : 255;
    float s = 0.f;
    for (int ch = 0; ch < NCH; ++ch){
        const float* Sb = Sp + ((size_t)(ch*nbat + bi)*tR)*256;
        s += Sb[g0*256+x0]+Sb[g0*256+xx]+Sb[g0*256+x2]
           + Sb[g1*256+x0]+Sb[g1*256+xx]+Sb[g1*256+x2]
           + Sb[g2*256+x0]+Sb[g2*256+xx]+Sb[g2*256+x2];
    }
    Lm[(size_t)bi*lRp*258 + (size_t)(grow-a+1)*258 + xx + 1] = s;
}

// ---------------- K3: fused h-finish + grouped 3x3 -> v, per (plane, 16-row tile) ----------------
// phase 1: build h2 tile (18 rows x 258 cols, zero-padded) in LDS from d1s plane g
// phase 2: v[g] = relu(analytic(Lm 3x3) + conv3x3(h2 tile)), packed (vl,vh)
__global__ __launch_bounds__(256) void k_mov(const ushort4* __restrict__ d1s,
     const float* __restrict__ Lm, const float* __restrict__ whp2,
     const float* __restrict__ ahp1s,
     const unsigned int* __restrict__ WPNL, const unsigned int* __restrict__ WPNH,
     const unsigned int* __restrict__ WLDpk, const unsigned int* __restrict__ WHDpk,
     unsigned int* __restrict__ v,
     int a, int orows, int tr0, int tR, int lRp){
    __shared__ uint2 h2t[18][258];
    int g = blockIdx.x % 127;
    int rest = blockIdx.x / 127;
    int ntiles = orows >> 4;
    int ti = rest % ntiles;
    int bi = rest / ntiles;
    int px = threadIdx.x;
    int row0 = a + ti*16;
    // ---- phase 1 ----
    const ushort4* db = d1s + ((size_t)bi*127 + g)*tR*256;
    const float* Lb = Lm + (size_t)bi*lRp*258;
    float as0 = ahp1s[4*g], as1 = ahp1s[4*g+1], as2 = ahp1s[4*g+2], as3 = ahp1s[4*g+3];
    float w2r[16];
    #pragma unroll
    for (int i = 0; i < 16; ++i) w2r[i] = whp2[g*16 + i];
    for (int rr = 0; rr < 18; ++rr){
        int gr = row0 - 1 + rr;
        uint2 hv; hv.x = 0u; hv.y = 0u;
        if (gr >= 0 && gr < 256){
            ushort4 dq = db[(size_t)(gr - tr0)*256 + px];
            float Lv = Lb[(size_t)(gr - a + 1)*258 + px + 1];
            float h0 = fmaxf(fmaf(-Lv, as0, bfu(dq.x)), 0.f);
            float h1 = fmaxf(fmaf(-Lv, as1, bfu(dq.y)), 0.f);
            float hm2 = fmaxf(fmaf(-Lv, as2, bfu(dq.z)), 0.f);
            float h3 = fmaxf(fmaf(-Lv, as3, bfu(dq.w)), 0.f);
            float a0 = fmaf(w2r[0], h0, fmaf(w2r[1], h1, fmaf(w2r[2], hm2, w2r[3]*h3)));
            float a1 = fmaf(w2r[4], h0, fmaf(w2r[5], h1, fmaf(w2r[6], hm2, w2r[7]*h3)));
            float a2 = fmaf(w2r[8], h0, fmaf(w2r[9], h1, fmaf(w2r[10], hm2, w2r[11]*h3)));
            float a3 = fmaf(w2r[12], h0, fmaf(w2r[13], h1, fmaf(w2r[14], hm2, w2r[15]*h3)));
            hv.x = pk2(a0, a1);
            hv.y = pk2(a2, a3);
        }
        h2t[rr][px+1] = hv;
    }
    if (px < 18){ uint2 z; z.x = 0u; z.y = 0u; h2t[px][0] = z; h2t[px][257] = z; }
    __syncthreads();
    // ---- block-uniform tables ----
    float WLp[9], WLn[9], WHp[9], WHn[9];
    #pragma unroll
    for (int q = 0; q < 9; ++q){
        unsigned int wl = WPNL[g*9+q], wh = WPNH[g*9+q];
        WLp[q] = bflo(wl); WLn[q] = bfhi(wl);
        WHp[q] = bflo(wh); WHn[q] = bfhi(wh);
    }
    bool lbr = (g >= 63), hbr = (g <= 63);
    s16x2 WDl[18], WDh[18];
    #pragma unroll
    for (int i = 0; i < 18; ++i){
        WDl[i] = __builtin_bit_cast(s16x2, WLDpk[g*18+i]);
        WDh[i] = __builtin_bit_cast(s16x2, WHDpk[g*18+i]);
    }
    // ---- phase 2 ----
    size_t ps = (size_t)orows*256;
    unsigned int* vb = v + ((size_t)bi*128 + g)*ps + (size_t)(ti*16)*256 + px;
    for (int r = 0; r < 16; ++r){
        float sl = 0.f, sh = 0.f;
        #pragma unroll
        for (int q = 0; q < 9; ++q){
            float lv = Lb[(size_t)(ti*16 + r + q/3)*258 + px + (q%3)];
            float lqp = fmaxf(lv, 0.f), lqn = fminf(lv, 0.f);
            sl = fmaf(WLp[q], lqp, fmaf(WLn[q], lqn, sl));
            sh = fmaf(WHp[q], lqp, fmaf(WHn[q], lqn, sh));
        }
        if (lbr){
            float s0 = 0.f, s1 = 0.f;
            #pragma unroll
            for (int q = 0; q < 9; ++q){
                uint2 tv = h2t[r + q/3][px + (q%3)];
                s0 = DOT2B(__builtin_bit_cast(s16x2, tv.x), WDl[2*q],   s0);
                s1 = DOT2B(__builtin_bit_cast(s16x2, tv.y), WDl[2*q+1], s1);
            }
            sl += s0 + s1;
        }
        if (hbr){
            float s0 = 0.f, s1 = 0.f;
            #pragma unroll
            for (int q = 0; q < 9; ++q){
                uint2 tv = h2t[r + q/3][px + (q%3)];
                s0 = DOT2B(__builtin_bit_cast(s16x2, tv.x), WDh[2*q],   s0);
                s1 = DOT2B(__builtin_bit_cast(s16x2, tv.y), WDh[2*q+1], s1);
            }
            sh += s0 + s1;
        }
        unsigned int lo = f2bu(fmaxf(sl, 0.f));
        unsigned int hi = f2bu(fmaxf(sh, 0.f));
        vb[(size_t)r*256] = lo | (hi << 16);
        if (g == 126) vb[(size_t)r*256 + ps] = 0u;   // zero pad plane 127
    }
}

// ---------------- K4: out = v @ BtP^T + x via MFMA, fused residual ----------------
__global__ __launch_bounds__(256) void k_proj(const unsigned int* __restrict__ v,
        const unsigned short* __restrict__ BtP, const float* __restrict__ x,
        float* __restrict__ out, int b0, int a, int orows){
    __shared__ float EoS[256*49];            // 50176 B; Bt overlays first 26112 B
    unsigned short* Bt = (unsigned short*)EoS;   // [48 n][136 u16]
    int t = threadIdx.x;
    for (int i = t; i < 48*256; i += 256){
        int n = i >> 8, k = i & 255;
        Bt[n*136 + k] = BtP[i];
    }
    int bi = blockIdx.x / orows;
    int lr = blockIdx.x - bi*orows;
    int b = b0 + bi;
    size_t ps = (size_t)orows*256;
    const unsigned int* vb = v + (size_t)bi*128*ps + (size_t)lr*256;
    int lane = t & 63, w = t >> 6;
    int pxl = w*64;
    __syncthreads();
    f32x4 acc[4][3];
    #pragma unroll
    for (int m = 0; m < 4; ++m)
        #pragma unroll
        for (int nt = 0; nt < 3; ++nt) acc[m][nt] = (f32x4){0.f,0.f,0.f,0.f};
    #pragma unroll
    for (int ch = 0; ch < 4; ++ch){
        bf16x8 bfr[3][2];
        #pragma unroll
        for (int nt = 0; nt < 3; ++nt)
            #pragma unroll
            for (int kk = 0; kk < 2; ++kk)
                bfr[nt][kk] = *reinterpret_cast<const bf16x8*>(
                    &Bt[(nt*16 + (lane&15))*136 + ch*64 + kk*32 + (lane>>4)*8]);
        #pragma unroll
        for (int m = 0; m < 4; ++m){
            int px = pxl + m*16 + (lane & 15);
            #pragma unroll
            for (int kk = 0; kk < 2; ++kk){
                int pl0 = ch*32 + kk*16 + (lane>>4)*4;
                unsigned int p0 = vb[(size_t)(pl0+0)*ps + px];
                unsigned int p1 = vb[(size_t)(pl0+1)*ps + px];
                unsigned int p2 = vb[(size_t)(pl0+2)*ps + px];
                unsigned int p3 = vb[(size_t)(pl0+3)*ps + px];
                bf16x8 af;
                af[0]=(short)(p0&0xffff); af[1]=(short)(p0>>16);
                af[2]=(short)(p1&0xffff); af[3]=(short)(p1>>16);
                af[4]=(short)(p2&0xffff); af[5]=(short)(p2>>16);
                af[6]=(short)(p3&0xffff); af[7]=(short)(p3>>16);
                #pragma unroll
                for (int nt = 0; nt < 3; ++nt)
                    acc[m][nt] = __builtin_amdgcn_mfma_f32_16x16x32_bf16(af, bfr[nt][kk], acc[m][nt], 0, 0, 0);
            }
        }
    }
    __syncthreads();   // Bt dead -> epilogue buffer
    #pragma unroll
    for (int m = 0; m < 4; ++m){
        #pragma unroll
        for (int nt = 0; nt < 3; ++nt){
            #pragma unroll
            for (int rg = 0; rg < 4; ++rg){
                int epx = pxl + m*16 + (lane>>4)*4 + rg;
                int eo  = nt*16 + (lane&15);
                EoS[epx*49 + eo] = acc[m][nt][rg];
            }
        }
    }
    __syncthreads();
    int grow = a + lr;
    const float* xb = x + (size_t)b*48*HW + (size_t)grow*256 + t;
    float* ob = out + (size_t)b*48*HW + (size_t)grow*256 + t;
    #pragma unroll
    for (int o = 0; o < 48; ++o)
        ob[(size_t)o*HW] = EoS[t*49 + o] + xb[(size_t)o*HW];
}

extern "C" void kernel_launch(void* const* d_in, const int* in_sizes, int n_in,
                              void* d_out, int out_size, void* d_ws, size_t ws_size,
                              hipStream_t stream){
    const float* x    = (const float*)d_in[0];
    const float* winP = (const float*)d_in[1];
    const float* winD = (const float*)d_in[2];
    const float* wlp1 = (const float*)d_in[3];
    const float* whp1 = (const float*)d_in[4];
    const float* wlp2 = (const float*)d_in[5];
    const float* whp2 = (const float*)d_in[6];
    const float* wld  = (const float*)d_in[7];
    const float* whd  = (const float*)d_in[8];
    const float* wout = (const float*)d_in[9];
    float* out = (float*)d_out;

    char* ws = (char*)d_ws;
    size_t off = 0;
    auto alloc = [&](size_t bytes)->char*{
        char* pp = ws + off; off += (bytes + 255) & ~(size_t)255; return pp;
    };
    auto A = [](size_t bytes)->size_t{ return (bytes + 255) & ~(size_t)255; };

    float* ahp1s = (float*)alloc(508*4);
    float* cpG = (float*)alloc(508*4);
    float* cnG = (float*)alloc(508*4);
    unsigned int* WPNL  = (unsigned int*)alloc(127*9*4);
    unsigned int* WPNH  = (unsigned int*)alloc(127*9*4);
    unsigned int* WLDpk = (unsigned int*)alloc(127*18*4);
    unsigned int* WHDpk = (unsigned int*)alloc(127*18*4);
    float* wDp  = (float*)alloc(512*9*4);
    unsigned short* WPb = (unsigned short*)alloc(256*64*2);
    unsigned short* BtP = (unsigned short*)alloc(48*256*2);

    // ladder: Hb must be a multiple of 16 (k_mov tiles)
    const int cfgs[6][2] = {{256,2},{128,2},{64,2},{64,1},{32,1},{16,1}};
    int Hb = 16, nbat = 1;
    for (int ci = 0; ci < 6; ++ci){
        int hb = cfgs[ci][0], nb = cfgs[ci][1];
        int uRr = hb+6 < 256 ? hb+6 : 256;
        int tRr = hb+4 < 256 ? hb+4 : 256;
        size_t need = off;
        need += A((size_t)nb*32*(uRr+2)*258*16);   // u (padded oct layout; v aliases it)
        need += A((size_t)nb*127*tRr*256*8);       // d1s
        need += A((size_t)nb*NCH*tRr*256*4);       // Sp
        need += A((size_t)nb*(hb+2)*258*4);        // Lm (padded)
        if (need <= ws_size){ Hb = hb; nbat = nb; break; }
    }
    int uR = Hb+6 < 256 ? Hb+6 : 256;
    int tR = Hb+4 < 256 ? Hb+4 : 256;
    int uRp = uR + 2;
    int lRp = Hb + 2;
    uint4* u   = (uint4*)alloc((size_t)nbat*32*uRp*258*16);
    unsigned short* d1s = (unsigned short*)alloc((size_t)nbat*127*tR*256*8);
    float* Sp = (float*)alloc((size_t)nbat*NCH*tR*256*4);
    float* Lm = (float*)alloc((size_t)nbat*lRp*258*4);
    // v aliases u: u is dead after k_dw; per-band order pconv->dw->mov->proj keeps it safe.
    // v = nbat*128*orows*256*4 <= u size for all cfgs (checked: 67.1<=68.2 MB at Hb=256, etc.)
    unsigned int* v = (unsigned int*)u;

    k_coef1<<<1, 512, 0, stream>>>(wlp1, whp1, wlp2, ahp1s, cpG, cnG);
    k_coef2<<<64, 256, 0, stream>>>(wld, whd, winP, winD, wout, cpG, cnG,
                                    WPNL, WPNH, WLDpk, WHDpk, wDp, WPb, BtP);

    for (int b0 = 0; b0 < 2; b0 += nbat){
        for (int a = 0; a < 256; a += Hb){
            int ur0 = a-3 > 0 ? a-3 : 0;  int ur1 = a+Hb+3 < 256 ? a+Hb+3 : 256;
            int tr0 = a-2 > 0 ? a-2 : 0;  int tr1 = a+Hb+2 < 256 ? a+Hb+2 : 256;
            int lr0 = a-1 > 0 ? a-1 : 0;  int lr1 = a+Hb+1 < 256 ? a+Hb+1 : 256;
            int urows = ur1-ur0, trows = tr1-tr0, lrows = lr1-lr0;
            int orows = (a+Hb < 256 ? a+Hb : 256) - a;
            k_padU<<<nbat*32 + nbat, 256, 0, stream>>>(u, Lm, uRp, lRp, nbat,
                                                       a == 0, a + Hb >= 256);
            k_pconv<<<nbat*urows*4, 256, 0, stream>>>(x, WPb, u, b0, ur0, urows, uRp);
            k_dw  <<<nbat*trows*NCH, 256, 0, stream>>>(u, wDp, whp1, d1s, Sp, tr0, trows, ur0, uRp, tR, nbat);
            k_box <<<nbat*lrows, 256, 0, stream>>>(Sp, Lm, lr0, lrows, tr0, tR, a, lRp, nbat);
            k_mov <<<nbat*(orows>>4)*127, 256, 0, stream>>>((const ushort4*)d1s, Lm, whp2, ahp1s,
                                                            WPNL, WPNH, WLDpk, WHDpk, v,
                                                            a, orows, tr0, tR, lRp);
            k_proj<<<nbat*orows, 256, 0, stream>>>(v, BtP, x, out, b0, a, orows);
        }
    }
}

// Round 12
// 196.680 us; speedup vs baseline: 10.0807x; 1.0426x over previous
//
#include <hip/hip_runtime.h>
#include <hip/hip_bf16.h>

#define HW 65536
#define NCH 16   // channel chunks in k_dw (2 octs each)

typedef __attribute__((ext_vector_type(8))) short bf16x8;
typedef __attribute__((ext_vector_type(4))) float f32x4;
typedef __attribute__((ext_vector_type(2))) float f32x2;
typedef __attribute__((ext_vector_type(2))) short s16x2;

__device__ __forceinline__ float bfu(unsigned short u){
    return __uint_as_float(((unsigned int)u) << 16);
}
__device__ __forceinline__ float bflo(unsigned int u){
    return __uint_as_float(u << 16);
}
__device__ __forceinline__ float bfhi(unsigned int u){
    return __uint_as_float(u & 0xffff0000u);
}
__device__ __forceinline__ unsigned short f2bu(float f){
    return __builtin_bit_cast(unsigned short, __float2bfloat16(f));
}
__device__ __forceinline__ unsigned int pk2(float a, float b){
    return (unsigned int)f2bu(a) | ((unsigned int)f2bu(b) << 16);
}
// v_cvt_pk_bf16_f32: packs (a,b) -> (lo=bf16(a), hi=bf16(b)), RTNE. No builtin on gfx950.
__device__ __forceinline__ unsigned int pk2c(float a, float b){
    unsigned int r;
    asm("v_cvt_pk_bf16_f32 %0, %1, %2" : "=v"(r) : "v"(a), "v"(b));
    return r;
}

#if __has_builtin(__builtin_amdgcn_fdot2_f32_bf16)
__device__ __forceinline__ float DOT2B(s16x2 a, s16x2 b, float c){
    return __builtin_amdgcn_fdot2_f32_bf16(a, b, c, false);
}
#else
__device__ __forceinline__ float DOT2B(s16x2 a, s16x2 b, float c){
    return fmaf(bfu((unsigned short)a.x), bfu((unsigned short)b.x),
           fmaf(bfu((unsigned short)a.y), bfu((unsigned short)b.y), c));
}
#endif

// ---------------- K0a: sequential coefficient core (1 block) ----------------
__global__ void k_coef1(const float* __restrict__ wlp1, const float* __restrict__ whp1,
                        const float* __restrict__ wlp2,
                        float* __restrict__ ahp1s,
                        float* __restrict__ cpG, float* __restrict__ cnG){
    __shared__ float aL[508], ah[508];
    int t = threadIdx.x;
    if (t < 508){
        int g = t >> 2, o = t & 3;
        float s = 0.f, s2 = 0.f;
        for (int i = 0; i < 4; ++i){ s += wlp1[g*16 + o*4 + i]; s2 += whp1[g*16 + o*4 + i]; }
        aL[t] = s; ah[t] = s2;
    }
    __syncthreads();
    if (t < 508){
        int g = t >> 2, o = t & 3;
        float p = 0.f, n = 0.f;
        for (int k = 0; k < 4; ++k){
            int idx = 4*g + k;                    // shuffled position
            int inv = (idx % 127)*4 + idx/127;    // original channel
            float av = aL[inv];
            float w2 = wlp2[g*16 + o*4 + k];
            p += w2 * fmaxf(av, 0.f);
            n += w2 * fminf(av, 0.f);
        }
        cpG[t] = p; cnG[t] = n;
        int inv = (t % 127)*4 + t/127;
        ahp1s[t] = ah[inv];
    }
}

// ---------------- K0b: parallel table fills (64 blocks, grid-strided) ----------------
__global__ void k_coef2(const float* __restrict__ wld, const float* __restrict__ whd,
                        const float* __restrict__ winP, const float* __restrict__ winD,
                        const float* __restrict__ wout,
                        const float* __restrict__ cp, const float* __restrict__ cn,
                        unsigned int* __restrict__ WPNL, unsigned int* __restrict__ WPNH,
                        unsigned int* __restrict__ WLDpk, unsigned int* __restrict__ WHDpk,
                        float* __restrict__ wDp,
                        unsigned short* __restrict__ WPb, unsigned short* __restrict__ BtP){
    int t0 = blockIdx.x*256 + threadIdx.x;
    int str = gridDim.x*256;
    // analytic tables, packed (pos,neg) bf16 pairs
    for (int idx = t0; idx < 127*9; idx += str){
        int g = idx/9, q = idx%9;
        float lp=0.f, ln=0.f, hp=0.f, hn=0.f;
        for (int i = 0; i < 4; ++i){
            int ch = 4*g + i;
            if (ch < 254){ float w = wld[g*36 + i*9 + q]; lp += w*cp[ch]; ln += w*cn[ch]; }
            else         { float w = whd[g*36 + i*9 + q]; hp += w*cp[ch]; hn += w*cn[ch]; }
        }
        WPNL[idx] = pk2(lp, ln);
        WPNH[idx] = pk2(hp, hn);
    }
    // conv tables, packed channel-pair bf16 weights (masked to h2-sourced channels)
    for (int idx = t0; idx < 127*18; idx += str){
        int g = idx/18, r = idx%18; int q = r >> 1, hp_ = r & 1;
        int c0 = 4*g + 2*hp_, c1 = c0 + 1;
        float wl0 = (c0 >= 254) ? wld[g*36 + (2*hp_)*9 + q]   : 0.f;
        float wl1 = (c1 >= 254) ? wld[g*36 + (2*hp_+1)*9 + q] : 0.f;
        float wh0 = (c0 <  254) ? whd[g*36 + (2*hp_)*9 + q]   : 0.f;
        float wh1 = (c1 <  254) ? whd[g*36 + (2*hp_+1)*9 + q] : 0.f;
        WLDpk[idx] = pk2(wl0, wl1);
        WHDpk[idx] = pk2(wh0, wh1);
    }
    // wDp: [512 tch][9], zero-padded winD (508x9)
    for (int idx = t0; idx < 512*9; idx += str){
        int ch = idx/9, q = idx - ch*9;
        wDp[idx] = (ch < 508) ? winD[ch*9 + q] : 0.f;
    }
    // WPb: [256 o][64 k] bf16, zero-padded winP
    for (int idx = t0; idx < 256*64; idx += str){
        int o = idx >> 6, k = idx & 63;
        float vv = (o < 254 && k < 48) ? winP[o*48 + k] : 0.f;
        WPb[idx] = f2bu(vv);
    }
    // BtP: [48 n][256 k] bf16; k=2g -> wout[n][g] (l), k=2g+1 -> wout[n][127+g] (h)
    for (int idx = t0; idx < 48*256; idx += str){
        int n = idx >> 8, k = idx & 255;
        int g = k >> 1;
        float vv = (g < 127) ? ((k & 1) ? wout[n*254 + 127 + g] : wout[n*254 + g]) : 0.f;
        BtP[idx] = f2bu(vv);
    }
}

// ---------------- per-band border zeroing ----------------
__global__ void k_padU(uint4* __restrict__ u, float* __restrict__ Lm,
                       int uRp, int lRp, int nbat, int zeroTop, int zeroBot){
    int p = blockIdx.x, t = threadIdx.x;
    int nu = nbat*32;
    if (p < nu){
        uint4* pl = u + (size_t)p*uRp*258;
        uint4 z = make_uint4(0,0,0,0);
        for (int i = t; i < 258; i += 256){ pl[i] = z; pl[(size_t)(uRp-1)*258 + i] = z; }
        for (int r = t; r < uRp; r += 256){ pl[(size_t)r*258] = z; pl[(size_t)r*258 + 257] = z; }
    } else {
        float* pl = Lm + (size_t)(p-nu)*lRp*258;
        if (zeroTop) for (int i = t; i < 258; i += 256) pl[i] = 0.f;
        if (zeroBot) for (int i = t; i < 258; i += 256) pl[(size_t)(lRp-1)*258 + i] = 0.f;
        for (int r = t; r < lRp; r += 256){ pl[(size_t)r*258] = 0.f; pl[(size_t)r*258 + 257] = 0.f; }
    }
}

// ---------------- K1a: u = w_inP @ x (1x1 48->254) via MFMA, padded oct layout ----------------
__global__ __launch_bounds__(256) void k_pconv(const float* __restrict__ x,
        const unsigned short* __restrict__ WPb, uint4* __restrict__ u,
        int b0, int ur0, int urows, int uRp){
    __shared__ unsigned short BtS[256*72];   // 36864 B; epilogue overlays [64px][264 u16]=33792 B
    int t = threadIdx.x;
    for (int i = t; i < 256*64; i += 256){
        int o = i >> 6, k = i & 63;
        BtS[o*72 + k] = WPb[i];
    }
    int bpb = urows*4;
    int bi = blockIdx.x / bpb;
    int r  = blockIdx.x - bi*bpb;
    int lr = r >> 2, quarter = r & 3;
    int b = b0 + bi;
    int grow = ur0 + lr;
    const float* xb = x + (size_t)b*48*HW + (size_t)grow*256 + quarter*64;
    int w = t >> 6, lane = t & 63;
    int px = w*16 + (lane & 15);
    int k0 = (lane >> 4)*8;
    bf16x8 afr[2];
    #pragma unroll
    for (int kk = 0; kk < 2; ++kk){
        #pragma unroll
        for (int j = 0; j < 8; ++j){
            int k = kk*32 + k0 + j;
            float vv = (k < 48) ? xb[(size_t)k*HW + px] : 0.f;
            afr[kk][j] = (short)f2bu(vv);
        }
    }
    __syncthreads();
    f32x4 acc[16];
    #pragma unroll
    for (int nt = 0; nt < 16; ++nt) acc[nt] = (f32x4){0.f,0.f,0.f,0.f};
    #pragma unroll
    for (int kk = 0; kk < 2; ++kk){
        #pragma unroll
        for (int nt = 0; nt < 16; ++nt){
            bf16x8 bfr = *reinterpret_cast<const bf16x8*>(&BtS[(nt*16 + (lane&15))*72 + kk*32 + k0]);
            acc[nt] = __builtin_amdgcn_mfma_f32_16x16x32_bf16(afr[kk], bfr, acc[nt], 0, 0, 0);
        }
    }
    __syncthreads();   // BtS dead -> epilogue buffer, stride 264 (16B-aligned rows)
    unsigned short* E = BtS;
    #pragma unroll
    for (int nt = 0; nt < 16; ++nt){
        #pragma unroll
        for (int rg = 0; rg < 4; ++rg){
            int epx = w*16 + (lane>>4)*4 + rg;
            int eo  = nt*16 + (lane&15);
            E[epx*264 + eo] = f2bu(acc[nt][rg]);
        }
    }
    __syncthreads();
    int spx = t & 63;
    size_t su = (size_t)uRp*258;
    uint4* ub = u + (size_t)bi*32*su + (size_t)(lr+1)*258 + (quarter*64 + spx + 1);
    int og = t >> 6;
    #pragma unroll
    for (int j = 0; j < 8; ++j){
        int od = og*8 + j;
        uint4 q4 = *reinterpret_cast<const uint4*>(&E[spx*264 + od*8]);
        ub[(size_t)od*su] = q4;
    }
}

// ---------------- K1b: depthwise 3x3 x2 + relu + channel-sum + fused h-g1x1 -> shuffled d1s ----------------
__global__ __launch_bounds__(256) void k_dw(const uint4* __restrict__ u,
        const float* __restrict__ wDp, const float* __restrict__ whp1,
        unsigned short* __restrict__ d1s, float* __restrict__ Sp,
        int tr0, int trows, int ur0, int uRp, int tR, int nbat){
    int chunk = blockIdx.x & (NCH-1);
    int rb = blockIdx.x >> 4;
    int bi = rb / trows;
    int lr = rb - bi*trows;
    int grow = tr0 + lr;
    int xx = threadIdx.x;
    int lrow = grow - ur0;
    size_t su = (size_t)uRp*258;
    const uint4* ubase = u + (size_t)bi*32*su + (size_t)lrow*258 + xx;
    unsigned short* db = d1s + (size_t)bi*127*tR*256*4 + ((size_t)lr*256 + xx)*4;
    size_t dcs = (size_t)tR*256*4;
    float ssum = 0.f;
    int od0 = chunk*2;
    for (int od = od0; od < od0+2; ++od){
        const uint4* up = ubase + (size_t)od*su;
        float o[16];
        #pragma unroll
        for (int j = 0; j < 16; ++j) o[j] = 0.f;
        #pragma unroll
        for (int q = 0; q < 9; ++q){
            uint4 rv = up[(q/3)*258 + (q%3)];
            float c0 = bflo(rv.x), c1 = bfhi(rv.x), c2 = bflo(rv.y), c3 = bfhi(rv.y);
            float c4 = bflo(rv.z), c5 = bfhi(rv.z), c6 = bflo(rv.w), c7 = bfhi(rv.w);
            const float* wq = wDp + (size_t)(16*od)*9 + q;
            o[0]  = fmaf(wq[0],   c0, o[0]);
            o[1]  = fmaf(wq[9],   c0, o[1]);
            o[2]  = fmaf(wq[18],  c1, o[2]);
            o[3]  = fmaf(wq[27],  c1, o[3]);
            o[4]  = fmaf(wq[36],  c2, o[4]);
            o[5]  = fmaf(wq[45],  c2, o[5]);
            o[6]  = fmaf(wq[54],  c3, o[6]);
            o[7]  = fmaf(wq[63],  c3, o[7]);
            o[8]  = fmaf(wq[72],  c4, o[8]);
            o[9]  = fmaf(wq[81],  c4, o[9]);
            o[10] = fmaf(wq[90],  c5, o[10]);
            o[11] = fmaf(wq[99],  c5, o[11]);
            o[12] = fmaf(wq[108], c6, o[12]);
            o[13] = fmaf(wq[117], c6, o[13]);
            o[14] = fmaf(wq[126], c7, o[14]);
            o[15] = fmaf(wq[135], c7, o[15]);
        }
        #pragma unroll
        for (int j = 0; j < 16; ++j){ o[j] = fmaxf(o[j], 0.f); ssum += o[j]; }
        int tqb = 4*od;
        #pragma unroll
        for (int m = 0; m < 4; ++m){
            int tq = tqb + m;
            if (tq < 127){
                const float* w1 = whp1 + tq*16;
                #pragma unroll
                for (int oi = 0; oi < 4; ++oi){
                    float d = fmaf(w1[oi*4+0], o[4*m+0], fmaf(w1[oi*4+1], o[4*m+1],
                              fmaf(w1[oi*4+2], o[4*m+2], w1[oi*4+3]*o[4*m+3])));
                    int idx = 127*oi + tq;
                    db[(size_t)(idx>>2)*dcs + (idx&3)] = f2bu(d);
                }
            }
        }
    }
    Sp[((size_t)(chunk*nbat + bi)*tR + lr)*256 + xx] = ssum * (1.f/9.f);
}

// ---------------- K2: sum chunks + 3x3 box with edge clamp -> padded Lm ----------------
__global__ __launch_bounds__(256) void k_box(const float* __restrict__ Sp, float* __restrict__ Lm,
        int lr0, int lrows, int tr0, int tR, int a, int lRp, int nbat){
    int bi = blockIdx.x / lrows;
    int lr = blockIdx.x - bi*lrows;
    int grow = lr0 + lr;
    int xx = threadIdx.x;
    int g0 = (grow-1 > 0 ? grow-1 : 0) - tr0, g1 = grow - tr0, g2 = (grow+1 < 255 ? grow+1 : 255) - tr0;
    int x0 = xx-1 > 0 ? xx-1 : 0, x2 = xx+1 < 255 ? xx+1 : 255;
    float s = 0.f;
    for (int ch = 0; ch < NCH; ++ch){
        const float* Sb = Sp + ((size_t)(ch*nbat + bi)*tR)*256;
        s += Sb[g0*256+x0]+Sb[g0*256+xx]+Sb[g0*256+x2]
           + Sb[g1*256+x0]+Sb[g1*256+xx]+Sb[g1*256+x2]
           + Sb[g2*256+x0]+Sb[g2*256+xx]+Sb[g2*256+x2];
    }
    Lm[(size_t)bi*lRp*258 + (size_t)(grow-a+1)*258 + xx + 1] = s;
}

// ---------------- K3: fused h-finish + grouped 3x3 -> v, rolling registers ----------------
__global__ __launch_bounds__(256) void k_mov(const ushort4* __restrict__ d1s,
     const float* __restrict__ Lm, const float* __restrict__ whp2,
     const float* __restrict__ ahp1s,
     const unsigned int* __restrict__ WPNL, const unsigned int* __restrict__ WPNH,
     const unsigned int* __restrict__ WLDpk, const unsigned int* __restrict__ WHDpk,
     unsigned int* __restrict__ v,
     int a, int orows, int tr0, int tR, int lRp){
    __shared__ uint2 h2t[18][258];
    int g = blockIdx.x % 127;
    int rest = blockIdx.x / 127;
    int ntiles = orows >> 4;
    int ti = rest % ntiles;
    int bi = rest / ntiles;
    int px = threadIdx.x;
    int row0 = a + ti*16;
    // ---- phase 1: build h2 tile in LDS ----
    const ushort4* db = d1s + ((size_t)bi*127 + g)*tR*256;
    const float* Lb = Lm + (size_t)bi*lRp*258;
    float as0 = ahp1s[4*g], as1 = ahp1s[4*g+1], as2 = ahp1s[4*g+2], as3 = ahp1s[4*g+3];
    float w2r[16];
    #pragma unroll
    for (int i = 0; i < 16; ++i) w2r[i] = whp2[g*16 + i];
    for (int rr = 0; rr < 18; ++rr){
        int gr = row0 - 1 + rr;
        uint2 hv; hv.x = 0u; hv.y = 0u;
        if (gr >= 0 && gr < 256){
            ushort4 dq = db[(size_t)(gr - tr0)*256 + px];
            float Lv = Lb[(size_t)(gr - a + 1)*258 + px + 1];
            float h0 = fmaxf(fmaf(-Lv, as0, bfu(dq.x)), 0.f);
            float h1 = fmaxf(fmaf(-Lv, as1, bfu(dq.y)), 0.f);
            float hm2 = fmaxf(fmaf(-Lv, as2, bfu(dq.z)), 0.f);
            float h3 = fmaxf(fmaf(-Lv, as3, bfu(dq.w)), 0.f);
            float a0 = fmaf(w2r[0], h0, fmaf(w2r[1], h1, fmaf(w2r[2], hm2, w2r[3]*h3)));
            float a1 = fmaf(w2r[4], h0, fmaf(w2r[5], h1, fmaf(w2r[6], hm2, w2r[7]*h3)));
            float a2 = fmaf(w2r[8], h0, fmaf(w2r[9], h1, fmaf(w2r[10], hm2, w2r[11]*h3)));
            float a3 = fmaf(w2r[12], h0, fmaf(w2r[13], h1, fmaf(w2r[14], hm2, w2r[15]*h3)));
            hv.x = pk2c(a0, a1);
            hv.y = pk2c(a2, a3);
        }
        h2t[rr][px+1] = hv;
    }
    if (px < 18){ uint2 z; z.x = 0u; z.y = 0u; h2t[px][0] = z; h2t[px][257] = z; }
    __syncthreads();
    // ---- block-uniform tables ----
    f32x2 WL2[9], WH2[9];
    #pragma unroll
    for (int q = 0; q < 9; ++q){
        unsigned int wl = WPNL[g*9+q], wh = WPNH[g*9+q];
        WL2[q] = (f32x2){bflo(wl), bfhi(wl)};
        WH2[q] = (f32x2){bflo(wh), bfhi(wh)};
    }
    bool lbr = (g >= 63), hbr = (g <= 63);
    s16x2 WDl[18], WDh[18];
    #pragma unroll
    for (int i = 0; i < 18; ++i){
        WDl[i] = __builtin_bit_cast(s16x2, WLDpk[g*18+i]);
        WDh[i] = __builtin_bit_cast(s16x2, WHDpk[g*18+i]);
    }
    // ---- phase 2: rolling registers over 16 output rows ----
    size_t ps = (size_t)orows*256;
    unsigned int* vb = v + ((size_t)bi*128 + g)*ps + (size_t)(ti*16)*256 + px;
    const float* Lt = Lb + (size_t)(ti*16)*258 + px;   // tap row base
    f32x2 l2[3][3];
    uint2 ta[3][3];
    #pragma unroll
    for (int rr = 0; rr < 2; ++rr){
        #pragma unroll
        for (int c = 0; c < 3; ++c){
            float lv = Lt[(size_t)rr*258 + c];
            l2[rr][c] = (f32x2){fmaxf(lv, 0.f), fminf(lv, 0.f)};
            ta[rr][c] = h2t[rr][px + c];
        }
    }
    #pragma unroll
    for (int r = 0; r < 16; ++r){
        #pragma unroll
        for (int c = 0; c < 3; ++c){
            float lv = Lt[(size_t)(r+2)*258 + c];
            l2[2][c] = (f32x2){fmaxf(lv, 0.f), fminf(lv, 0.f)};
            ta[2][c] = h2t[r+2][px + c];
        }
        f32x2 aL = (f32x2){0.f, 0.f}, aH = (f32x2){0.f, 0.f};
        #pragma unroll
        for (int dy = 0; dy < 3; ++dy){
            #pragma unroll
            for (int dx = 0; dx < 3; ++dx){
                int q = dy*3 + dx;
                aL = aL + WL2[q]*l2[dy][dx];
                aH = aH + WH2[q]*l2[dy][dx];
            }
        }
        float sl = aL.x + aL.y, sh = aH.x + aH.y;
        if (lbr){
            float s0 = 0.f, s1 = 0.f;
            #pragma unroll
            for (int dy = 0; dy < 3; ++dy){
                #pragma unroll
                for (int dx = 0; dx < 3; ++dx){
                    int q = dy*3 + dx;
                    uint2 tv = ta[dy][dx];
                    s0 = DOT2B(__builtin_bit_cast(s16x2, tv.x), WDl[2*q],   s0);
                    s1 = DOT2B(__builtin_bit_cast(s16x2, tv.y), WDl[2*q+1], s1);
                }
            }
            sl += s0 + s1;
        }
        if (hbr){
            float s0 = 0.f, s1 = 0.f;
            #pragma unroll
            for (int dy = 0; dy < 3; ++dy){
                #pragma unroll
                for (int dx = 0; dx < 3; ++dx){
                    int q = dy*3 + dx;
                    uint2 tv = ta[dy][dx];
                    s0 = DOT2B(__builtin_bit_cast(s16x2, tv.x), WDh[2*q],   s0);
                    s1 = DOT2B(__builtin_bit_cast(s16x2, tv.y), WDh[2*q+1], s1);
                }
            }
            sh += s0 + s1;
        }
        vb[(size_t)r*256] = pk2c(fmaxf(sl, 0.f), fmaxf(sh, 0.f));
        if (g == 126) vb[(size_t)r*256 + ps] = 0u;   // zero pad plane 127
        #pragma unroll
        for (int c = 0; c < 3; ++c){
            ta[0][c] = ta[1][c]; ta[1][c] = ta[2][c];
            l2[0][c] = l2[1][c]; l2[1][c] = l2[2][c];
        }
    }
}

// ---------------- K4: out = v @ BtP^T + x via MFMA, fused residual ----------------
__global__ __launch_bounds__(256) void k_proj(const unsigned int* __restrict__ v,
        const unsigned short* __restrict__ BtP, const float* __restrict__ x,
        float* __restrict__ out, int b0, int a, int orows){
    __shared__ float EoS[256*49];            // 50176 B; Bt overlays first 26112 B
    unsigned short* Bt = (unsigned short*)EoS;   // [48 n][136 u16]
    int t = threadIdx.x;
    for (int i = t; i < 48*256; i += 256){
        int n = i >> 8, k = i & 255;
        Bt[n*136 + k] = BtP[i];
    }
    int bi = blockIdx.x / orows;
    int lr = blockIdx.x - bi*orows;
    int b = b0 + bi;
    size_t ps = (size_t)orows*256;
    const unsigned int* vb = v + (size_t)bi*128*ps + (size_t)lr*256;
    int lane = t & 63, w = t >> 6;
    int pxl = w*64;
    __syncthreads();
    f32x4 acc[4][3];
    #pragma unroll
    for (int m = 0; m < 4; ++m)
        #pragma unroll
        for (int nt = 0; nt < 3; ++nt) acc[m][nt] = (f32x4){0.f,0.f,0.f,0.f};
    #pragma unroll
    for (int ch = 0; ch < 4; ++ch){
        bf16x8 bfr[3][2];
        #pragma unroll
        for (int nt = 0; nt < 3; ++nt)
            #pragma unroll
            for (int kk = 0; kk < 2; ++kk)
                bfr[nt][kk] = *reinterpret_cast<const bf16x8*>(
                    &Bt[(nt*16 + (lane&15))*136 + ch*64 + kk*32 + (lane>>4)*8]);
        #pragma unroll
        for (int m = 0; m < 4; ++m){
            int px = pxl + m*16 + (lane & 15);
            #pragma unroll
            for (int kk = 0; kk < 2; ++kk){
                int pl0 = ch*32 + kk*16 + (lane>>4)*4;
                unsigned int p0 = vb[(size_t)(pl0+0)*ps + px];
                unsigned int p1 = vb[(size_t)(pl0+1)*ps + px];
                unsigned int p2 = vb[(size_t)(pl0+2)*ps + px];
                unsigned int p3 = vb[(size_t)(pl0+3)*ps + px];
                bf16x8 af;
                af[0]=(short)(p0&0xffff); af[1]=(short)(p0>>16);
                af[2]=(short)(p1&0xffff); af[3]=(short)(p1>>16);
                af[4]=(short)(p2&0xffff); af[5]=(short)(p2>>16);
                af[6]=(short)(p3&0xffff); af[7]=(short)(p3>>16);
                #pragma unroll
                for (int nt = 0; nt < 3; ++nt)
                    acc[m][nt] = __builtin_amdgcn_mfma_f32_16x16x32_bf16(af, bfr[nt][kk], acc[m][nt], 0, 0, 0);
            }
        }
    }
    __syncthreads();   // Bt dead -> epilogue buffer
    #pragma unroll
    for (int m = 0; m < 4; ++m){
        #pragma unroll
        for (int nt = 0; nt < 3; ++nt){
            #pragma unroll
            for (int rg = 0; rg < 4; ++rg){
                int epx = pxl + m*16 + (lane>>4)*4 + rg;
                int eo  = nt*16 + (lane&15);
                EoS[epx*49 + eo] = acc[m][nt][rg];
            }
        }
    }
    __syncthreads();
    int grow = a + lr;
    const float* xb = x + (size_t)b*48*HW + (size_t)grow*256 + t;
    float* ob = out + (size_t)b*48*HW + (size_t)grow*256 + t;
    #pragma unroll
    for (int o = 0; o < 48; ++o)
        ob[(size_t)o*HW] = EoS[t*49 + o] + xb[(size_t)o*HW];
}

extern "C" void kernel_launch(void* const* d_in, const int* in_sizes, int n_in,
                              void* d_out, int out_size, void* d_ws, size_t ws_size,
                              hipStream_t stream){
    const float* x    = (const float*)d_in[0];
    const float* winP = (const float*)d_in[1];
    const float* winD = (const float*)d_in[2];
    const float* wlp1 = (const float*)d_in[3];
    const float* whp1 = (const float*)d_in[4];
    const float* wlp2 = (const float*)d_in[5];
    const float* whp2 = (const float*)d_in[6];
    const float* wld  = (const float*)d_in[7];
    const float* whd  = (const float*)d_in[8];
    const float* wout = (const float*)d_in[9];
    float* out = (float*)d_out;

    char* ws = (char*)d_ws;
    size_t off = 0;
    auto alloc = [&](size_t bytes)->char*{
        char* pp = ws + off; off += (bytes + 255) & ~(size_t)255; return pp;
    };
    auto A = [](size_t bytes)->size_t{ return (bytes + 255) & ~(size_t)255; };

    float* ahp1s = (float*)alloc(508*4);
    float* cpG = (float*)alloc(508*4);
    float* cnG = (float*)alloc(508*4);
    unsigned int* WPNL  = (unsigned int*)alloc(127*9*4);
    unsigned int* WPNH  = (unsigned int*)alloc(127*9*4);
    unsigned int* WLDpk = (unsigned int*)alloc(127*18*4);
    unsigned int* WHDpk = (unsigned int*)alloc(127*18*4);
    float* wDp  = (float*)alloc(512*9*4);
    unsigned short* WPb = (unsigned short*)alloc(256*64*2);
    unsigned short* BtP = (unsigned short*)alloc(48*256*2);

    // ladder: Hb must be a multiple of 16 (k_mov tiles)
    const int cfgs[6][2] = {{256,2},{128,2},{64,2},{64,1},{32,1},{16,1}};
    int Hb = 16, nbat = 1;
    for (int ci = 0; ci < 6; ++ci){
        int hb = cfgs[ci][0], nb = cfgs[ci][1];
        int uRr = hb+6 < 256 ? hb+6 : 256;
        int tRr = hb+4 < 256 ? hb+4 : 256;
        size_t need = off;
        need += A((size_t)nb*32*(uRr+2)*258*16);   // u (padded oct layout; v aliases it)
        need += A((size_t)nb*127*tRr*256*8);       // d1s
        need += A((size_t)nb*NCH*tRr*256*4);       // Sp
        need += A((size_t)nb*(hb+2)*258*4);        // Lm (padded)
        if (need <= ws_size){ Hb = hb; nbat = nb; break; }
    }
    int uR = Hb+6 < 256 ? Hb+6 : 256;
    int tR = Hb+4 < 256 ? Hb+4 : 256;
    int uRp = uR + 2;
    int lRp = Hb + 2;
    uint4* u   = (uint4*)alloc((size_t)nbat*32*uRp*258*16);
    unsigned short* d1s = (unsigned short*)alloc((size_t)nbat*127*tR*256*8);
    float* Sp = (float*)alloc((size_t)nbat*NCH*tR*256*4);
    float* Lm = (float*)alloc((size_t)nbat*lRp*258*4);
    // v aliases u: u is dead after k_dw; per-band order pconv->dw->mov->proj keeps it safe.
    unsigned int* v = (unsigned int*)u;

    k_coef1<<<1, 512, 0, stream>>>(wlp1, whp1, wlp2, ahp1s, cpG, cnG);
    k_coef2<<<64, 256, 0, stream>>>(wld, whd, winP, winD, wout, cpG, cnG,
                                    WPNL, WPNH, WLDpk, WHDpk, wDp, WPb, BtP);

    for (int b0 = 0; b0 < 2; b0 += nbat){
        for (int a = 0; a < 256; a += Hb){
            int ur0 = a-3 > 0 ? a-3 : 0;  int ur1 = a+Hb+3 < 256 ? a+Hb+3 : 256;
            int tr0 = a-2 > 0 ? a-2 : 0;  int tr1 = a+Hb+2 < 256 ? a+Hb+2 : 256;
            int lr0 = a-1 > 0 ? a-1 : 0;  int lr1 = a+Hb+1 < 256 ? a+Hb+1 : 256;
            int urows = ur1-ur0, trows = tr1-tr0, lrows = lr1-lr0;
            int orows = (a+Hb < 256 ? a+Hb : 256) - a;
            k_padU<<<nbat*32 + nbat, 256, 0, stream>>>(u, Lm, uRp, lRp, nbat,
                                                       a == 0, a + Hb >= 256);
            k_pconv<<<nbat*urows*4, 256, 0, stream>>>(x, WPb, u, b0, ur0, urows, uRp);
            k_dw  <<<nbat*trows*NCH, 256, 0, stream>>>(u, wDp, whp1, d1s, Sp, tr0, trows, ur0, uRp, tR, nbat);
            k_box <<<nbat*lrows, 256, 0, stream>>>(Sp, Lm, lr0, lrows, tr0, tR, a, lRp, nbat);
            k_mov <<<nbat*(orows>>4)*127, 256, 0, stream>>>((const ushort4*)d1s, Lm, whp2, ahp1s,
                                                            WPNL, WPNH, WLDpk, WHDpk, v,
                                                            a, orows, tr0, tR, lRp);
            k_proj<<<nbat*orows, 256, 0, stream>>>(v, BtP, x, out, b0, a, orows);
        }
    }
}

// Round 13
// 175.282 us; speedup vs baseline: 11.3113x; 1.1221x over previous
//
#include <hip/hip_runtime.h>
#include <hip/hip_bf16.h>

#define HW 65536
#define NCH 16   // channel chunks in k_dw (2 octs each)

typedef __attribute__((ext_vector_type(8))) short bf16x8;
typedef __attribute__((ext_vector_type(4))) float f32x4;
typedef __attribute__((ext_vector_type(2))) float f32x2;
typedef __attribute__((ext_vector_type(2))) short s16x2;

__device__ __forceinline__ float bfu(unsigned short u){
    return __uint_as_float(((unsigned int)u) << 16);
}
__device__ __forceinline__ float bflo(unsigned int u){
    return __uint_as_float(u << 16);
}
__device__ __forceinline__ float bfhi(unsigned int u){
    return __uint_as_float(u & 0xffff0000u);
}
__device__ __forceinline__ unsigned short f2bu(float f){
    return __builtin_bit_cast(unsigned short, __float2bfloat16(f));
}
__device__ __forceinline__ unsigned int pk2(float a, float b){
    return (unsigned int)f2bu(a) | ((unsigned int)f2bu(b) << 16);
}
// v_cvt_pk_bf16_f32: packs (a,b) -> (lo=bf16(a), hi=bf16(b)), RTNE. No builtin on gfx950.
__device__ __forceinline__ unsigned int pk2c(float a, float b){
    unsigned int r;
    asm("v_cvt_pk_bf16_f32 %0, %1, %2" : "=v"(r) : "v"(a), "v"(b));
    return r;
}

#if __has_builtin(__builtin_amdgcn_fdot2_f32_bf16)
__device__ __forceinline__ float DOT2B(s16x2 a, s16x2 b, float c){
    return __builtin_amdgcn_fdot2_f32_bf16(a, b, c, false);
}
#else
__device__ __forceinline__ float DOT2B(s16x2 a, s16x2 b, float c){
    return fmaf(bfu((unsigned short)a.x), bfu((unsigned short)b.x),
           fmaf(bfu((unsigned short)a.y), bfu((unsigned short)b.y), c));
}
#endif

// ---------------- K0a: sequential coefficient core (1 block) ----------------
__global__ void k_coef1(const float* __restrict__ wlp1, const float* __restrict__ whp1,
                        const float* __restrict__ wlp2,
                        float* __restrict__ ahp1s,
                        float* __restrict__ cpG, float* __restrict__ cnG){
    __shared__ float aL[508], ah[508];
    int t = threadIdx.x;
    if (t < 508){
        int g = t >> 2, o = t & 3;
        float s = 0.f, s2 = 0.f;
        for (int i = 0; i < 4; ++i){ s += wlp1[g*16 + o*4 + i]; s2 += whp1[g*16 + o*4 + i]; }
        aL[t] = s; ah[t] = s2;
    }
    __syncthreads();
    if (t < 508){
        int g = t >> 2, o = t & 3;
        float p = 0.f, n = 0.f;
        for (int k = 0; k < 4; ++k){
            int idx = 4*g + k;                    // shuffled position
            int inv = (idx % 127)*4 + idx/127;    // original channel
            float av = aL[inv];
            float w2 = wlp2[g*16 + o*4 + k];
            p += w2 * fmaxf(av, 0.f);
            n += w2 * fminf(av, 0.f);
        }
        cpG[t] = p; cnG[t] = n;
        int inv = (t % 127)*4 + t/127;
        ahp1s[t] = ah[inv];
    }
}

// ---------------- K0b: parallel table fills (64 blocks, grid-strided) ----------------
__global__ void k_coef2(const float* __restrict__ wld, const float* __restrict__ whd,
                        const float* __restrict__ winP, const float* __restrict__ winD,
                        const float* __restrict__ wout,
                        const float* __restrict__ cp, const float* __restrict__ cn,
                        unsigned int* __restrict__ WPNL, unsigned int* __restrict__ WPNH,
                        unsigned int* __restrict__ WLDpk, unsigned int* __restrict__ WHDpk,
                        float* __restrict__ wDp,
                        unsigned short* __restrict__ WPb, unsigned short* __restrict__ BtP){
    int t0 = blockIdx.x*256 + threadIdx.x;
    int str = gridDim.x*256;
    // analytic tables, packed (pos,neg) bf16 pairs
    for (int idx = t0; idx < 127*9; idx += str){
        int g = idx/9, q = idx%9;
        float lp=0.f, ln=0.f, hp=0.f, hn=0.f;
        for (int i = 0; i < 4; ++i){
            int ch = 4*g + i;
            if (ch < 254){ float w = wld[g*36 + i*9 + q]; lp += w*cp[ch]; ln += w*cn[ch]; }
            else         { float w = whd[g*36 + i*9 + q]; hp += w*cp[ch]; hn += w*cn[ch]; }
        }
        WPNL[idx] = pk2(lp, ln);
        WPNH[idx] = pk2(hp, hn);
    }
    // conv tables, packed channel-pair bf16 weights (masked to h2-sourced channels)
    for (int idx = t0; idx < 127*18; idx += str){
        int g = idx/18, r = idx%18; int q = r >> 1, hp_ = r & 1;
        int c0 = 4*g + 2*hp_, c1 = c0 + 1;
        float wl0 = (c0 >= 254) ? wld[g*36 + (2*hp_)*9 + q]   : 0.f;
        float wl1 = (c1 >= 254) ? wld[g*36 + (2*hp_+1)*9 + q] : 0.f;
        float wh0 = (c0 <  254) ? whd[g*36 + (2*hp_)*9 + q]   : 0.f;
        float wh1 = (c1 <  254) ? whd[g*36 + (2*hp_+1)*9 + q] : 0.f;
        WLDpk[idx] = pk2(wl0, wl1);
        WHDpk[idx] = pk2(wh0, wh1);
    }
    // wDp: [512 tch][9], zero-padded winD (508x9)
    for (int idx = t0; idx < 512*9; idx += str){
        int ch = idx/9, q = idx - ch*9;
        wDp[idx] = (ch < 508) ? winD[ch*9 + q] : 0.f;
    }
    // WPb: [256 o][64 k] bf16, zero-padded winP
    for (int idx = t0; idx < 256*64; idx += str){
        int o = idx >> 6, k = idx & 63;
        float vv = (o < 254 && k < 48) ? winP[o*48 + k] : 0.f;
        WPb[idx] = f2bu(vv);
    }
    // BtP: [48 n][256 k] bf16; k=2g -> wout[n][g] (l), k=2g+1 -> wout[n][127+g] (h)
    for (int idx = t0; idx < 48*256; idx += str){
        int n = idx >> 8, k = idx & 255;
        int g = k >> 1;
        float vv = (g < 127) ? ((k & 1) ? wout[n*254 + 127 + g] : wout[n*254 + g]) : 0.f;
        BtP[idx] = f2bu(vv);
    }
}

// ---------------- per-band border zeroing ----------------
__global__ void k_padU(uint4* __restrict__ u, float* __restrict__ Lm, unsigned int* __restrict__ Lpk,
                       int uRp, int lRp, int nbat, int zeroTop, int zeroBot){
    int p = blockIdx.x, t = threadIdx.x;
    int nu = nbat*32;
    if (p < nu){
        uint4* pl = u + (size_t)p*uRp*258;
        uint4 z = make_uint4(0,0,0,0);
        for (int i = t; i < 258; i += 256){ pl[i] = z; pl[(size_t)(uRp-1)*258 + i] = z; }
        for (int r = t; r < uRp; r += 256){ pl[(size_t)r*258] = z; pl[(size_t)r*258 + 257] = z; }
    } else {
        float* pl = Lm + (size_t)(p-nu)*lRp*258;
        unsigned int* pk = Lpk + (size_t)(p-nu)*lRp*258;
        if (zeroTop) for (int i = t; i < 258; i += 256){ pl[i] = 0.f; pk[i] = 0u; }
        if (zeroBot) for (int i = t; i < 258; i += 256){ pl[(size_t)(lRp-1)*258 + i] = 0.f; pk[(size_t)(lRp-1)*258 + i] = 0u; }
        for (int r = t; r < lRp; r += 256){
            pl[(size_t)r*258] = 0.f; pl[(size_t)r*258 + 257] = 0.f;
            pk[(size_t)r*258] = 0u;  pk[(size_t)r*258 + 257] = 0u;
        }
    }
}

// ---------------- K1a: u = w_inP @ x (1x1 48->254) via MFMA, padded oct layout ----------------
__global__ __launch_bounds__(256) void k_pconv(const float* __restrict__ x,
        const unsigned short* __restrict__ WPb, uint4* __restrict__ u,
        int b0, int ur0, int urows, int uRp){
    __shared__ unsigned short BtS[256*72];   // 36864 B; epilogue overlays [64px][264 u16]=33792 B
    int t = threadIdx.x;
    for (int i = t; i < 256*64; i += 256){
        int o = i >> 6, k = i & 63;
        BtS[o*72 + k] = WPb[i];
    }
    int bpb = urows*4;
    int bi = blockIdx.x / bpb;
    int r  = blockIdx.x - bi*bpb;
    int lr = r >> 2, quarter = r & 3;
    int b = b0 + bi;
    int grow = ur0 + lr;
    const float* xb = x + (size_t)b*48*HW + (size_t)grow*256 + quarter*64;
    int w = t >> 6, lane = t & 63;
    int px = w*16 + (lane & 15);
    int k0 = (lane >> 4)*8;
    bf16x8 afr[2];
    #pragma unroll
    for (int kk = 0; kk < 2; ++kk){
        #pragma unroll
        for (int j = 0; j < 8; ++j){
            int k = kk*32 + k0 + j;
            float vv = (k < 48) ? xb[(size_t)k*HW + px] : 0.f;
            afr[kk][j] = (short)f2bu(vv);
        }
    }
    __syncthreads();
    f32x4 acc[16];
    #pragma unroll
    for (int nt = 0; nt < 16; ++nt) acc[nt] = (f32x4){0.f,0.f,0.f,0.f};
    #pragma unroll
    for (int kk = 0; kk < 2; ++kk){
        #pragma unroll
        for (int nt = 0; nt < 16; ++nt){
            bf16x8 bfr = *reinterpret_cast<const bf16x8*>(&BtS[(nt*16 + (lane&15))*72 + kk*32 + k0]);
            acc[nt] = __builtin_amdgcn_mfma_f32_16x16x32_bf16(afr[kk], bfr, acc[nt], 0, 0, 0);
        }
    }
    __syncthreads();   // BtS dead -> epilogue buffer, stride 264 (16B-aligned rows)
    unsigned short* E = BtS;
    #pragma unroll
    for (int nt = 0; nt < 16; ++nt){
        #pragma unroll
        for (int rg = 0; rg < 4; ++rg){
            int epx = w*16 + (lane>>4)*4 + rg;
            int eo  = nt*16 + (lane&15);
            E[epx*264 + eo] = f2bu(acc[nt][rg]);
        }
    }
    __syncthreads();
    int spx = t & 63;
    size_t su = (size_t)uRp*258;
    uint4* ub = u + (size_t)bi*32*su + (size_t)(lr+1)*258 + (quarter*64 + spx + 1);
    int og = t >> 6;
    #pragma unroll
    for (int j = 0; j < 8; ++j){
        int od = og*8 + j;
        uint4 q4 = *reinterpret_cast<const uint4*>(&E[spx*264 + od*8]);
        ub[(size_t)od*su] = q4;
    }
}

// ---------------- K1b: depthwise 3x3 x2 + relu + channel-sum + fused h-g1x1 -> shuffled d1s ----------------
__global__ __launch_bounds__(256) void k_dw(const uint4* __restrict__ u,
        const float* __restrict__ wDp, const float* __restrict__ whp1,
        unsigned short* __restrict__ d1s, float* __restrict__ Sp,
        int tr0, int trows, int ur0, int uRp, int tR, int nbat){
    int chunk = blockIdx.x & (NCH-1);
    int rb = blockIdx.x >> 4;
    int bi = rb / trows;
    int lr = rb - bi*trows;
    int grow = tr0 + lr;
    int xx = threadIdx.x;
    int lrow = grow - ur0;
    size_t su = (size_t)uRp*258;
    const uint4* ubase = u + (size_t)bi*32*su + (size_t)lrow*258 + xx;
    unsigned short* db = d1s + (size_t)bi*127*tR*256*4 + ((size_t)lr*256 + xx)*4;
    size_t dcs = (size_t)tR*256*4;
    float ssum = 0.f;
    int od0 = chunk*2;
    for (int od = od0; od < od0+2; ++od){
        const uint4* up = ubase + (size_t)od*su;
        float o[16];
        #pragma unroll
        for (int j = 0; j < 16; ++j) o[j] = 0.f;
        #pragma unroll
        for (int q = 0; q < 9; ++q){
            uint4 rv = up[(q/3)*258 + (q%3)];
            float c0 = bflo(rv.x), c1 = bfhi(rv.x), c2 = bflo(rv.y), c3 = bfhi(rv.y);
            float c4 = bflo(rv.z), c5 = bfhi(rv.z), c6 = bflo(rv.w), c7 = bfhi(rv.w);
            const float* wq = wDp + (size_t)(16*od)*9 + q;
            o[0]  = fmaf(wq[0],   c0, o[0]);
            o[1]  = fmaf(wq[9],   c0, o[1]);
            o[2]  = fmaf(wq[18],  c1, o[2]);
            o[3]  = fmaf(wq[27],  c1, o[3]);
            o[4]  = fmaf(wq[36],  c2, o[4]);
            o[5]  = fmaf(wq[45],  c2, o[5]);
            o[6]  = fmaf(wq[54],  c3, o[6]);
            o[7]  = fmaf(wq[63],  c3, o[7]);
            o[8]  = fmaf(wq[72],  c4, o[8]);
            o[9]  = fmaf(wq[81],  c4, o[9]);
            o[10] = fmaf(wq[90],  c5, o[10]);
            o[11] = fmaf(wq[99],  c5, o[11]);
            o[12] = fmaf(wq[108], c6, o[12]);
            o[13] = fmaf(wq[117], c6, o[13]);
            o[14] = fmaf(wq[126], c7, o[14]);
            o[15] = fmaf(wq[135], c7, o[15]);
        }
        #pragma unroll
        for (int j = 0; j < 16; ++j){ o[j] = fmaxf(o[j], 0.f); ssum += o[j]; }
        int tqb = 4*od;
        #pragma unroll
        for (int m = 0; m < 4; ++m){
            int tq = tqb + m;
            if (tq < 127){
                const float* w1 = whp1 + tq*16;
                #pragma unroll
                for (int oi = 0; oi < 4; ++oi){
                    float d = fmaf(w1[oi*4+0], o[4*m+0], fmaf(w1[oi*4+1], o[4*m+1],
                              fmaf(w1[oi*4+2], o[4*m+2], w1[oi*4+3]*o[4*m+3])));
                    int idx = 127*oi + tq;
                    db[(size_t)(idx>>2)*dcs + (idx&3)] = f2bu(d);
                }
            }
        }
    }
    Sp[((size_t)(chunk*nbat + bi)*tR + lr)*256 + xx] = ssum * (1.f/9.f);
}

// ---------------- K2: sum chunks + 3x3 box -> padded Lm (f32) + Lpk (packed max/min bf16) ----------------
__global__ __launch_bounds__(256) void k_box(const float* __restrict__ Sp, float* __restrict__ Lm,
        unsigned int* __restrict__ Lpk,
        int lr0, int lrows, int tr0, int tR, int a, int lRp, int nbat){
    int bi = blockIdx.x / lrows;
    int lr = blockIdx.x - bi*lrows;
    int grow = lr0 + lr;
    int xx = threadIdx.x;
    int g0 = (grow-1 > 0 ? grow-1 : 0) - tr0, g1 = grow - tr0, g2 = (grow+1 < 255 ? grow+1 : 255) - tr0;
    int x0 = xx-1 > 0 ? xx-1 : 0, x2 = xx+1 < 255 ? xx+1 : 255;
    float s = 0.f;
    for (int ch = 0; ch < NCH; ++ch){
        const float* Sb = Sp + ((size_t)(ch*nbat + bi)*tR)*256;
        s += Sb[g0*256+x0]+Sb[g0*256+xx]+Sb[g0*256+x2]
           + Sb[g1*256+x0]+Sb[g1*256+xx]+Sb[g1*256+x2]
           + Sb[g2*256+x0]+Sb[g2*256+xx]+Sb[g2*256+x2];
    }
    size_t o = (size_t)bi*lRp*258 + (size_t)(grow-a+1)*258 + xx + 1;
    Lm[o] = s;
    Lpk[o] = pk2c(fmaxf(s, 0.f), fminf(s, 0.f));
}

// ---------------- K3: fused h-finish + grouped 3x3 -> v, 8-row tiles, rolling registers ----------------
__global__ __launch_bounds__(256) void k_mov(const ushort4* __restrict__ d1s,
     const float* __restrict__ Lm, const unsigned int* __restrict__ Lpk,
     const float* __restrict__ whp2, const float* __restrict__ ahp1s,
     const unsigned int* __restrict__ WPNL, const unsigned int* __restrict__ WPNH,
     const unsigned int* __restrict__ WLDpk, const unsigned int* __restrict__ WHDpk,
     unsigned int* __restrict__ v,
     int a, int orows, int tr0, int tR, int lRp){
    __shared__ uint2 h2t[10][258];
    int g = blockIdx.x % 127;
    int rest = blockIdx.x / 127;
    int ntiles = orows >> 3;
    int ti = rest % ntiles;
    int bi = rest / ntiles;
    int px = threadIdx.x;
    int row0 = a + ti*8;
    // ---- phase 1: build h2 tile (10 rows) in LDS ----
    const ushort4* db = d1s + ((size_t)bi*127 + g)*tR*256;
    const float* Lb = Lm + (size_t)bi*lRp*258;
    float as0 = ahp1s[4*g], as1 = ahp1s[4*g+1], as2 = ahp1s[4*g+2], as3 = ahp1s[4*g+3];
    float w2r[16];
    #pragma unroll
    for (int i = 0; i < 16; ++i) w2r[i] = whp2[g*16 + i];
    #pragma unroll
    for (int rr = 0; rr < 10; ++rr){
        int gr = row0 - 1 + rr;
        uint2 hv; hv.x = 0u; hv.y = 0u;
        if (gr >= 0 && gr < 256){
            ushort4 dq = db[(size_t)(gr - tr0)*256 + px];
            float Lv = Lb[(size_t)(gr - a + 1)*258 + px + 1];
            float h0 = fmaxf(fmaf(-Lv, as0, bfu(dq.x)), 0.f);
            float h1 = fmaxf(fmaf(-Lv, as1, bfu(dq.y)), 0.f);
            float hm2 = fmaxf(fmaf(-Lv, as2, bfu(dq.z)), 0.f);
            float h3 = fmaxf(fmaf(-Lv, as3, bfu(dq.w)), 0.f);
            float a0 = fmaf(w2r[0], h0, fmaf(w2r[1], h1, fmaf(w2r[2], hm2, w2r[3]*h3)));
            float a1 = fmaf(w2r[4], h0, fmaf(w2r[5], h1, fmaf(w2r[6], hm2, w2r[7]*h3)));
            float a2 = fmaf(w2r[8], h0, fmaf(w2r[9], h1, fmaf(w2r[10], hm2, w2r[11]*h3)));
            float a3 = fmaf(w2r[12], h0, fmaf(w2r[13], h1, fmaf(w2r[14], hm2, w2r[15]*h3)));
            hv.x = pk2c(a0, a1);
            hv.y = pk2c(a2, a3);
        }
        h2t[rr][px+1] = hv;
    }
    if (px < 10){ uint2 z; z.x = 0u; z.y = 0u; h2t[px][0] = z; h2t[px][257] = z; }
    __syncthreads();
    // ---- block-uniform tables ----
    s16x2 WPl[9], WPh[9];
    #pragma unroll
    for (int q = 0; q < 9; ++q){
        WPl[q] = __builtin_bit_cast(s16x2, WPNL[g*9+q]);
        WPh[q] = __builtin_bit_cast(s16x2, WPNH[g*9+q]);
    }
    bool lbr = (g >= 63), hbr = (g <= 63);
    s16x2 WDl[18], WDh[18];
    #pragma unroll
    for (int i = 0; i < 18; ++i){
        WDl[i] = __builtin_bit_cast(s16x2, WLDpk[g*18+i]);
        WDh[i] = __builtin_bit_cast(s16x2, WHDpk[g*18+i]);
    }
    // ---- phase 2: rolling registers over 8 output rows ----
    size_t ps = (size_t)orows*256;
    unsigned int* vb = v + ((size_t)bi*128 + g)*ps + (size_t)(ti*8)*256 + px;
    const unsigned int* Lq = Lpk + (size_t)bi*lRp*258 + (size_t)(ti*8)*258 + px;   // tap row base
    s16x2 lq[3][3];
    uint2 ta[3][3];
    #pragma unroll
    for (int rr = 0; rr < 2; ++rr){
        #pragma unroll
        for (int c = 0; c < 3; ++c){
            lq[rr][c] = __builtin_bit_cast(s16x2, Lq[(size_t)rr*258 + c]);
            ta[rr][c] = h2t[rr][px + c];
        }
    }
    #pragma unroll
    for (int r = 0; r < 8; ++r){
        #pragma unroll
        for (int c = 0; c < 3; ++c){
            lq[2][c] = __builtin_bit_cast(s16x2, Lq[(size_t)(r+2)*258 + c]);
            ta[2][c] = h2t[r+2][px + c];
        }
        float sl0 = 0.f, sl1 = 0.f, sh0 = 0.f, sh1 = 0.f;
        #pragma unroll
        for (int dy = 0; dy < 3; ++dy){
            #pragma unroll
            for (int dx = 0; dx < 3; ++dx){
                int q = dy*3 + dx;
                if (q & 1){ sl1 = DOT2B(lq[dy][dx], WPl[q], sl1); sh1 = DOT2B(lq[dy][dx], WPh[q], sh1); }
                else      { sl0 = DOT2B(lq[dy][dx], WPl[q], sl0); sh0 = DOT2B(lq[dy][dx], WPh[q], sh0); }
            }
        }
        if (lbr){
            #pragma unroll
            for (int dy = 0; dy < 3; ++dy){
                #pragma unroll
                for (int dx = 0; dx < 3; ++dx){
                    int q = dy*3 + dx;
                    uint2 tv = ta[dy][dx];
                    sl0 = DOT2B(__builtin_bit_cast(s16x2, tv.x), WDl[2*q],   sl0);
                    sl1 = DOT2B(__builtin_bit_cast(s16x2, tv.y), WDl[2*q+1], sl1);
                }
            }
        }
        if (hbr){
            #pragma unroll
            for (int dy = 0; dy < 3; ++dy){
                #pragma unroll
                for (int dx = 0; dx < 3; ++dx){
                    int q = dy*3 + dx;
                    uint2 tv = ta[dy][dx];
                    sh0 = DOT2B(__builtin_bit_cast(s16x2, tv.x), WDh[2*q],   sh0);
                    sh1 = DOT2B(__builtin_bit_cast(s16x2, tv.y), WDh[2*q+1], sh1);
                }
            }
        }
        vb[(size_t)r*256] = pk2c(fmaxf(sl0+sl1, 0.f), fmaxf(sh0+sh1, 0.f));
        if (g == 126) vb[(size_t)r*256 + ps] = 0u;   // zero pad plane 127
        #pragma unroll
        for (int c = 0; c < 3; ++c){
            ta[0][c] = ta[1][c]; ta[1][c] = ta[2][c];
            lq[0][c] = lq[1][c]; lq[1][c] = lq[2][c];
        }
    }
}

// ---------------- K4: out = v @ BtP^T + x via MFMA, fused residual ----------------
__global__ __launch_bounds__(256) void k_proj(const unsigned int* __restrict__ v,
        const unsigned short* __restrict__ BtP, const float* __restrict__ x,
        float* __restrict__ out, int b0, int a, int orows){
    __shared__ float EoS[256*49];            // 50176 B; Bt overlays first 26112 B
    unsigned short* Bt = (unsigned short*)EoS;   // [48 n][136 u16]
    int t = threadIdx.x;
    for (int i = t; i < 48*256; i += 256){
        int n = i >> 8, k = i & 255;
        Bt[n*136 + k] = BtP[i];
    }
    int bi = blockIdx.x / orows;
    int lr = blockIdx.x - bi*orows;
    int b = b0 + bi;
    size_t ps = (size_t)orows*256;
    const unsigned int* vb = v + (size_t)bi*128*ps + (size_t)lr*256;
    int lane = t & 63, w = t >> 6;
    int pxl = w*64;
    __syncthreads();
    f32x4 acc[4][3];
    #pragma unroll
    for (int m = 0; m < 4; ++m)
        #pragma unroll
        for (int nt = 0; nt < 3; ++nt) acc[m][nt] = (f32x4){0.f,0.f,0.f,0.f};
    #pragma unroll
    for (int ch = 0; ch < 4; ++ch){
        bf16x8 bfr[3][2];
        #pragma unroll
        for (int nt = 0; nt < 3; ++nt)
            #pragma unroll
            for (int kk = 0; kk < 2; ++kk)
                bfr[nt][kk] = *reinterpret_cast<const bf16x8*>(
                    &Bt[(nt*16 + (lane&15))*136 + ch*64 + kk*32 + (lane>>4)*8]);
        #pragma unroll
        for (int m = 0; m < 4; ++m){
            int px = pxl + m*16 + (lane & 15);
            #pragma unroll
            for (int kk = 0; kk < 2; ++kk){
                int pl0 = ch*32 + kk*16 + (lane>>4)*4;
                unsigned int p0 = vb[(size_t)(pl0+0)*ps + px];
                unsigned int p1 = vb[(size_t)(pl0+1)*ps + px];
                unsigned int p2 = vb[(size_t)(pl0+2)*ps + px];
                unsigned int p3 = vb[(size_t)(pl0+3)*ps + px];
                bf16x8 af;
                af[0]=(short)(p0&0xffff); af[1]=(short)(p0>>16);
                af[2]=(short)(p1&0xffff); af[3]=(short)(p1>>16);
                af[4]=(short)(p2&0xffff); af[5]=(short)(p2>>16);
                af[6]=(short)(p3&0xffff); af[7]=(short)(p3>>16);
                #pragma unroll
                for (int nt = 0; nt < 3; ++nt)
                    acc[m][nt] = __builtin_amdgcn_mfma_f32_16x16x32_bf16(af, bfr[nt][kk], acc[m][nt], 0, 0, 0);
            }
        }
    }
    __syncthreads();   // Bt dead -> epilogue buffer
    #pragma unroll
    for (int m = 0; m < 4; ++m){
        #pragma unroll
        for (int nt = 0; nt < 3; ++nt){
            #pragma unroll
            for (int rg = 0; rg < 4; ++rg){
                int epx = pxl + m*16 + (lane>>4)*4 + rg;
                int eo  = nt*16 + (lane&15);
                EoS[epx*49 + eo] = acc[m][nt][rg];
            }
        }
    }
    __syncthreads();
    int grow = a + lr;
    const float* xb = x + (size_t)b*48*HW + (size_t)grow*256 + t;
    float* ob = out + (size_t)b*48*HW + (size_t)grow*256 + t;
    #pragma unroll
    for (int o = 0; o < 48; ++o)
        ob[(size_t)o*HW] = EoS[t*49 + o] + xb[(size_t)o*HW];
}

extern "C" void kernel_launch(void* const* d_in, const int* in_sizes, int n_in,
                              void* d_out, int out_size, void* d_ws, size_t ws_size,
                              hipStream_t stream){
    const float* x    = (const float*)d_in[0];
    const float* winP = (const float*)d_in[1];
    const float* winD = (const float*)d_in[2];
    const float* wlp1 = (const float*)d_in[3];
    const float* whp1 = (const float*)d_in[4];
    const float* wlp2 = (const float*)d_in[5];
    const float* whp2 = (const float*)d_in[6];
    const float* wld  = (const float*)d_in[7];
    const float* whd  = (const float*)d_in[8];
    const float* wout = (const float*)d_in[9];
    float* out = (float*)d_out;

    char* ws = (char*)d_ws;
    size_t off = 0;
    auto alloc = [&](size_t bytes)->char*{
        char* pp = ws + off; off += (bytes + 255) & ~(size_t)255; return pp;
    };
    auto A = [](size_t bytes)->size_t{ return (bytes + 255) & ~(size_t)255; };

    float* ahp1s = (float*)alloc(508*4);
    float* cpG = (float*)alloc(508*4);
    float* cnG = (float*)alloc(508*4);
    unsigned int* WPNL  = (unsigned int*)alloc(127*9*4);
    unsigned int* WPNH  = (unsigned int*)alloc(127*9*4);
    unsigned int* WLDpk = (unsigned int*)alloc(127*18*4);
    unsigned int* WHDpk = (unsigned int*)alloc(127*18*4);
    float* wDp  = (float*)alloc(512*9*4);
    unsigned short* WPb = (unsigned short*)alloc(256*64*2);
    unsigned short* BtP = (unsigned short*)alloc(48*256*2);

    // ladder: Hb must be a multiple of 8 (k_mov tiles)
    const int cfgs[6][2] = {{256,2},{128,2},{64,2},{64,1},{32,1},{16,1}};
    int Hb = 16, nbat = 1;
    for (int ci = 0; ci < 6; ++ci){
        int hb = cfgs[ci][0], nb = cfgs[ci][1];
        int uRr = hb+6 < 256 ? hb+6 : 256;
        int tRr = hb+4 < 256 ? hb+4 : 256;
        size_t need = off;
        need += A((size_t)nb*32*(uRr+2)*258*16);   // u (padded oct layout; v aliases it)
        need += A((size_t)nb*127*tRr*256*8);       // d1s
        need += A((size_t)nb*NCH*tRr*256*4);       // Sp
        need += A((size_t)nb*(hb+2)*258*4);        // Lm (padded)
        need += A((size_t)nb*(hb+2)*258*4);        // Lpk (padded)
        if (need <= ws_size){ Hb = hb; nbat = nb; break; }
    }
    int uR = Hb+6 < 256 ? Hb+6 : 256;
    int tR = Hb+4 < 256 ? Hb+4 : 256;
    int uRp = uR + 2;
    int lRp = Hb + 2;
    uint4* u   = (uint4*)alloc((size_t)nbat*32*uRp*258*16);
    unsigned short* d1s = (unsigned short*)alloc((size_t)nbat*127*tR*256*8);
    float* Sp = (float*)alloc((size_t)nbat*NCH*tR*256*4);
    float* Lm = (float*)alloc((size_t)nbat*lRp*258*4);
    unsigned int* Lpk = (unsigned int*)alloc((size_t)nbat*lRp*258*4);
    // v aliases u: u is dead after k_dw; per-band order pconv->dw->mov->proj keeps it safe.
    unsigned int* v = (unsigned int*)u;

    k_coef1<<<1, 512, 0, stream>>>(wlp1, whp1, wlp2, ahp1s, cpG, cnG);
    k_coef2<<<64, 256, 0, stream>>>(wld, whd, winP, winD, wout, cpG, cnG,
                                    WPNL, WPNH, WLDpk, WHDpk, wDp, WPb, BtP);

    for (int b0 = 0; b0 < 2; b0 += nbat){
        for (int a = 0; a < 256; a += Hb){
            int ur0 = a-3 > 0 ? a-3 : 0;  int ur1 = a+Hb+3 < 256 ? a+Hb+3 : 256;
            int tr0 = a-2 > 0 ? a-2 : 0;  int tr1 = a+Hb+2 < 256 ? a+Hb+2 : 256;
            int lr0 = a-1 > 0 ? a-1 : 0;  int lr1 = a+Hb+1 < 256 ? a+Hb+1 : 256;
            int urows = ur1-ur0, trows = tr1-tr0, lrows = lr1-lr0;
            int orows = (a+Hb < 256 ? a+Hb : 256) - a;
            k_padU<<<nbat*32 + nbat, 256, 0, stream>>>(u, Lm, Lpk, uRp, lRp, nbat,
                                                       a == 0, a + Hb >= 256);
            k_pconv<<<nbat*urows*4, 256, 0, stream>>>(x, WPb, u, b0, ur0, urows, uRp);
            k_dw  <<<nbat*trows*NCH, 256, 0, stream>>>(u, wDp, whp1, d1s, Sp, tr0, trows, ur0, uRp, tR, nbat);
            k_box <<<nbat*lrows, 256, 0, stream>>>(Sp, Lm, Lpk, lr0, lrows, tr0, tR, a, lRp, nbat);
            k_mov <<<nbat*(orows>>3)*127, 256, 0, stream>>>((const ushort4*)d1s, Lm, Lpk, whp2, ahp1s,
                                                            WPNL, WPNH, WLDpk, WHDpk, v,
                                                            a, orows, tr0, tR, lRp);
            k_proj<<<nbat*orows, 256, 0, stream>>>(v, BtP, x, out, b0, a, orows);
        }
    }
}

// Round 14
// 163.452 us; speedup vs baseline: 12.1300x; 1.0724x over previous
//
#include <hip/hip_runtime.h>
#include <hip/hip_bf16.h>

#define HW 65536
#define NCH 16   // channel chunks in k_dw (2 octs each)

typedef __attribute__((ext_vector_type(8))) short bf16x8;
typedef __attribute__((ext_vector_type(4))) float f32x4;
typedef __attribute__((ext_vector_type(2))) float f32x2;
typedef __attribute__((ext_vector_type(2))) short s16x2;

__device__ __forceinline__ float bfu(unsigned short u){
    return __uint_as_float(((unsigned int)u) << 16);
}
__device__ __forceinline__ float bflo(unsigned int u){
    return __uint_as_float(u << 16);
}
__device__ __forceinline__ float bfhi(unsigned int u){
    return __uint_as_float(u & 0xffff0000u);
}
__device__ __forceinline__ unsigned short f2bu(float f){
    return __builtin_bit_cast(unsigned short, __float2bfloat16(f));
}
__device__ __forceinline__ unsigned int pk2(float a, float b){
    return (unsigned int)f2bu(a) | ((unsigned int)f2bu(b) << 16);
}
// v_cvt_pk_bf16_f32: packs (a,b) -> (lo=bf16(a), hi=bf16(b)), RTNE. No builtin on gfx950.
__device__ __forceinline__ unsigned int pk2c(float a, float b){
    unsigned int r;
    asm("v_cvt_pk_bf16_f32 %0, %1, %2" : "=v"(r) : "v"(a), "v"(b));
    return r;
}

#if __has_builtin(__builtin_amdgcn_fdot2_f32_bf16)
__device__ __forceinline__ float DOT2B(s16x2 a, s16x2 b, float c){
    return __builtin_amdgcn_fdot2_f32_bf16(a, b, c, false);
}
#else
__device__ __forceinline__ float DOT2B(s16x2 a, s16x2 b, float c){
    return fmaf(bfu((unsigned short)a.x), bfu((unsigned short)b.x),
           fmaf(bfu((unsigned short)a.y), bfu((unsigned short)b.y), c));
}
#endif

// ---------------- K0a: sequential coefficient core (1 block) ----------------
__global__ void k_coef1(const float* __restrict__ wlp1, const float* __restrict__ whp1,
                        const float* __restrict__ wlp2,
                        float* __restrict__ ahp1s,
                        float* __restrict__ cpG, float* __restrict__ cnG){
    __shared__ float aL[508], ah[508];
    int t = threadIdx.x;
    if (t < 508){
        int g = t >> 2, o = t & 3;
        float s = 0.f, s2 = 0.f;
        for (int i = 0; i < 4; ++i){ s += wlp1[g*16 + o*4 + i]; s2 += whp1[g*16 + o*4 + i]; }
        aL[t] = s; ah[t] = s2;
    }
    __syncthreads();
    if (t < 508){
        int g = t >> 2, o = t & 3;
        float p = 0.f, n = 0.f;
        for (int k = 0; k < 4; ++k){
            int idx = 4*g + k;                    // shuffled position
            int inv = (idx % 127)*4 + idx/127;    // original channel
            float av = aL[inv];
            float w2 = wlp2[g*16 + o*4 + k];
            p += w2 * fmaxf(av, 0.f);
            n += w2 * fminf(av, 0.f);
        }
        cpG[t] = p; cnG[t] = n;
        int inv = (t % 127)*4 + t/127;
        ahp1s[t] = ah[inv];
    }
}

// ---------------- K0b: parallel table fills (64 blocks, grid-strided) ----------------
__global__ void k_coef2(const float* __restrict__ wld, const float* __restrict__ whd,
                        const float* __restrict__ winP, const float* __restrict__ winD,
                        const float* __restrict__ wout,
                        const float* __restrict__ cp, const float* __restrict__ cn,
                        unsigned int* __restrict__ WPNL, unsigned int* __restrict__ WPNH,
                        unsigned int* __restrict__ WLDpk, unsigned int* __restrict__ WHDpk,
                        float* __restrict__ wDp,
                        unsigned short* __restrict__ WPb, unsigned short* __restrict__ BtP){
    int t0 = blockIdx.x*256 + threadIdx.x;
    int str = gridDim.x*256;
    // analytic tables, packed (pos,neg) bf16 pairs
    for (int idx = t0; idx < 127*9; idx += str){
        int g = idx/9, q = idx%9;
        float lp=0.f, ln=0.f, hp=0.f, hn=0.f;
        for (int i = 0; i < 4; ++i){
            int ch = 4*g + i;
            if (ch < 254){ float w = wld[g*36 + i*9 + q]; lp += w*cp[ch]; ln += w*cn[ch]; }
            else         { float w = whd[g*36 + i*9 + q]; hp += w*cp[ch]; hn += w*cn[ch]; }
        }
        WPNL[idx] = pk2(lp, ln);
        WPNH[idx] = pk2(hp, hn);
    }
    // conv tables, packed channel-pair bf16 weights (masked to h2-sourced channels)
    for (int idx = t0; idx < 127*18; idx += str){
        int g = idx/18, r = idx%18; int q = r >> 1, hp_ = r & 1;
        int c0 = 4*g + 2*hp_, c1 = c0 + 1;
        float wl0 = (c0 >= 254) ? wld[g*36 + (2*hp_)*9 + q]   : 0.f;
        float wl1 = (c1 >= 254) ? wld[g*36 + (2*hp_+1)*9 + q] : 0.f;
        float wh0 = (c0 <  254) ? whd[g*36 + (2*hp_)*9 + q]   : 0.f;
        float wh1 = (c1 <  254) ? whd[g*36 + (2*hp_+1)*9 + q] : 0.f;
        WLDpk[idx] = pk2(wl0, wl1);
        WHDpk[idx] = pk2(wh0, wh1);
    }
    // wDp: [512 tch][9], zero-padded winD (508x9)
    for (int idx = t0; idx < 512*9; idx += str){
        int ch = idx/9, q = idx - ch*9;
        wDp[idx] = (ch < 508) ? winD[ch*9 + q] : 0.f;
    }
    // WPb: [256 o][64 k] bf16, zero-padded winP
    for (int idx = t0; idx < 256*64; idx += str){
        int o = idx >> 6, k = idx & 63;
        float vv = (o < 254 && k < 48) ? winP[o*48 + k] : 0.f;
        WPb[idx] = f2bu(vv);
    }
    // BtP: [48 n][256 k] bf16; k=2g -> wout[n][g] (l), k=2g+1 -> wout[n][127+g] (h)
    for (int idx = t0; idx < 48*256; idx += str){
        int n = idx >> 8, k = idx & 255;
        int g = k >> 1;
        float vv = (g < 127) ? ((k & 1) ? wout[n*254 + 127 + g] : wout[n*254 + g]) : 0.f;
        BtP[idx] = f2bu(vv);
    }
}

// ---------------- per-band border zeroing ----------------
__global__ void k_padU(uint4* __restrict__ u, float* __restrict__ Lm, unsigned int* __restrict__ Lpk,
                       int uRp, int lRp, int nbat, int zeroTop, int zeroBot){
    int p = blockIdx.x, t = threadIdx.x;
    int nu = nbat*32;
    if (p < nu){
        uint4* pl = u + (size_t)p*uRp*258;
        uint4 z = make_uint4(0,0,0,0);
        for (int i = t; i < 258; i += 256){ pl[i] = z; pl[(size_t)(uRp-1)*258 + i] = z; }
        for (int r = t; r < uRp; r += 256){ pl[(size_t)r*258] = z; pl[(size_t)r*258 + 257] = z; }
    } else {
        float* pl = Lm + (size_t)(p-nu)*lRp*258;
        unsigned int* pk = Lpk + (size_t)(p-nu)*lRp*258;
        if (zeroTop) for (int i = t; i < 258; i += 256){ pl[i] = 0.f; pk[i] = 0u; }
        if (zeroBot) for (int i = t; i < 258; i += 256){ pl[(size_t)(lRp-1)*258 + i] = 0.f; pk[(size_t)(lRp-1)*258 + i] = 0u; }
        for (int r = t; r < lRp; r += 256){
            pl[(size_t)r*258] = 0.f; pl[(size_t)r*258 + 257] = 0.f;
            pk[(size_t)r*258] = 0u;  pk[(size_t)r*258 + 257] = 0u;
        }
    }
}

// ---------------- K1a: u = w_inP @ x (1x1 48->254) via MFMA, padded oct layout ----------------
__global__ __launch_bounds__(256) void k_pconv(const float* __restrict__ x,
        const unsigned short* __restrict__ WPb, uint4* __restrict__ u,
        int b0, int ur0, int urows, int uRp){
    __shared__ unsigned short BtS[256*72];   // 36864 B; epilogue overlays [64px][264 u16]=33792 B
    int t = threadIdx.x;
    for (int i = t; i < 256*64; i += 256){
        int o = i >> 6, k = i & 63;
        BtS[o*72 + k] = WPb[i];
    }
    int bpb = urows*4;
    int bi = blockIdx.x / bpb;
    int r  = blockIdx.x - bi*bpb;
    int lr = r >> 2, quarter = r & 3;
    int b = b0 + bi;
    int grow = ur0 + lr;
    const float* xb = x + (size_t)b*48*HW + (size_t)grow*256 + quarter*64;
    int w = t >> 6, lane = t & 63;
    int px = w*16 + (lane & 15);
    int k0 = (lane >> 4)*8;
    bf16x8 afr[2];
    #pragma unroll
    for (int kk = 0; kk < 2; ++kk){
        #pragma unroll
        for (int j = 0; j < 8; ++j){
            int k = kk*32 + k0 + j;
            float vv = (k < 48) ? xb[(size_t)k*HW + px] : 0.f;
            afr[kk][j] = (short)f2bu(vv);
        }
    }
    __syncthreads();
    f32x4 acc[16];
    #pragma unroll
    for (int nt = 0; nt < 16; ++nt) acc[nt] = (f32x4){0.f,0.f,0.f,0.f};
    #pragma unroll
    for (int kk = 0; kk < 2; ++kk){
        #pragma unroll
        for (int nt = 0; nt < 16; ++nt){
            bf16x8 bfr = *reinterpret_cast<const bf16x8*>(&BtS[(nt*16 + (lane&15))*72 + kk*32 + k0]);
            acc[nt] = __builtin_amdgcn_mfma_f32_16x16x32_bf16(afr[kk], bfr, acc[nt], 0, 0, 0);
        }
    }
    __syncthreads();   // BtS dead -> epilogue buffer, stride 264 (16B-aligned rows)
    unsigned short* E = BtS;
    #pragma unroll
    for (int nt = 0; nt < 16; ++nt){
        #pragma unroll
        for (int rg = 0; rg < 4; ++rg){
            int epx = w*16 + (lane>>4)*4 + rg;
            int eo  = nt*16 + (lane&15);
            E[epx*264 + eo] = f2bu(acc[nt][rg]);
        }
    }
    __syncthreads();
    int spx = t & 63;
    size_t su = (size_t)uRp*258;
    uint4* ub = u + (size_t)bi*32*su + (size_t)(lr+1)*258 + (quarter*64 + spx + 1);
    int og = t >> 6;
    #pragma unroll
    for (int j = 0; j < 8; ++j){
        int od = og*8 + j;
        uint4 q4 = *reinterpret_cast<const uint4*>(&E[spx*264 + od*8]);
        ub[(size_t)od*su] = q4;
    }
}

// ---------------- K1b: depthwise 3x3 x2 + relu + channel-sum + fused h-g1x1 ----------------
// d1s layout: [508 planes (linear shuffled idx)][tR rows][256] u16 — dense coalesced stores.
__global__ __launch_bounds__(256) void k_dw(const uint4* __restrict__ u,
        const float* __restrict__ wDp, const float* __restrict__ whp1,
        unsigned short* __restrict__ d1s, float* __restrict__ Sp,
        int tr0, int trows, int ur0, int uRp, int tR, int nbat){
    int chunk = blockIdx.x & (NCH-1);
    int rb = blockIdx.x >> 4;
    int bi = rb / trows;
    int lr = rb - bi*trows;
    int grow = tr0 + lr;
    int xx = threadIdx.x;
    int lrow = grow - ur0;
    size_t su = (size_t)uRp*258;
    const uint4* ubase = u + (size_t)bi*32*su + (size_t)lrow*258 + xx;
    size_t ps_d = (size_t)tR*256;
    unsigned short* dbs = d1s + (size_t)bi*508*ps_d + (size_t)lr*256 + xx;
    float ssum = 0.f;
    int od0 = chunk*2;
    for (int od = od0; od < od0+2; ++od){
        const uint4* up = ubase + (size_t)od*su;
        f32x2 P[8];
        #pragma unroll
        for (int j = 0; j < 8; ++j) P[j] = (f32x2){0.f, 0.f};
        #pragma unroll
        for (int q = 0; q < 9; ++q){
            uint4 rv = up[(q/3)*258 + (q%3)];
            f32x2 d0 = (f32x2){bflo(rv.x), bfhi(rv.x)};
            f32x2 d1v = (f32x2){bflo(rv.y), bfhi(rv.y)};
            f32x2 d2 = (f32x2){bflo(rv.z), bfhi(rv.z)};
            f32x2 d3 = (f32x2){bflo(rv.w), bfhi(rv.w)};
            const float* wq = wDp + (size_t)(16*od)*9 + q;
            P[0] += (f32x2){wq[0],   wq[18]}  * d0;
            P[1] += (f32x2){wq[9],   wq[27]}  * d0;
            P[2] += (f32x2){wq[36],  wq[54]}  * d1v;
            P[3] += (f32x2){wq[45],  wq[63]}  * d1v;
            P[4] += (f32x2){wq[72],  wq[90]}  * d2;
            P[5] += (f32x2){wq[81],  wq[99]}  * d2;
            P[6] += (f32x2){wq[108], wq[126]} * d3;
            P[7] += (f32x2){wq[117], wq[135]} * d3;
        }
        // relu + channel-sum
        #pragma unroll
        for (int j = 0; j < 8; ++j){
            P[j].x = fmaxf(P[j].x, 0.f);
            P[j].y = fmaxf(P[j].y, 0.f);
            ssum += P[j].x + P[j].y;
        }
        // fused h-path first g1x1; o[4m..4m+3] = P[2m].x, P[2m+1].x, P[2m].y, P[2m+1].y
        int tqb = 4*od;
        #pragma unroll
        for (int m = 0; m < 4; ++m){
            int tq = tqb + m;
            if (tq < 127){
                float o0 = P[2*m].x, o1 = P[2*m+1].x, o2 = P[2*m].y, o3 = P[2*m+1].y;
                const float* w1 = whp1 + tq*16;
                #pragma unroll
                for (int oi = 0; oi < 4; ++oi){
                    float d = fmaf(w1[oi*4+0], o0, fmaf(w1[oi*4+1], o1,
                              fmaf(w1[oi*4+2], o2, w1[oi*4+3]*o3)));
                    int idx = 127*oi + tq;
                    dbs[(size_t)idx*ps_d] = f2bu(d);
                }
            }
        }
    }
    Sp[((size_t)(chunk*nbat + bi)*tR + lr)*256 + xx] = ssum * (1.f/9.f);
}

// ---------------- K2: sum chunks + 3x3 box -> padded Lm (f32) + Lpk (packed max/min bf16) ----------------
__global__ __launch_bounds__(256) void k_box(const float* __restrict__ Sp, float* __restrict__ Lm,
        unsigned int* __restrict__ Lpk,
        int lr0, int lrows, int tr0, int tR, int a, int lRp, int nbat){
    int bi = blockIdx.x / lrows;
    int lr = blockIdx.x - bi*lrows;
    int grow = lr0 + lr;
    int xx = threadIdx.x;
    int g0 = (grow-1 > 0 ? grow-1 : 0) - tr0, g1 = grow - tr0, g2 = (grow+1 < 255 ? grow+1 : 255) - tr0;
    int x0 = xx-1 > 0 ? xx-1 : 0, x2 = xx+1 < 255 ? xx+1 : 255;
    float s = 0.f;
    for (int ch = 0; ch < NCH; ++ch){
        const float* Sb = Sp + ((size_t)(ch*nbat + bi)*tR)*256;
        s += Sb[g0*256+x0]+Sb[g0*256+xx]+Sb[g0*256+x2]
           + Sb[g1*256+x0]+Sb[g1*256+xx]+Sb[g1*256+x2]
           + Sb[g2*256+x0]+Sb[g2*256+xx]+Sb[g2*256+x2];
    }
    size_t o = (size_t)bi*lRp*258 + (size_t)(grow-a+1)*258 + xx + 1;
    Lm[o] = s;
    Lpk[o] = pk2c(fmaxf(s, 0.f), fminf(s, 0.f));
}

// ---------------- K3: fused h-finish + grouped 3x3 -> v, 8-row tiles, rolling registers ----------------
__global__ __launch_bounds__(256) void k_mov(const unsigned short* __restrict__ d1s,
     const float* __restrict__ Lm, const unsigned int* __restrict__ Lpk,
     const float* __restrict__ whp2, const float* __restrict__ ahp1s,
     const unsigned int* __restrict__ WPNL, const unsigned int* __restrict__ WPNH,
     const unsigned int* __restrict__ WLDpk, const unsigned int* __restrict__ WHDpk,
     unsigned int* __restrict__ v,
     int a, int orows, int tr0, int tR, int lRp){
    __shared__ uint2 h2t[10][258];
    int g = blockIdx.x % 127;
    int rest = blockIdx.x / 127;
    int ntiles = orows >> 3;
    int ti = rest % ntiles;
    int bi = rest / ntiles;
    int px = threadIdx.x;
    int row0 = a + ti*8;
    // ---- phase 1: build h2 tile (10 rows) in LDS ----
    size_t ps_d = (size_t)tR*256;
    const unsigned short* dp0 = d1s + ((size_t)bi*508 + 4*g+0)*ps_d;
    const unsigned short* dp1 = d1s + ((size_t)bi*508 + 4*g+1)*ps_d;
    const unsigned short* dp2 = d1s + ((size_t)bi*508 + 4*g+2)*ps_d;
    const unsigned short* dp3 = d1s + ((size_t)bi*508 + 4*g+3)*ps_d;
    const float* Lb = Lm + (size_t)bi*lRp*258;
    float as0 = ahp1s[4*g], as1 = ahp1s[4*g+1], as2 = ahp1s[4*g+2], as3 = ahp1s[4*g+3];
    float w2r[16];
    #pragma unroll
    for (int i = 0; i < 16; ++i) w2r[i] = whp2[g*16 + i];
    #pragma unroll
    for (int rr = 0; rr < 10; ++rr){
        int gr = row0 - 1 + rr;
        uint2 hv; hv.x = 0u; hv.y = 0u;
        if (gr >= 0 && gr < 256){
            size_t ro = (size_t)(gr - tr0)*256 + px;
            float d0 = bfu(dp0[ro]);
            float d1 = bfu(dp1[ro]);
            float d2 = bfu(dp2[ro]);
            float d3 = bfu(dp3[ro]);
            float Lv = Lb[(size_t)(gr - a + 1)*258 + px + 1];
            float h0 = fmaxf(fmaf(-Lv, as0, d0), 0.f);
            float h1 = fmaxf(fmaf(-Lv, as1, d1), 0.f);
            float hm2 = fmaxf(fmaf(-Lv, as2, d2), 0.f);
            float h3 = fmaxf(fmaf(-Lv, as3, d3), 0.f);
            float a0 = fmaf(w2r[0], h0, fmaf(w2r[1], h1, fmaf(w2r[2], hm2, w2r[3]*h3)));
            float a1 = fmaf(w2r[4], h0, fmaf(w2r[5], h1, fmaf(w2r[6], hm2, w2r[7]*h3)));
            float a2 = fmaf(w2r[8], h0, fmaf(w2r[9], h1, fmaf(w2r[10], hm2, w2r[11]*h3)));
            float a3 = fmaf(w2r[12], h0, fmaf(w2r[13], h1, fmaf(w2r[14], hm2, w2r[15]*h3)));
            hv.x = pk2c(a0, a1);
            hv.y = pk2c(a2, a3);
        }
        h2t[rr][px+1] = hv;
    }
    if (px < 10){ uint2 z; z.x = 0u; z.y = 0u; h2t[px][0] = z; h2t[px][257] = z; }
    __syncthreads();
    // ---- block-uniform tables ----
    s16x2 WPl[9], WPh[9];
    #pragma unroll
    for (int q = 0; q < 9; ++q){
        WPl[q] = __builtin_bit_cast(s16x2, WPNL[g*9+q]);
        WPh[q] = __builtin_bit_cast(s16x2, WPNH[g*9+q]);
    }
    bool lbr = (g >= 63), hbr = (g <= 63);
    s16x2 WDl[18], WDh[18];
    #pragma unroll
    for (int i = 0; i < 18; ++i){
        WDl[i] = __builtin_bit_cast(s16x2, WLDpk[g*18+i]);
        WDh[i] = __builtin_bit_cast(s16x2, WHDpk[g*18+i]);
    }
    // ---- phase 2: rolling registers over 8 output rows ----
    size_t ps = (size_t)orows*256;
    unsigned int* vb = v + ((size_t)bi*128 + g)*ps + (size_t)(ti*8)*256 + px;
    const unsigned int* Lq = Lpk + (size_t)bi*lRp*258 + (size_t)(ti*8)*258 + px;   // tap row base
    s16x2 lq[3][3];
    uint2 ta[3][3];
    #pragma unroll
    for (int rr = 0; rr < 2; ++rr){
        #pragma unroll
        for (int c = 0; c < 3; ++c){
            lq[rr][c] = __builtin_bit_cast(s16x2, Lq[(size_t)rr*258 + c]);
            ta[rr][c] = h2t[rr][px + c];
        }
    }
    #pragma unroll
    for (int r = 0; r < 8; ++r){
        #pragma unroll
        for (int c = 0; c < 3; ++c){
            lq[2][c] = __builtin_bit_cast(s16x2, Lq[(size_t)(r+2)*258 + c]);
            ta[2][c] = h2t[r+2][px + c];
        }
        float sl0 = 0.f, sl1 = 0.f, sh0 = 0.f, sh1 = 0.f;
        #pragma unroll
        for (int dy = 0; dy < 3; ++dy){
            #pragma unroll
            for (int dx = 0; dx < 3; ++dx){
                int q = dy*3 + dx;
                if (q & 1){ sl1 = DOT2B(lq[dy][dx], WPl[q], sl1); sh1 = DOT2B(lq[dy][dx], WPh[q], sh1); }
                else      { sl0 = DOT2B(lq[dy][dx], WPl[q], sl0); sh0 = DOT2B(lq[dy][dx], WPh[q], sh0); }
            }
        }
        if (lbr){
            #pragma unroll
            for (int dy = 0; dy < 3; ++dy){
                #pragma unroll
                for (int dx = 0; dx < 3; ++dx){
                    int q = dy*3 + dx;
                    uint2 tv = ta[dy][dx];
                    sl0 = DOT2B(__builtin_bit_cast(s16x2, tv.x), WDl[2*q],   sl0);
                    sl1 = DOT2B(__builtin_bit_cast(s16x2, tv.y), WDl[2*q+1], sl1);
                }
            }
        }
        if (hbr){
            #pragma unroll
            for (int dy = 0; dy < 3; ++dy){
                #pragma unroll
                for (int dx = 0; dx < 3; ++dx){
                    int q = dy*3 + dx;
                    uint2 tv = ta[dy][dx];
                    sh0 = DOT2B(__builtin_bit_cast(s16x2, tv.x), WDh[2*q],   sh0);
                    sh1 = DOT2B(__builtin_bit_cast(s16x2, tv.y), WDh[2*q+1], sh1);
                }
            }
        }
        vb[(size_t)r*256] = pk2c(fmaxf(sl0+sl1, 0.f), fmaxf(sh0+sh1, 0.f));
        if (g == 126) vb[(size_t)r*256 + ps] = 0u;   // zero pad plane 127
        #pragma unroll
        for (int c = 0; c < 3; ++c){
            ta[0][c] = ta[1][c]; ta[1][c] = ta[2][c];
            lq[0][c] = lq[1][c]; lq[1][c] = lq[2][c];
        }
    }
}

// ---------------- K4: out = v @ BtP^T + x via MFMA, fused residual ----------------
__global__ __launch_bounds__(256) void k_proj(const unsigned int* __restrict__ v,
        const unsigned short* __restrict__ BtP, const float* __restrict__ x,
        float* __restrict__ out, int b0, int a, int orows){
    __shared__ float EoS[256*49];            // 50176 B; Bt overlays first 26112 B
    unsigned short* Bt = (unsigned short*)EoS;   // [48 n][136 u16]
    int t = threadIdx.x;
    for (int i = t; i < 48*256; i += 256){
        int n = i >> 8, k = i & 255;
        Bt[n*136 + k] = BtP[i];
    }
    int bi = blockIdx.x / orows;
    int lr = blockIdx.x - bi*orows;
    int b = b0 + bi;
    size_t ps = (size_t)orows*256;
    const unsigned int* vb = v + (size_t)bi*128*ps + (size_t)lr*256;
    int lane = t & 63, w = t >> 6;
    int pxl = w*64;
    __syncthreads();
    f32x4 acc[4][3];
    #pragma unroll
    for (int m = 0; m < 4; ++m)
        #pragma unroll
        for (int nt = 0; nt < 3; ++nt) acc[m][nt] = (f32x4){0.f,0.f,0.f,0.f};
    #pragma unroll
    for (int ch = 0; ch < 4; ++ch){
        bf16x8 bfr[3][2];
        #pragma unroll
        for (int nt = 0; nt < 3; ++nt)
            #pragma unroll
            for (int kk = 0; kk < 2; ++kk)
                bfr[nt][kk] = *reinterpret_cast<const bf16x8*>(
                    &Bt[(nt*16 + (lane&15))*136 + ch*64 + kk*32 + (lane>>4)*8]);
        #pragma unroll
        for (int m = 0; m < 4; ++m){
            int px = pxl + m*16 + (lane & 15);
            #pragma unroll
            for (int kk = 0; kk < 2; ++kk){
                int pl0 = ch*32 + kk*16 + (lane>>4)*4;
                unsigned int p0 = vb[(size_t)(pl0+0)*ps + px];
                unsigned int p1 = vb[(size_t)(pl0+1)*ps + px];
                unsigned int p2 = vb[(size_t)(pl0+2)*ps + px];
                unsigned int p3 = vb[(size_t)(pl0+3)*ps + px];
                bf16x8 af;
                af[0]=(short)(p0&0xffff); af[1]=(short)(p0>>16);
                af[2]=(short)(p1&0xffff); af[3]=(short)(p1>>16);
                af[4]=(short)(p2&0xffff); af[5]=(short)(p2>>16);
                af[6]=(short)(p3&0xffff); af[7]=(short)(p3>>16);
                #pragma unroll
                for (int nt = 0; nt < 3; ++nt)
                    acc[m][nt] = __builtin_amdgcn_mfma_f32_16x16x32_bf16(af, bfr[nt][kk], acc[m][nt], 0, 0, 0);
            }
        }
    }
    __syncthreads();   // Bt dead -> epilogue buffer
    #pragma unroll
    for (int m = 0; m < 4; ++m){
        #pragma unroll
        for (int nt = 0; nt < 3; ++nt){
            #pragma unroll
            for (int rg = 0; rg < 4; ++rg){
                int epx = pxl + m*16 + (lane>>4)*4 + rg;
                int eo  = nt*16 + (lane&15);
                EoS[epx*49 + eo] = acc[m][nt][rg];
            }
        }
    }
    __syncthreads();
    int grow = a + lr;
    const float* xb = x + (size_t)b*48*HW + (size_t)grow*256 + t;
    float* ob = out + (size_t)b*48*HW + (size_t)grow*256 + t;
    #pragma unroll
    for (int o = 0; o < 48; ++o)
        ob[(size_t)o*HW] = EoS[t*49 + o] + xb[(size_t)o*HW];
}

extern "C" void kernel_launch(void* const* d_in, const int* in_sizes, int n_in,
                              void* d_out, int out_size, void* d_ws, size_t ws_size,
                              hipStream_t stream){
    const float* x    = (const float*)d_in[0];
    const float* winP = (const float*)d_in[1];
    const float* winD = (const float*)d_in[2];
    const float* wlp1 = (const float*)d_in[3];
    const float* whp1 = (const float*)d_in[4];
    const float* wlp2 = (const float*)d_in[5];
    const float* whp2 = (const float*)d_in[6];
    const float* wld  = (const float*)d_in[7];
    const float* whd  = (const float*)d_in[8];
    const float* wout = (const float*)d_in[9];
    float* out = (float*)d_out;

    char* ws = (char*)d_ws;
    size_t off = 0;
    auto alloc = [&](size_t bytes)->char*{
        char* pp = ws + off; off += (bytes + 255) & ~(size_t)255; return pp;
    };
    auto A = [](size_t bytes)->size_t{ return (bytes + 255) & ~(size_t)255; };

    float* ahp1s = (float*)alloc(508*4);
    float* cpG = (float*)alloc(508*4);
    float* cnG = (float*)alloc(508*4);
    unsigned int* WPNL  = (unsigned int*)alloc(127*9*4);
    unsigned int* WPNH  = (unsigned int*)alloc(127*9*4);
    unsigned int* WLDpk = (unsigned int*)alloc(127*18*4);
    unsigned int* WHDpk = (unsigned int*)alloc(127*18*4);
    float* wDp  = (float*)alloc(512*9*4);
    unsigned short* WPb = (unsigned short*)alloc(256*64*2);
    unsigned short* BtP = (unsigned short*)alloc(48*256*2);

    // ladder: Hb must be a multiple of 8 (k_mov tiles)
    const int cfgs[6][2] = {{256,2},{128,2},{64,2},{64,1},{32,1},{16,1}};
    int Hb = 16, nbat = 1;
    for (int ci = 0; ci < 6; ++ci){
        int hb = cfgs[ci][0], nb = cfgs[ci][1];
        int uRr = hb+6 < 256 ? hb+6 : 256;
        int tRr = hb+4 < 256 ? hb+4 : 256;
        size_t need = off;
        need += A((size_t)nb*32*(uRr+2)*258*16);   // u (padded oct layout; v aliases it)
        need += A((size_t)nb*508*tRr*256*2);       // d1s (508 u16 planes)
        need += A((size_t)nb*NCH*tRr*256*4);       // Sp
        need += A((size_t)nb*(hb+2)*258*4);        // Lm (padded)
        need += A((size_t)nb*(hb+2)*258*4);        // Lpk (padded)
        if (need <= ws_size){ Hb = hb; nbat = nb; break; }
    }
    int uR = Hb+6 < 256 ? Hb+6 : 256;
    int tR = Hb+4 < 256 ? Hb+4 : 256;
    int uRp = uR + 2;
    int lRp = Hb + 2;
    uint4* u   = (uint4*)alloc((size_t)nbat*32*uRp*258*16);
    unsigned short* d1s = (unsigned short*)alloc((size_t)nbat*508*tR*256*2);
    float* Sp = (float*)alloc((size_t)nbat*NCH*tR*256*4);
    float* Lm = (float*)alloc((size_t)nbat*lRp*258*4);
    unsigned int* Lpk = (unsigned int*)alloc((size_t)nbat*lRp*258*4);
    // v aliases u: u is dead after k_dw; per-band order pconv->dw->mov->proj keeps it safe.
    unsigned int* v = (unsigned int*)u;

    k_coef1<<<1, 512, 0, stream>>>(wlp1, whp1, wlp2, ahp1s, cpG, cnG);
    k_coef2<<<64, 256, 0, stream>>>(wld, whd, winP, winD, wout, cpG, cnG,
                                    WPNL, WPNH, WLDpk, WHDpk, wDp, WPb, BtP);

    for (int b0 = 0; b0 < 2; b0 += nbat){
        for (int a = 0; a < 256; a += Hb){
            int ur0 = a-3 > 0 ? a-3 : 0;  int ur1 = a+Hb+3 < 256 ? a+Hb+3 : 256;
            int tr0 = a-2 > 0 ? a-2 : 0;  int tr1 = a+Hb+2 < 256 ? a+Hb+2 : 256;
            int lr0 = a-1 > 0 ? a-1 : 0;  int lr1 = a+Hb+1 < 256 ? a+Hb+1 : 256;
            int urows = ur1-ur0, trows = tr1-tr0, lrows = lr1-lr0;
            int orows = (a+Hb < 256 ? a+Hb : 256) - a;
            k_padU<<<nbat*32 + nbat, 256, 0, stream>>>(u, Lm, Lpk, uRp, lRp, nbat,
                                                       a == 0, a + Hb >= 256);
            k_pconv<<<nbat*urows*4, 256, 0, stream>>>(x, WPb, u, b0, ur0, urows, uRp);
            k_dw  <<<nbat*trows*NCH, 256, 0, stream>>>(u, wDp, whp1, d1s, Sp, tr0, trows, ur0, uRp, tR, nbat);
            k_box <<<nbat*lrows, 256, 0, stream>>>(Sp, Lm, Lpk, lr0, lrows, tr0, tR, a, lRp, nbat);
            k_mov <<<nbat*(orows>>3)*127, 256, 0, stream>>>(d1s, Lm, Lpk, whp2, ahp1s,
                                                            WPNL, WPNH, WLDpk, WHDpk, v,
                                                            a, orows, tr0, tR, lRp);
            k_proj<<<nbat*orows, 256, 0, stream>>>(v, BtP, x, out, b0, a, orows);
        }
    }
}